// Round 3
// baseline (9617.579 us; speedup 1.0000x reference)
//
#include <hip/hip_runtime.h>
#include <math.h>

// B=64, L=512, C=64, E=64, F=257, PRED=512, H1=1024, H2=3072
// ---- workspace layout (f32 units), peak 17,047,552 = 68.2 MB ----
#define U_XRE   0               // [64][257][64]
#define U_XIM   1052672
#define U_KEEPI 2105344         // int[4096*32]
#define U_KEEPW 2236416         // f32[4096*32]
#define U_XFILT 2367488         // [64][512][64]
#define U_NORM  4464640         // [64][512][64]
#define U_H     6561792         // [4096][1024]
#define U_Q     10756096        // [64][512][64] f32
#define U_K     12853248
#define U_V     14950400        // ends 17047552
#define U_HID   0               // chunk [1024][3072] = 3145728 (xre/xim/keep/xfilt dead by fc1)

#define TWO_PI_OVER_512 0.012271846303085129

// ===== 1. naive DFT: one block per (f, b), one thread per channel =====
__global__ __launch_bounds__(64) void dft_naive(const float* __restrict__ x,
                                                float* __restrict__ xre,
                                                float* __restrict__ xim) {
    __shared__ float ct[512], st[512];
    int c = threadIdx.x;
    int f = blockIdx.x;
    int b = blockIdx.y;
    for (int i = c; i < 512; i += 64) {
        float s, cc; sincosf((float)((double)i * TWO_PI_OVER_512), &s, &cc);
        ct[i] = cc; st[i] = s;
    }
    __syncthreads();
    float re = 0.f, im = 0.f;
    for (int t = 0; t < 512; ++t) {
        int idx = (f * t) & 511;
        float v = x[((size_t)b * 512 + t) * 64 + c];
        re += v * ct[idx];
        im -= v * st[idx];
    }
    xre[((size_t)b * 257 + f) * 64 + c] = re;
    xim[((size_t)b * 257 + f) * 64 + c] = im;
}

// ===== 2. naive top-k: one thread per (b,c), serial selection =====
__global__ __launch_bounds__(256) void topk_naive(const float* __restrict__ xre,
                                                  const float* __restrict__ xim,
                                                  int* __restrict__ keepi,
                                                  float* __restrict__ keepw,
                                                  const int* __restrict__ kptr) {
    int bc = blockIdx.x * 256 + threadIdx.x;   // 0..4095
    int b = bc >> 6, c = bc & 63;
    int kk = *kptr; if (kk > 32) kk = 32;
    float mag[257];
    for (int f = 0; f < 257; ++f) {
        float re = xre[((size_t)b * 257 + f) * 64 + c];
        float im = xim[((size_t)b * 257 + f) * 64 + c];
        mag[f] = sqrtf(re * re + im * im);
    }
    for (int j = 0; j < kk; ++j) {
        float best = -1.f; int bf = 0;
        for (int f = 0; f < 257; ++f)
            if (mag[f] > best) { best = mag[f]; bf = f; }   // strict >: lowest f on ties
        keepi[bc * 32 + j] = bf;
        keepw[bc * 32 + j] = (bf == 0 || bf == 256) ? (1.f / 512.f) : (2.f / 512.f);
        mag[bf] = -1.f;
    }
}

// ===== 3. naive x_filt + norm: one block per (t, b), thread per channel =====
__global__ __launch_bounds__(64) void xfilt_naive(const float* __restrict__ x,
                                                  const float* __restrict__ xre,
                                                  const float* __restrict__ xim,
                                                  const int* __restrict__ keepi,
                                                  const float* __restrict__ keepw,
                                                  float* __restrict__ xfilt,
                                                  float* __restrict__ norm,
                                                  const int* __restrict__ kptr) {
    __shared__ float ct[512], st[512];
    int c = threadIdx.x;
    int t = blockIdx.x;
    int b = blockIdx.y;
    for (int i = c; i < 512; i += 64) {
        float s, cc; sincosf((float)((double)i * TWO_PI_OVER_512), &s, &cc);
        ct[i] = cc; st[i] = s;
    }
    __syncthreads();
    int kk = *kptr; if (kk > 32) kk = 32;
    int bc = b * 64 + c;
    float acc = 0.f;
    for (int j = 0; j < kk; ++j) {
        int f = keepi[bc * 32 + j];
        float w = keepw[bc * 32 + j];
        float re = xre[((size_t)b * 257 + f) * 64 + c];
        float im = xim[((size_t)b * 257 + f) * 64 + c];
        int idx = (f * t) & 511;
        acc += w * (re * ct[idx] - im * st[idx]);
    }
    size_t a = ((size_t)b * 512 + t) * 64 + c;
    xfilt[a] = acc;
    norm[a] = x[a] - acc;
}

// ===== 4. naive FAN + xt: one block per row (b,c) =====
__global__ __launch_bounds__(512) void fanh_naive(const float* __restrict__ x,
                                                  const float* __restrict__ xfilt,
                                                  const float* __restrict__ Wp,
                                                  const float* __restrict__ bp,
                                                  const float* __restrict__ Wg,
                                                  const float* __restrict__ bg,
                                                  const float* __restrict__ gate,
                                                  float* __restrict__ h) {
    __shared__ float mf[512];
    int tid = threadIdx.x;
    int row = blockIdx.x;          // b*64 + c
    int b = row >> 6, c = row & 63;
    mf[tid] = xfilt[((size_t)b * 512 + tid) * 64 + c];
    __syncthreads();
    float gt = 1.f / (1.f + expf(-gate[0]));
    if (tid < 128) {
        int j = tid;
        float acc = bp[j];
        for (int t = 0; t < 512; ++t) acc += mf[t] * Wp[(size_t)j * 512 + t];
        h[(size_t)row * 1024 + j]       = gt * cosf(acc);
        h[(size_t)row * 1024 + 128 + j] = gt * sinf(acc);
    } else if (tid < 384) {
        int j = tid - 128;
        float acc = bg[j];
        for (int t = 0; t < 512; ++t) acc += mf[t] * Wg[(size_t)j * 512 + t];
        h[(size_t)row * 1024 + 256 + j] = (1.f - gt) * 0.5f * acc * (1.f + erff(acc * 0.70710678118f));
    } else {
        for (int i = 0; i < 4; ++i) {
            int t = (tid - 384) + 128 * i;
            h[(size_t)row * 1024 + 512 + t] = x[((size_t)b * 512 + t) * 64 + c];
        }
    }
}

// ===== 5. naive QKV: one block per (t, b), thread per output (192) =====
__global__ __launch_bounds__(192) void qkv_naive(const float* __restrict__ xfilt,
                                                 const float* __restrict__ norm,
                                                 const float* __restrict__ w,
                                                 const float* __restrict__ bias,
                                                 float* __restrict__ q,
                                                 float* __restrict__ kmat,
                                                 float* __restrict__ v) {
    __shared__ float xf[64], nm[64];
    int tid = threadIdx.x;
    int t = blockIdx.x;
    int b = blockIdx.y;
    if (tid < 64) {
        size_t a = ((size_t)b * 512 + t) * 64 + tid;
        xf[tid] = xfilt[a];
        nm[tid] = norm[a];
    }
    __syncthreads();
    int o = tid;
    const float* src = (o < 64) ? xf : nm;
    float acc = bias[o];
    for (int e = 0; e < 64; ++e) acc += w[(size_t)o * 64 + e] * src[e];
    size_t base = ((size_t)b * 512 + t) * 64;
    if (o < 64)       q[base + o] = acc;
    else if (o < 128) kmat[base + o - 64] = acc;
    else              v[base + o - 128] = acc;
}

// ===== 6. attention + out-proj (retained from round 0, fp32) =====
__global__ __launch_bounds__(256) void attn_kernel(const float* __restrict__ q,
                                                   const float* __restrict__ kmat,
                                                   const float* __restrict__ v,
                                                   const float* __restrict__ ow,
                                                   const float* __restrict__ ob,
                                                   float* __restrict__ out) {
    __shared__ float qs[16 * 65];
    __shared__ float kv[64 * 65];
    __shared__ float S[16 * 512];
    __shared__ float Os[16 * 65];
    __shared__ float invl[16];
    int tid = threadIdx.x;
    int b = blockIdx.y;
    int i0 = blockIdx.x * 16;
    int jl = tid & 63, rg = tid >> 6;
    for (int i = tid; i < 1024; i += 256) {
        int r = i >> 6, e = i & 63;
        qs[r * 65 + e] = q[((size_t)(b * 512) + i0 + r) * 64 + e];
    }
    for (int jt = 0; jt < 8; ++jt) {
        __syncthreads();
        for (int i = tid; i < 4096; i += 256) {
            int r = i >> 6, e = i & 63;
            kv[r * 65 + e] = kmat[((size_t)(b * 512) + jt * 64 + r) * 64 + e];
        }
        __syncthreads();
        float a0 = 0, a1 = 0, a2 = 0, a3 = 0;
        for (int e = 0; e < 64; ++e) {
            float kvv = kv[jl * 65 + e];
            a0 += qs[(rg * 4 + 0) * 65 + e] * kvv;
            a1 += qs[(rg * 4 + 1) * 65 + e] * kvv;
            a2 += qs[(rg * 4 + 2) * 65 + e] * kvv;
            a3 += qs[(rg * 4 + 3) * 65 + e] * kvv;
        }
        S[(rg * 4 + 0) * 512 + jt * 64 + jl] = a0 * 0.125f;
        S[(rg * 4 + 1) * 512 + jt * 64 + jl] = a1 * 0.125f;
        S[(rg * 4 + 2) * 512 + jt * 64 + jl] = a2 * 0.125f;
        S[(rg * 4 + 3) * 512 + jt * 64 + jl] = a3 * 0.125f;
    }
    #pragma unroll
    for (int ii = 0; ii < 4; ++ii) {
        int il = rg * 4 + ii;
        float p[8];
        float mx = -1e30f;
        #pragma unroll
        for (int s = 0; s < 8; ++s) { p[s] = S[il * 512 + jl + 64 * s]; mx = fmaxf(mx, p[s]); }
        for (int off = 32; off; off >>= 1) mx = fmaxf(mx, __shfl_xor(mx, off));
        float sum = 0.f;
        #pragma unroll
        for (int s = 0; s < 8; ++s) { p[s] = expf(p[s] - mx); sum += p[s]; S[il * 512 + jl + 64 * s] = p[s]; }
        for (int off = 32; off; off >>= 1) sum += __shfl_xor(sum, off);
        if (jl == 0) invl[il] = 1.0f / sum;
    }
    float o0 = 0, o1 = 0, o2 = 0, o3 = 0;
    for (int jt = 0; jt < 8; ++jt) {
        __syncthreads();
        for (int i = tid; i < 4096; i += 256) {
            int r = i >> 6, e = i & 63;
            kv[r * 65 + e] = v[((size_t)(b * 512) + jt * 64 + r) * 64 + e];
        }
        __syncthreads();
        for (int j2 = 0; j2 < 64; ++j2) {
            float vv = kv[j2 * 65 + jl];
            o0 += S[(rg * 4 + 0) * 512 + jt * 64 + j2] * vv;
            o1 += S[(rg * 4 + 1) * 512 + jt * 64 + j2] * vv;
            o2 += S[(rg * 4 + 2) * 512 + jt * 64 + j2] * vv;
            o3 += S[(rg * 4 + 3) * 512 + jt * 64 + j2] * vv;
        }
    }
    o0 *= invl[rg * 4 + 0]; o1 *= invl[rg * 4 + 1];
    o2 *= invl[rg * 4 + 2]; o3 *= invl[rg * 4 + 3];
    Os[(rg * 4 + 0) * 65 + jl] = o0;
    Os[(rg * 4 + 1) * 65 + jl] = o1;
    Os[(rg * 4 + 2) * 65 + jl] = o2;
    Os[(rg * 4 + 3) * 65 + jl] = o3;
    __syncthreads();
    for (int i = tid; i < 4096; i += 256) {
        int o = i >> 6, e = i & 63;
        kv[e * 65 + o] = ow[i];
    }
    __syncthreads();
    {
        int o = jl;
        float bb = ob[o];
        #pragma unroll
        for (int ii = 0; ii < 4; ++ii) {
            int il = rg * 4 + ii;
            float acc = bb;
            for (int e = 0; e < 64; ++e) acc += Os[il * 65 + e] * kv[e * 65 + o];
            out[((size_t)(b * 512) + i0 + il) * 64 + o] = acc;
        }
    }
}

// ===== 7. naive fc1 (relu): block per row, 256 cols per grid.y =====
__global__ __launch_bounds__(256) void fc1_naive(const float* __restrict__ h,
                                                 const float* __restrict__ fc1_w,
                                                 const float* __restrict__ fc1_b,
                                                 float* __restrict__ hid,
                                                 int row0) {
    __shared__ float hr[1024];
    int tid = threadIdx.x;
    int row = blockIdx.x;                 // chunk-local 0..1023
    size_t grow = row0 + row;
    for (int i = tid; i < 1024; i += 256) hr[i] = h[grow * 1024 + i];
    __syncthreads();
    int n = blockIdx.y * 256 + tid;
    float acc = fc1_b[n];
    for (int e = 0; e < 1024; ++e) acc += hr[e] * fc1_w[(size_t)n * 1024 + e];
    hid[(size_t)row * 3072 + n] = fmaxf(acc, 0.f);
}

// ===== 8. naive fc2 + transposed store =====
__global__ __launch_bounds__(256) void fc2_naive(const float* __restrict__ hid,
                                                 const float* __restrict__ fc2_w,
                                                 const float* __restrict__ fc2_b,
                                                 float* __restrict__ out2,
                                                 int row0) {
    __shared__ float hr[3072];
    int tid = threadIdx.x;
    int row = blockIdx.x;                 // chunk-local 0..1023
    int grow = row0 + row;
    int b = grow >> 6, c = grow & 63;
    for (int i = tid; i < 3072; i += 256) hr[i] = hid[(size_t)row * 3072 + i];
    __syncthreads();
    int n = blockIdx.y * 256 + tid;       // pred index 0..511
    float acc = fc2_b[n];
    for (int e = 0; e < 3072; ++e) acc += hr[e] * fc2_w[(size_t)n * 3072 + e];
    out2[((size_t)b * 512 + n) * 64 + c] = acc;
}

extern "C" void kernel_launch(void* const* d_in, const int* in_sizes, int n_in,
                              void* d_out, int out_size, void* d_ws, size_t ws_size,
                              hipStream_t stream) {
    const float* x         = (const float*)d_in[0];
    const float* in_proj_w = (const float*)d_in[1];
    const float* in_proj_b = (const float*)d_in[2];
    const float* out_w     = (const float*)d_in[3];
    const float* out_b     = (const float*)d_in[4];
    const float* Wp        = (const float*)d_in[5];
    const float* bp        = (const float*)d_in[6];
    const float* Wg        = (const float*)d_in[7];
    const float* bg        = (const float*)d_in[8];
    const float* gate      = (const float*)d_in[9];
    const float* fc1_w     = (const float*)d_in[10];
    const float* fc1_b     = (const float*)d_in[11];
    const float* fc2_w     = (const float*)d_in[12];
    const float* fc2_b     = (const float*)d_in[13];
    const int*   kptr      = (const int*)d_in[14];
    float* ws  = (float*)d_ws;
    float* out = (float*)d_out;

    float* xre   = ws + U_XRE;
    float* xim   = ws + U_XIM;
    int*   keepi = (int*)(ws + U_KEEPI);
    float* keepw = ws + U_KEEPW;
    float* xfilt = ws + U_XFILT;
    float* norm  = ws + U_NORM;
    float* h     = ws + U_H;
    float* qb    = ws + U_Q;
    float* kb    = ws + U_K;
    float* vb    = ws + U_V;
    float* hid   = ws + U_HID;

    dft_naive  <<<dim3(257, 64), 64,  0, stream>>>(x, xre, xim);
    topk_naive <<<dim3(16),      256, 0, stream>>>(xre, xim, keepi, keepw, kptr);
    xfilt_naive<<<dim3(512, 64), 64,  0, stream>>>(x, xre, xim, keepi, keepw, xfilt, norm, kptr);
    qkv_naive  <<<dim3(512, 64), 192, 0, stream>>>(xfilt, norm, in_proj_w, in_proj_b, qb, kb, vb);
    attn_kernel<<<dim3(32, 64),  256, 0, stream>>>(qb, kb, vb, out_w, out_b, out);
    fanh_naive <<<dim3(4096),    512, 0, stream>>>(x, xfilt, Wp, bp, Wg, bg, gate, h);
    for (int c4 = 0; c4 < 4; ++c4) {
        fc1_naive<<<dim3(1024, 12), 256, 0, stream>>>(h, fc1_w, fc1_b, hid, c4 * 1024);
        fc2_naive<<<dim3(1024, 2),  256, 0, stream>>>(hid, fc2_w, fc2_b, out + 2097152, c4 * 1024);
    }
}

// Round 4
// 2343.857 us; speedup vs baseline: 4.1033x; 4.1033x over previous
//
#include <hip/hip_runtime.h>
#include <math.h>

// B=64, L=512, C=64, E=64, F=257, PRED=512, H1=1024, H2=3072
// ---- workspace layout (f32 units), peak 17,047,552 = 68.19 MB (== round-3 proven) ----
// lifetimes: xre/xim[dft..xfilt] keep[topk..xfilt] xfilt[xfilt..transpose]
//            norm[xfilt..qkv] q/k/v[qkv..attn] mft[transpose..fan] h[transpose..fc1]
#define U_H     0            // [4096][1024]            -> 4194304
#define U_MFT   4194304      // [4096][512]             -> 6291456
#define U_XRE   6291456      // [64][257][64]           -> 7344128
#define U_XIM   7344128      //                         -> 8396800
#define U_KEEPI 8396800      // int[4096*32]            -> 8527872
#define U_KEEPW 8527872      //                         -> 8658944
#define U_XFILT 8658944      // [64][512][64]           -> 10756096
#define U_NORM  10756096     // [64][512][64]           -> 12853248
#define U_Q     6291456      // f32 [64][512][64] over dead xre/xim -> 8388608
#define U_K     12853248     //                         -> 14950400
#define U_V     14950400     //                         -> 17047552  (peak)
#define U_HID   6291456      // chunk [1024][3072] over dead q/keep/xfilt -> 9437184

#define TWO_PI_OVER_512 0.012271846303085129

// ===== 1. naive DFT (proven round 3) =====
__global__ __launch_bounds__(64) void dft_naive(const float* __restrict__ x,
                                                float* __restrict__ xre,
                                                float* __restrict__ xim) {
    __shared__ float ct[512], st[512];
    int c = threadIdx.x;
    int f = blockIdx.x;
    int b = blockIdx.y;
    for (int i = c; i < 512; i += 64) {
        float s, cc; sincosf((float)((double)i * TWO_PI_OVER_512), &s, &cc);
        ct[i] = cc; st[i] = s;
    }
    __syncthreads();
    float re = 0.f, im = 0.f;
    for (int t = 0; t < 512; ++t) {
        int idx = (f * t) & 511;
        float v = x[((size_t)b * 512 + t) * 64 + c];
        re += v * ct[idx];
        im -= v * st[idx];
    }
    xre[((size_t)b * 257 + f) * 64 + c] = re;
    xim[((size_t)b * 257 + f) * 64 + c] = im;
}

// ===== 2. naive top-k (proven round 3) =====
__global__ __launch_bounds__(256) void topk_naive(const float* __restrict__ xre,
                                                  const float* __restrict__ xim,
                                                  int* __restrict__ keepi,
                                                  float* __restrict__ keepw,
                                                  const int* __restrict__ kptr) {
    int bc = blockIdx.x * 256 + threadIdx.x;
    int b = bc >> 6, c = bc & 63;
    int kk = *kptr; if (kk > 32) kk = 32;
    float mag[257];
    for (int f = 0; f < 257; ++f) {
        float re = xre[((size_t)b * 257 + f) * 64 + c];
        float im = xim[((size_t)b * 257 + f) * 64 + c];
        mag[f] = sqrtf(re * re + im * im);
    }
    for (int j = 0; j < kk; ++j) {
        float best = -1.f; int bf = 0;
        for (int f = 0; f < 257; ++f)
            if (mag[f] > best) { best = mag[f]; bf = f; }
        keepi[bc * 32 + j] = bf;
        keepw[bc * 32 + j] = (bf == 0 || bf == 256) ? (1.f / 512.f) : (2.f / 512.f);
        mag[bf] = -1.f;
    }
}

// ===== 3. naive x_filt + norm (proven round 3) =====
__global__ __launch_bounds__(64) void xfilt_naive(const float* __restrict__ x,
                                                  const float* __restrict__ xre,
                                                  const float* __restrict__ xim,
                                                  const int* __restrict__ keepi,
                                                  const float* __restrict__ keepw,
                                                  float* __restrict__ xfilt,
                                                  float* __restrict__ norm,
                                                  const int* __restrict__ kptr) {
    __shared__ float ct[512], st[512];
    int c = threadIdx.x;
    int t = blockIdx.x;
    int b = blockIdx.y;
    for (int i = c; i < 512; i += 64) {
        float s, cc; sincosf((float)((double)i * TWO_PI_OVER_512), &s, &cc);
        ct[i] = cc; st[i] = s;
    }
    __syncthreads();
    int kk = *kptr; if (kk > 32) kk = 32;
    int bc = b * 64 + c;
    float acc = 0.f;
    for (int j = 0; j < kk; ++j) {
        int f = keepi[bc * 32 + j];
        float w = keepw[bc * 32 + j];
        float re = xre[((size_t)b * 257 + f) * 64 + c];
        float im = xim[((size_t)b * 257 + f) * 64 + c];
        int idx = (f * t) & 511;
        acc += w * (re * ct[idx] - im * st[idx]);
    }
    size_t a = ((size_t)b * 512 + t) * 64 + c;
    xfilt[a] = acc;
    norm[a] = x[a] - acc;
}

// ===== 4. naive QKV (proven round 3) =====
__global__ __launch_bounds__(192) void qkv_naive(const float* __restrict__ xfilt,
                                                 const float* __restrict__ norm,
                                                 const float* __restrict__ w,
                                                 const float* __restrict__ bias,
                                                 float* __restrict__ q,
                                                 float* __restrict__ kmat,
                                                 float* __restrict__ v) {
    __shared__ float xf[64], nm[64];
    int tid = threadIdx.x;
    int t = blockIdx.x;
    int b = blockIdx.y;
    if (tid < 64) {
        size_t a = ((size_t)b * 512 + t) * 64 + tid;
        xf[tid] = xfilt[a];
        nm[tid] = norm[a];
    }
    __syncthreads();
    int o = tid;
    const float* src = (o < 64) ? xf : nm;
    float acc = bias[o];
    for (int e = 0; e < 64; ++e) acc += w[(size_t)o * 64 + e] * src[e];
    size_t base = ((size_t)b * 512 + t) * 64;
    if (o < 64)       q[base + o] = acc;
    else if (o < 128) kmat[base + o - 64] = acc;
    else              v[base + o - 128] = acc;
}

// ===== 5. transpose: xfilt[b][t][c] -> mft[bc][t]; x[b][t][c] -> h[bc][512+t] =====
__global__ __launch_bounds__(256) void transpose_k(const float* __restrict__ x,
                                                   const float* __restrict__ xfilt,
                                                   float* __restrict__ mft,
                                                   float* __restrict__ h) {
    __shared__ float t1[64 * 65], t2[64 * 65];
    int tid = threadIdx.x;
    int t0 = blockIdx.x * 64;
    int b = blockIdx.y;
    for (int i = tid; i < 4096; i += 256) {
        int tl = i >> 6, c = i & 63;
        size_t a = ((size_t)(b * 512) + t0 + tl) * 64 + c;
        t1[c * 65 + tl] = xfilt[a];
        t2[c * 65 + tl] = x[a];
    }
    __syncthreads();
    for (int i = tid; i < 4096; i += 256) {
        int c = i >> 6, tl = i & 63;
        mft[((size_t)(b * 64) + c) * 512 + t0 + tl] = t1[c * 65 + tl];
        h[((size_t)(b * 64) + c) * 1024 + 512 + t0 + tl] = t2[c * 65 + tl];
    }
}

// ===== 6. attention + out-proj (proven rounds 0-3) =====
__global__ __launch_bounds__(256) void attn_kernel(const float* __restrict__ q,
                                                   const float* __restrict__ kmat,
                                                   const float* __restrict__ v,
                                                   const float* __restrict__ ow,
                                                   const float* __restrict__ ob,
                                                   float* __restrict__ out) {
    __shared__ float qs[16 * 65];
    __shared__ float kv[64 * 65];
    __shared__ float S[16 * 512];
    __shared__ float Os[16 * 65];
    __shared__ float invl[16];
    int tid = threadIdx.x;
    int b = blockIdx.y;
    int i0 = blockIdx.x * 16;
    int jl = tid & 63, rg = tid >> 6;
    for (int i = tid; i < 1024; i += 256) {
        int r = i >> 6, e = i & 63;
        qs[r * 65 + e] = q[((size_t)(b * 512) + i0 + r) * 64 + e];
    }
    for (int jt = 0; jt < 8; ++jt) {
        __syncthreads();
        for (int i = tid; i < 4096; i += 256) {
            int r = i >> 6, e = i & 63;
            kv[r * 65 + e] = kmat[((size_t)(b * 512) + jt * 64 + r) * 64 + e];
        }
        __syncthreads();
        float a0 = 0, a1 = 0, a2 = 0, a3 = 0;
        for (int e = 0; e < 64; ++e) {
            float kvv = kv[jl * 65 + e];
            a0 += qs[(rg * 4 + 0) * 65 + e] * kvv;
            a1 += qs[(rg * 4 + 1) * 65 + e] * kvv;
            a2 += qs[(rg * 4 + 2) * 65 + e] * kvv;
            a3 += qs[(rg * 4 + 3) * 65 + e] * kvv;
        }
        S[(rg * 4 + 0) * 512 + jt * 64 + jl] = a0 * 0.125f;
        S[(rg * 4 + 1) * 512 + jt * 64 + jl] = a1 * 0.125f;
        S[(rg * 4 + 2) * 512 + jt * 64 + jl] = a2 * 0.125f;
        S[(rg * 4 + 3) * 512 + jt * 64 + jl] = a3 * 0.125f;
    }
    #pragma unroll
    for (int ii = 0; ii < 4; ++ii) {
        int il = rg * 4 + ii;
        float p[8];
        float mx = -1e30f;
        #pragma unroll
        for (int s = 0; s < 8; ++s) { p[s] = S[il * 512 + jl + 64 * s]; mx = fmaxf(mx, p[s]); }
        for (int off = 32; off; off >>= 1) mx = fmaxf(mx, __shfl_xor(mx, off));
        float sum = 0.f;
        #pragma unroll
        for (int s = 0; s < 8; ++s) { p[s] = expf(p[s] - mx); sum += p[s]; S[il * 512 + jl + 64 * s] = p[s]; }
        for (int off = 32; off; off >>= 1) sum += __shfl_xor(sum, off);
        if (jl == 0) invl[il] = 1.0f / sum;
    }
    float o0 = 0, o1 = 0, o2 = 0, o3 = 0;
    for (int jt = 0; jt < 8; ++jt) {
        __syncthreads();
        for (int i = tid; i < 4096; i += 256) {
            int r = i >> 6, e = i & 63;
            kv[r * 65 + e] = v[((size_t)(b * 512) + jt * 64 + r) * 64 + e];
        }
        __syncthreads();
        for (int j2 = 0; j2 < 64; ++j2) {
            float vv = kv[j2 * 65 + jl];
            o0 += S[(rg * 4 + 0) * 512 + jt * 64 + j2] * vv;
            o1 += S[(rg * 4 + 1) * 512 + jt * 64 + j2] * vv;
            o2 += S[(rg * 4 + 2) * 512 + jt * 64 + j2] * vv;
            o3 += S[(rg * 4 + 3) * 512 + jt * 64 + j2] * vv;
        }
    }
    o0 *= invl[rg * 4 + 0]; o1 *= invl[rg * 4 + 1];
    o2 *= invl[rg * 4 + 2]; o3 *= invl[rg * 4 + 3];
    Os[(rg * 4 + 0) * 65 + jl] = o0;
    Os[(rg * 4 + 1) * 65 + jl] = o1;
    Os[(rg * 4 + 2) * 65 + jl] = o2;
    Os[(rg * 4 + 3) * 65 + jl] = o3;
    __syncthreads();
    for (int i = tid; i < 4096; i += 256) {
        int o = i >> 6, e = i & 63;
        kv[e * 65 + o] = ow[i];
    }
    __syncthreads();
    {
        int o = jl;
        float bb = ob[o];
        #pragma unroll
        for (int ii = 0; ii < 4; ++ii) {
            int il = rg * 4 + ii;
            float acc = bb;
            for (int e = 0; e < 64; ++e) acc += Os[il * 65 + e] * kv[e * 65 + o];
            out[((size_t)(b * 512) + i0 + il) * 64 + o] = acc;
        }
    }
}

// ===== 7. tiled fp32 GEMM: C = A[M,K] @ W[N,K]^T + bias, 64x64 tile =====
// EPI 1: relu -> C[row*ldc+col]
// EPI 2: h[row,col]=gt*cos(v); h[row,128+col]=gt*sin(v)
// EPI 3: h[row,256+col]=(1-gt)*gelu(v)
// EPI 4: pred transpose store: out[(b*512 + n)*64 + c], b=(moff+m0)/64, c=row%64
template<int EPI>
__global__ __launch_bounds__(256) void gemm_k(const float* __restrict__ A,
                                              const float* __restrict__ W,
                                              const float* __restrict__ bias,
                                              float* __restrict__ C,
                                              int K, int ldc,
                                              const float* __restrict__ gate,
                                              int moff) {
    __shared__ float As[32 * 64];
    __shared__ float Bs[32 * 64];
    __shared__ float Cs[(EPI == 4) ? 64 * 65 : 1];
    int tid = threadIdx.x;
    int tx = tid & 15, ty = tid >> 4;
    int m0 = blockIdx.y * 64, n0 = blockIdx.x * 64;
    float acc[4][4] = {};
    for (int k0 = 0; k0 < K; k0 += 32) {
        __syncthreads();
        #pragma unroll
        for (int s = 0; s < 2; ++s) {
            int i4 = tid + s * 256;
            int row = i4 >> 3, kq = i4 & 7;
            float4 a4 = *(const float4*)&A[(size_t)(m0 + row) * K + k0 + kq * 4];
            float4 w4 = *(const float4*)&W[(size_t)(n0 + row) * K + k0 + kq * 4];
            int kb = kq * 4;
            As[(kb + 0) * 64 + row] = a4.x; As[(kb + 1) * 64 + row] = a4.y;
            As[(kb + 2) * 64 + row] = a4.z; As[(kb + 3) * 64 + row] = a4.w;
            Bs[(kb + 0) * 64 + row] = w4.x; Bs[(kb + 1) * 64 + row] = w4.y;
            Bs[(kb + 2) * 64 + row] = w4.z; Bs[(kb + 3) * 64 + row] = w4.w;
        }
        __syncthreads();
        #pragma unroll
        for (int kk = 0; kk < 32; ++kk) {
            float4 a4 = *(const float4*)&As[kk * 64 + (ty << 2)];
            float4 b4 = *(const float4*)&Bs[kk * 64 + (tx << 2)];
            #pragma unroll
            for (int i = 0; i < 4; ++i)
                #pragma unroll
                for (int j = 0; j < 4; ++j)
                    acc[i][j] += (&a4.x)[i] * (&b4.x)[j];
        }
    }
    int row0 = m0 + ty * 4, col0 = n0 + tx * 4;
    float4 bb = *(const float4*)&bias[col0];
    float gt = 0.f;
    if (EPI == 2 || EPI == 3) gt = 1.f / (1.f + expf(-gate[0]));
    #pragma unroll
    for (int i = 0; i < 4; ++i) {
        int row = row0 + i;
        float v0 = acc[i][0] + bb.x, v1 = acc[i][1] + bb.y;
        float v2 = acc[i][2] + bb.z, v3 = acc[i][3] + bb.w;
        if (EPI == 1) {
            float4 o = make_float4(fmaxf(v0, 0.f), fmaxf(v1, 0.f), fmaxf(v2, 0.f), fmaxf(v3, 0.f));
            *(float4*)&C[(size_t)row * ldc + col0] = o;
        } else if (EPI == 2) {
            float4 co = make_float4(gt * cosf(v0), gt * cosf(v1), gt * cosf(v2), gt * cosf(v3));
            float4 si = make_float4(gt * sinf(v0), gt * sinf(v1), gt * sinf(v2), gt * sinf(v3));
            *(float4*)&C[(size_t)row * 1024 + col0] = co;
            *(float4*)&C[(size_t)row * 1024 + 128 + col0] = si;
        } else if (EPI == 3) {
            float ig = 1.f - gt;
            float4 o = make_float4(
                ig * 0.5f * v0 * (1.f + erff(v0 * 0.70710678118f)),
                ig * 0.5f * v1 * (1.f + erff(v1 * 0.70710678118f)),
                ig * 0.5f * v2 * (1.f + erff(v2 * 0.70710678118f)),
                ig * 0.5f * v3 * (1.f + erff(v3 * 0.70710678118f)));
            *(float4*)&C[(size_t)row * 1024 + 256 + col0] = o;
        } else if (EPI == 4) {
            int rl = ty * 4 + i;
            Cs[rl * 65 + tx * 4 + 0] = v0;
            Cs[rl * 65 + tx * 4 + 1] = v1;
            Cs[rl * 65 + tx * 4 + 2] = v2;
            Cs[rl * 65 + tx * 4 + 3] = v3;
        }
    }
    if (EPI == 4) {
        __syncthreads();
        int b = (moff + m0) >> 6;
        for (int i2 = tid; i2 < 4096; i2 += 256) {
            int tl = i2 >> 6, cl = i2 & 63;
            C[((size_t)(b * 512) + n0 + tl) * 64 + cl] = Cs[cl * 65 + tl];
        }
    }
}

extern "C" void kernel_launch(void* const* d_in, const int* in_sizes, int n_in,
                              void* d_out, int out_size, void* d_ws, size_t ws_size,
                              hipStream_t stream) {
    const float* x         = (const float*)d_in[0];
    const float* in_proj_w = (const float*)d_in[1];
    const float* in_proj_b = (const float*)d_in[2];
    const float* out_w     = (const float*)d_in[3];
    const float* out_b     = (const float*)d_in[4];
    const float* Wp        = (const float*)d_in[5];
    const float* bp        = (const float*)d_in[6];
    const float* Wg        = (const float*)d_in[7];
    const float* bg        = (const float*)d_in[8];
    const float* gate      = (const float*)d_in[9];
    const float* fc1_w     = (const float*)d_in[10];
    const float* fc1_b     = (const float*)d_in[11];
    const float* fc2_w     = (const float*)d_in[12];
    const float* fc2_b     = (const float*)d_in[13];
    const int*   kptr      = (const int*)d_in[14];
    float* ws  = (float*)d_ws;
    float* out = (float*)d_out;

    float* h     = ws + U_H;
    float* mft   = ws + U_MFT;
    float* xre   = ws + U_XRE;
    float* xim   = ws + U_XIM;
    int*   keepi = (int*)(ws + U_KEEPI);
    float* keepw = ws + U_KEEPW;
    float* xfilt = ws + U_XFILT;
    float* norm  = ws + U_NORM;
    float* qb    = ws + U_Q;
    float* kb    = ws + U_K;
    float* vb    = ws + U_V;
    float* hid   = ws + U_HID;

    dft_naive  <<<dim3(257, 64), 64,  0, stream>>>(x, xre, xim);
    topk_naive <<<dim3(16),      256, 0, stream>>>(xre, xim, keepi, keepw, kptr);
    xfilt_naive<<<dim3(512, 64), 64,  0, stream>>>(x, xre, xim, keepi, keepw, xfilt, norm, kptr);
    qkv_naive  <<<dim3(512, 64), 192, 0, stream>>>(xfilt, norm, in_proj_w, in_proj_b, qb, kb, vb);
    transpose_k<<<dim3(8, 64),   256, 0, stream>>>(x, xfilt, mft, h);
    attn_kernel<<<dim3(32, 64),  256, 0, stream>>>(qb, kb, vb, out_w, out_b, out);
    gemm_k<2>  <<<dim3(2, 64),   256, 0, stream>>>(mft, Wp, bp, h, 512, 1024, gate, 0);
    gemm_k<3>  <<<dim3(4, 64),   256, 0, stream>>>(mft, Wg, bg, h, 512, 1024, gate, 0);
    for (int c4 = 0; c4 < 4; ++c4) {
        gemm_k<1><<<dim3(48, 16), 256, 0, stream>>>(
            h + (size_t)c4 * 1024 * 1024, fc1_w, fc1_b, hid, 1024, 3072, gate, 0);
        gemm_k<4><<<dim3(8, 16),  256, 0, stream>>>(
            hid, fc2_w, fc2_b, out + 2097152, 3072, 0, gate, c4 * 1024);
    }
}

// Round 6
// 1391.109 us; speedup vs baseline: 6.9136x; 1.6849x over previous
//
#include <hip/hip_runtime.h>
#include <math.h>

// B=64, L=512, C=64, E=64, F=257, PRED=512, H1=1024, H2=3072
// ---- workspace layout (f32 units), peak 17,047,552 = 68.19 MB (proven round 3/4) ----
// lifetimes: xre/xim[dft..xfilt] keep[topk..xfilt] xfilt[xfilt..transpose]
//            norm[xfilt..qkv] q/k/v[qkv..attn] mft[transpose..gemm3] h[transpose..cast]
// bf16 stage (after attn; overlays dead front-end buffers):
//   HBF  over xre/xim/q, HIDBF over keep/xfilt/norm/k, W1BF/W2BF over v
#define U_H     0            // [4096][1024]            -> 4194304
#define U_MFT   4194304      // [4096][512]             -> 6291456
#define U_XRE   6291456      // [64][257][64]           -> 7344128
#define U_XIM   7344128      //                         -> 8396800
#define U_KEEPI 8396800      // int[4096*32]            -> 8527872
#define U_KEEPW 8527872      //                         -> 8658944
#define U_XFILT 8658944      // [64][512][64]           -> 10756096
#define U_NORM  10756096     // [64][512][64]           -> 12853248
#define U_Q     6291456      // f32 [64][512][64] over dead xre/xim -> 8388608
#define U_K     12853248     //                         -> 14950400
#define U_V     14950400     //                         -> 17047552  (peak)
#define U_HBF   6291456      // bf16 [4096][1024] = 2097152 u -> 8388608
#define U_HIDBF 8388608      // bf16 [4096][3072] = 6291456 u -> 14680064
#define U_W1BF  14680064     // bf16 [3072][1024] = 1572864 u -> 16252928
#define U_W2BF  16252928     // bf16 [512][3072]  =  786432 u -> 17039360

#define TWO_PI_OVER_512 0.012271846303085129

typedef __attribute__((ext_vector_type(8))) short short8;
typedef __attribute__((ext_vector_type(4))) float floatx4;

__device__ inline unsigned short f2bf(float f) {
    union { unsigned int i; float f; } x; x.f = f;
    unsigned int r = x.i + 0x7fff + ((x.i >> 16) & 1);
    return (unsigned short)(r >> 16);
}

// ===== 1. naive DFT (proven round 3) =====
__global__ __launch_bounds__(64) void dft_naive(const float* __restrict__ x,
                                                float* __restrict__ xre,
                                                float* __restrict__ xim) {
    __shared__ float ct[512], st[512];
    int c = threadIdx.x;
    int f = blockIdx.x;
    int b = blockIdx.y;
    for (int i = c; i < 512; i += 64) {
        float s, cc; sincosf((float)((double)i * TWO_PI_OVER_512), &s, &cc);
        ct[i] = cc; st[i] = s;
    }
    __syncthreads();
    float re = 0.f, im = 0.f;
    for (int t = 0; t < 512; ++t) {
        int idx = (f * t) & 511;
        float v = x[((size_t)b * 512 + t) * 64 + c];
        re += v * ct[idx];
        im -= v * st[idx];
    }
    xre[((size_t)b * 257 + f) * 64 + c] = re;
    xim[((size_t)b * 257 + f) * 64 + c] = im;
}

// ===== 2. naive top-k (proven round 3) =====
__global__ __launch_bounds__(256) void topk_naive(const float* __restrict__ xre,
                                                  const float* __restrict__ xim,
                                                  int* __restrict__ keepi,
                                                  float* __restrict__ keepw,
                                                  const int* __restrict__ kptr) {
    int bc = blockIdx.x * 256 + threadIdx.x;
    int b = bc >> 6, c = bc & 63;
    int kk = *kptr; if (kk > 32) kk = 32;
    float mag[257];
    for (int f = 0; f < 257; ++f) {
        float re = xre[((size_t)b * 257 + f) * 64 + c];
        float im = xim[((size_t)b * 257 + f) * 64 + c];
        mag[f] = sqrtf(re * re + im * im);
    }
    for (int j = 0; j < kk; ++j) {
        float best = -1.f; int bf = 0;
        for (int f = 0; f < 257; ++f)
            if (mag[f] > best) { best = mag[f]; bf = f; }
        keepi[bc * 32 + j] = bf;
        keepw[bc * 32 + j] = (bf == 0 || bf == 256) ? (1.f / 512.f) : (2.f / 512.f);
        mag[bf] = -1.f;
    }
}

// ===== 3. naive x_filt + norm (proven round 3) =====
__global__ __launch_bounds__(64) void xfilt_naive(const float* __restrict__ x,
                                                  const float* __restrict__ xre,
                                                  const float* __restrict__ xim,
                                                  const int* __restrict__ keepi,
                                                  const float* __restrict__ keepw,
                                                  float* __restrict__ xfilt,
                                                  float* __restrict__ norm,
                                                  const int* __restrict__ kptr) {
    __shared__ float ct[512], st[512];
    int c = threadIdx.x;
    int t = blockIdx.x;
    int b = blockIdx.y;
    for (int i = c; i < 512; i += 64) {
        float s, cc; sincosf((float)((double)i * TWO_PI_OVER_512), &s, &cc);
        ct[i] = cc; st[i] = s;
    }
    __syncthreads();
    int kk = *kptr; if (kk > 32) kk = 32;
    int bc = b * 64 + c;
    float acc = 0.f;
    for (int j = 0; j < kk; ++j) {
        int f = keepi[bc * 32 + j];
        float w = keepw[bc * 32 + j];
        float re = xre[((size_t)b * 257 + f) * 64 + c];
        float im = xim[((size_t)b * 257 + f) * 64 + c];
        int idx = (f * t) & 511;
        acc += w * (re * ct[idx] - im * st[idx]);
    }
    size_t a = ((size_t)b * 512 + t) * 64 + c;
    xfilt[a] = acc;
    norm[a] = x[a] - acc;
}

// ===== 4. naive QKV (proven round 3) =====
__global__ __launch_bounds__(192) void qkv_naive(const float* __restrict__ xfilt,
                                                 const float* __restrict__ norm,
                                                 const float* __restrict__ w,
                                                 const float* __restrict__ bias,
                                                 float* __restrict__ q,
                                                 float* __restrict__ kmat,
                                                 float* __restrict__ v) {
    __shared__ float xf[64], nm[64];
    int tid = threadIdx.x;
    int t = blockIdx.x;
    int b = blockIdx.y;
    if (tid < 64) {
        size_t a = ((size_t)b * 512 + t) * 64 + tid;
        xf[tid] = xfilt[a];
        nm[tid] = norm[a];
    }
    __syncthreads();
    int o = tid;
    const float* src = (o < 64) ? xf : nm;
    float acc = bias[o];
    for (int e = 0; e < 64; ++e) acc += w[(size_t)o * 64 + e] * src[e];
    size_t base = ((size_t)b * 512 + t) * 64;
    if (o < 64)       q[base + o] = acc;
    else if (o < 128) kmat[base + o - 64] = acc;
    else              v[base + o - 128] = acc;
}

// ===== 5. transpose (proven round 4) =====
__global__ __launch_bounds__(256) void transpose_k(const float* __restrict__ x,
                                                   const float* __restrict__ xfilt,
                                                   float* __restrict__ mft,
                                                   float* __restrict__ h) {
    __shared__ float t1[64 * 65], t2[64 * 65];
    int tid = threadIdx.x;
    int t0 = blockIdx.x * 64;
    int b = blockIdx.y;
    for (int i = tid; i < 4096; i += 256) {
        int tl = i >> 6, c = i & 63;
        size_t a = ((size_t)(b * 512) + t0 + tl) * 64 + c;
        t1[c * 65 + tl] = xfilt[a];
        t2[c * 65 + tl] = x[a];
    }
    __syncthreads();
    for (int i = tid; i < 4096; i += 256) {
        int c = i >> 6, tl = i & 63;
        mft[((size_t)(b * 64) + c) * 512 + t0 + tl] = t1[c * 65 + tl];
        h[((size_t)(b * 64) + c) * 1024 + 512 + t0 + tl] = t2[c * 65 + tl];
    }
}

// ===== 6. attention + out-proj (proven rounds 0-4) =====
__global__ __launch_bounds__(256) void attn_kernel(const float* __restrict__ q,
                                                   const float* __restrict__ kmat,
                                                   const float* __restrict__ v,
                                                   const float* __restrict__ ow,
                                                   const float* __restrict__ ob,
                                                   float* __restrict__ out) {
    __shared__ float qs[16 * 65];
    __shared__ float kv[64 * 65];
    __shared__ float S[16 * 512];
    __shared__ float Os[16 * 65];
    __shared__ float invl[16];
    int tid = threadIdx.x;
    int b = blockIdx.y;
    int i0 = blockIdx.x * 16;
    int jl = tid & 63, rg = tid >> 6;
    for (int i = tid; i < 1024; i += 256) {
        int r = i >> 6, e = i & 63;
        qs[r * 65 + e] = q[((size_t)(b * 512) + i0 + r) * 64 + e];
    }
    for (int jt = 0; jt < 8; ++jt) {
        __syncthreads();
        for (int i = tid; i < 4096; i += 256) {
            int r = i >> 6, e = i & 63;
            kv[r * 65 + e] = kmat[((size_t)(b * 512) + jt * 64 + r) * 64 + e];
        }
        __syncthreads();
        float a0 = 0, a1 = 0, a2 = 0, a3 = 0;
        for (int e = 0; e < 64; ++e) {
            float kvv = kv[jl * 65 + e];
            a0 += qs[(rg * 4 + 0) * 65 + e] * kvv;
            a1 += qs[(rg * 4 + 1) * 65 + e] * kvv;
            a2 += qs[(rg * 4 + 2) * 65 + e] * kvv;
            a3 += qs[(rg * 4 + 3) * 65 + e] * kvv;
        }
        S[(rg * 4 + 0) * 512 + jt * 64 + jl] = a0 * 0.125f;
        S[(rg * 4 + 1) * 512 + jt * 64 + jl] = a1 * 0.125f;
        S[(rg * 4 + 2) * 512 + jt * 64 + jl] = a2 * 0.125f;
        S[(rg * 4 + 3) * 512 + jt * 64 + jl] = a3 * 0.125f;
    }
    #pragma unroll
    for (int ii = 0; ii < 4; ++ii) {
        int il = rg * 4 + ii;
        float p[8];
        float mx = -1e30f;
        #pragma unroll
        for (int s = 0; s < 8; ++s) { p[s] = S[il * 512 + jl + 64 * s]; mx = fmaxf(mx, p[s]); }
        for (int off = 32; off; off >>= 1) mx = fmaxf(mx, __shfl_xor(mx, off));
        float sum = 0.f;
        #pragma unroll
        for (int s = 0; s < 8; ++s) { p[s] = expf(p[s] - mx); sum += p[s]; S[il * 512 + jl + 64 * s] = p[s]; }
        for (int off = 32; off; off >>= 1) sum += __shfl_xor(sum, off);
        if (jl == 0) invl[il] = 1.0f / sum;
    }
    float o0 = 0, o1 = 0, o2 = 0, o3 = 0;
    for (int jt = 0; jt < 8; ++jt) {
        __syncthreads();
        for (int i = tid; i < 4096; i += 256) {
            int r = i >> 6, e = i & 63;
            kv[r * 65 + e] = v[((size_t)(b * 512) + jt * 64 + r) * 64 + e];
        }
        __syncthreads();
        for (int j2 = 0; j2 < 64; ++j2) {
            float vv = kv[j2 * 65 + jl];
            o0 += S[(rg * 4 + 0) * 512 + jt * 64 + j2] * vv;
            o1 += S[(rg * 4 + 1) * 512 + jt * 64 + j2] * vv;
            o2 += S[(rg * 4 + 2) * 512 + jt * 64 + j2] * vv;
            o3 += S[(rg * 4 + 3) * 512 + jt * 64 + j2] * vv;
        }
    }
    o0 *= invl[rg * 4 + 0]; o1 *= invl[rg * 4 + 1];
    o2 *= invl[rg * 4 + 2]; o3 *= invl[rg * 4 + 3];
    Os[(rg * 4 + 0) * 65 + jl] = o0;
    Os[(rg * 4 + 1) * 65 + jl] = o1;
    Os[(rg * 4 + 2) * 65 + jl] = o2;
    Os[(rg * 4 + 3) * 65 + jl] = o3;
    __syncthreads();
    for (int i = tid; i < 4096; i += 256) {
        int o = i >> 6, e = i & 63;
        kv[e * 65 + o] = ow[i];
    }
    __syncthreads();
    {
        int o = jl;
        float bb = ob[o];
        #pragma unroll
        for (int ii = 0; ii < 4; ++ii) {
            int il = rg * 4 + ii;
            float acc = bb;
            for (int e = 0; e < 64; ++e) acc += Os[il * 65 + e] * kv[e * 65 + o];
            out[((size_t)(b * 512) + i0 + il) * 64 + o] = acc;
        }
    }
}

// ===== 7. tiled fp32 GEMM (proven round 4) — FAN epilogues only =====
template<int EPI>
__global__ __launch_bounds__(256) void gemm_k(const float* __restrict__ A,
                                              const float* __restrict__ W,
                                              const float* __restrict__ bias,
                                              float* __restrict__ C,
                                              int K, int ldc,
                                              const float* __restrict__ gate,
                                              int moff) {
    __shared__ float As[32 * 64];
    __shared__ float Bs[32 * 64];
    int tid = threadIdx.x;
    int tx = tid & 15, ty = tid >> 4;
    int m0 = blockIdx.y * 64, n0 = blockIdx.x * 64;
    float acc[4][4] = {};
    for (int k0 = 0; k0 < K; k0 += 32) {
        __syncthreads();
        #pragma unroll
        for (int s = 0; s < 2; ++s) {
            int i4 = tid + s * 256;
            int row = i4 >> 3, kq = i4 & 7;
            float4 a4 = *(const float4*)&A[(size_t)(m0 + row) * K + k0 + kq * 4];
            float4 w4 = *(const float4*)&W[(size_t)(n0 + row) * K + k0 + kq * 4];
            int kb = kq * 4;
            As[(kb + 0) * 64 + row] = a4.x; As[(kb + 1) * 64 + row] = a4.y;
            As[(kb + 2) * 64 + row] = a4.z; As[(kb + 3) * 64 + row] = a4.w;
            Bs[(kb + 0) * 64 + row] = w4.x; Bs[(kb + 1) * 64 + row] = w4.y;
            Bs[(kb + 2) * 64 + row] = w4.z; Bs[(kb + 3) * 64 + row] = w4.w;
        }
        __syncthreads();
        #pragma unroll
        for (int kk = 0; kk < 32; ++kk) {
            float4 a4 = *(const float4*)&As[kk * 64 + (ty << 2)];
            float4 b4 = *(const float4*)&Bs[kk * 64 + (tx << 2)];
            #pragma unroll
            for (int i = 0; i < 4; ++i)
                #pragma unroll
                for (int j = 0; j < 4; ++j)
                    acc[i][j] += (&a4.x)[i] * (&b4.x)[j];
        }
    }
    int row0 = m0 + ty * 4, col0 = n0 + tx * 4;
    float4 bb = *(const float4*)&bias[col0];
    float gt = 1.f / (1.f + expf(-gate[0]));
    #pragma unroll
    for (int i = 0; i < 4; ++i) {
        int row = row0 + i;
        float v0 = acc[i][0] + bb.x, v1 = acc[i][1] + bb.y;
        float v2 = acc[i][2] + bb.z, v3 = acc[i][3] + bb.w;
        if (EPI == 2) {
            float4 co = make_float4(gt * cosf(v0), gt * cosf(v1), gt * cosf(v2), gt * cosf(v3));
            float4 si = make_float4(gt * sinf(v0), gt * sinf(v1), gt * sinf(v2), gt * sinf(v3));
            *(float4*)&C[(size_t)row * 1024 + col0] = co;
            *(float4*)&C[(size_t)row * 1024 + 128 + col0] = si;
        } else if (EPI == 3) {
            float ig = 1.f - gt;
            float4 o = make_float4(
                ig * 0.5f * v0 * (1.f + erff(v0 * 0.70710678118f)),
                ig * 0.5f * v1 * (1.f + erff(v1 * 0.70710678118f)),
                ig * 0.5f * v2 * (1.f + erff(v2 * 0.70710678118f)),
                ig * 0.5f * v3 * (1.f + erff(v3 * 0.70710678118f)));
            *(float4*)&C[(size_t)row * 1024 + 256 + col0] = o;
        }
    }
}

// ===== 8. cast f32 -> bf16 =====
__global__ __launch_bounds__(256) void cast_bf16(const float* __restrict__ in,
                                                 unsigned short* __restrict__ out, int n4) {
    int i = blockIdx.x * 256 + threadIdx.x;
    if (i < n4) {
        float4 v = *(const float4*)&in[(size_t)i * 4];
        ushort4 o;
        o.x = f2bf(v.x); o.y = f2bf(v.y); o.z = f2bf(v.z); o.w = f2bf(v.w);
        *(ushort4*)&out[(size_t)i * 4] = o;
    }
}

// ===== 9. bf16 MFMA GEMM: C = A[M,K] @ B[N,K]^T, 128x128 tile, BK=64 =====
// 4 waves, each owns a 64x64 quadrant = 4x4 frags of mfma_f32_16x16x32_bf16.
// LDS in fragment order; staged via global_load_lds width-16 (wave-uniform base + lane*16).
// EPI 1: +bias[col], relu, bf16 store to C[row*N+col]   (fc1)
// EPI 2: +bias[row], pred-transpose store (fc2: A=w2 rows=t, B=hid cols=bc)
template<int EPI>
__global__ __launch_bounds__(256) void gemm_mfma(const unsigned short* __restrict__ A,
                                                 const unsigned short* __restrict__ B,
                                                 const float* __restrict__ bias,
                                                 void* __restrict__ Cout,
                                                 int M, int N, int K) {
    __shared__ unsigned short As[8192];   // 16 chunks of 512 ushorts (1KB): id = wm*8 + ks*4 + f
    __shared__ unsigned short Bs[8192];
    int tid = threadIdx.x;
    int l = tid & 63, w = tid >> 6;
    int q = l >> 4, cl = l & 15;
    int wm = w >> 1, wn = w & 1;
    int m0 = blockIdx.y * 128, n0 = blockIdx.x * 128;
    floatx4 acc[4][4];
    #pragma unroll
    for (int i = 0; i < 4; ++i)
        #pragma unroll
        for (int j = 0; j < 4; ++j)
            acc[i][j] = (floatx4){0.f, 0.f, 0.f, 0.f};

    for (int k0 = 0; k0 < K; k0 += 64) {
        __syncthreads();
        #pragma unroll
        for (int ci = 0; ci < 8; ++ci) {
            int cid = w * 8 + ci;              // 0..15 A-chunks, 16..31 B-chunks
            int isB = cid >> 4;
            int c = cid & 15;
            int cq = c >> 3, cks = (c >> 2) & 1, cf = c & 3;
            int row = cq * 64 + cf * 16 + cl;  // this lane's source row
            int col = k0 + cks * 32 + q * 8;   // 8 bf16 = 16 B along K
            const unsigned short* gp = isB ? (B + (size_t)(n0 + row) * K + col)
                                           : (A + (size_t)(m0 + row) * K + col);
            unsigned short* lp = (isB ? Bs : As) + c * 512;
            __builtin_amdgcn_global_load_lds((const __attribute__((address_space(1))) void*)gp,
                                             (__attribute__((address_space(3))) void*)lp,
                                             16, 0, 0);
        }
        __syncthreads();   // compiler emits vmcnt(0) drain before barrier (m97 structure)
        #pragma unroll
        for (int ks = 0; ks < 2; ++ks) {
            short8 af[4], bg[4];
            #pragma unroll
            for (int f = 0; f < 4; ++f) {
                af[f] = *(short8*)&As[(wm * 8 + ks * 4 + f) * 512 + l * 8];
                bg[f] = *(short8*)&Bs[(wn * 8 + ks * 4 + f) * 512 + l * 8];
            }
            #pragma unroll
            for (int i = 0; i < 4; ++i)
                #pragma unroll
                for (int j = 0; j < 4; ++j)
                    acc[i][j] = __builtin_amdgcn_mfma_f32_16x16x32_bf16(af[i], bg[j], acc[i][j], 0, 0, 0);
        }
    }

    // epilogue: C/D layout col=lane&15, row=quad*4+reg (m89-verified)
    if (EPI == 1) {
        unsigned short* Cb = (unsigned short*)Cout;
        #pragma unroll
        for (int j = 0; j < 4; ++j) {
            int col = n0 + wn * 64 + j * 16 + cl;
            float bb = bias[col];
            #pragma unroll
            for (int i = 0; i < 4; ++i) {
                int rowb = m0 + wm * 64 + i * 16 + q * 4;
                #pragma unroll
                for (int r = 0; r < 4; ++r) {
                    float v = acc[i][j][r] + bb;
                    Cb[(size_t)(rowb + r) * N + col] = f2bf(fmaxf(v, 0.f));
                }
            }
        }
    } else {
        // rows = pred t (M=512), cols = bc (N=4096); out[(b*512+t)*64 + c]
        float* Ob = (float*)Cout;
        int bidx = (n0 >> 6) + wn;
        #pragma unroll
        for (int i = 0; i < 4; ++i) {
            #pragma unroll
            for (int r = 0; r < 4; ++r) {
                int t = m0 + wm * 64 + i * 16 + q * 4 + r;
                float bb = bias[t];
                #pragma unroll
                for (int j = 0; j < 4; ++j) {
                    int c = j * 16 + cl;
                    Ob[((size_t)bidx * 512 + t) * 64 + c] = acc[i][j][r] + bb;
                }
            }
        }
    }
}

extern "C" void kernel_launch(void* const* d_in, const int* in_sizes, int n_in,
                              void* d_out, int out_size, void* d_ws, size_t ws_size,
                              hipStream_t stream) {
    const float* x         = (const float*)d_in[0];
    const float* in_proj_w = (const float*)d_in[1];
    const float* in_proj_b = (const float*)d_in[2];
    const float* out_w     = (const float*)d_in[3];
    const float* out_b     = (const float*)d_in[4];
    const float* Wp        = (const float*)d_in[5];
    const float* bp        = (const float*)d_in[6];
    const float* Wg        = (const float*)d_in[7];
    const float* bg        = (const float*)d_in[8];
    const float* gate      = (const float*)d_in[9];
    const float* fc1_w     = (const float*)d_in[10];
    const float* fc1_b     = (const float*)d_in[11];
    const float* fc2_w     = (const float*)d_in[12];
    const float* fc2_b     = (const float*)d_in[13];
    const int*   kptr      = (const int*)d_in[14];
    float* ws  = (float*)d_ws;
    float* out = (float*)d_out;

    float* h     = ws + U_H;
    float* mft   = ws + U_MFT;
    float* xre   = ws + U_XRE;
    float* xim   = ws + U_XIM;
    int*   keepi = (int*)(ws + U_KEEPI);
    float* keepw = ws + U_KEEPW;
    float* xfilt = ws + U_XFILT;
    float* norm  = ws + U_NORM;
    float* qb    = ws + U_Q;
    float* kb    = ws + U_K;
    float* vb    = ws + U_V;
    unsigned short* hbf   = (unsigned short*)(ws + U_HBF);
    unsigned short* hidbf = (unsigned short*)(ws + U_HIDBF);
    unsigned short* w1bf  = (unsigned short*)(ws + U_W1BF);
    unsigned short* w2bf  = (unsigned short*)(ws + U_W2BF);

    dft_naive  <<<dim3(257, 64), 64,  0, stream>>>(x, xre, xim);
    topk_naive <<<dim3(16),      256, 0, stream>>>(xre, xim, keepi, keepw, kptr);
    xfilt_naive<<<dim3(512, 64), 64,  0, stream>>>(x, xre, xim, keepi, keepw, xfilt, norm, kptr);
    qkv_naive  <<<dim3(512, 64), 192, 0, stream>>>(xfilt, norm, in_proj_w, in_proj_b, qb, kb, vb);
    transpose_k<<<dim3(8, 64),   256, 0, stream>>>(x, xfilt, mft, h);
    attn_kernel<<<dim3(32, 64),  256, 0, stream>>>(qb, kb, vb, out_w, out_b, out);
    gemm_k<2>  <<<dim3(2, 64),   256, 0, stream>>>(mft, Wp, bp, h, 512, 1024, gate, 0);
    gemm_k<3>  <<<dim3(4, 64),   256, 0, stream>>>(mft, Wg, bg, h, 512, 1024, gate, 0);
    // bf16 stage (after attn: overlays dead q/k/v/xre/xim/keep/xfilt/norm)
    cast_bf16<<<4096, 256, 0, stream>>>(h,     hbf,  1048576);
    cast_bf16<<<3072, 256, 0, stream>>>(fc1_w, w1bf, 786432);
    cast_bf16<<<1536, 256, 0, stream>>>(fc2_w, w2bf, 393216);   // FIX: 1,572,864 floats = 393,216 float4s (was 131072 -> 2/3 of w2bf stale junk -> NaN)
    gemm_mfma<1><<<dim3(24, 32), 256, 0, stream>>>(hbf,  w1bf,  fc1_b, hidbf,          4096, 3072, 1024);
    gemm_mfma<2><<<dim3(32, 4),  256, 0, stream>>>(w2bf, hidbf, fc2_b, out + 2097152,  512,  4096, 3072);
}

// Round 7
// 1129.493 us; speedup vs baseline: 8.5150x; 1.2316x over previous
//
#include <hip/hip_runtime.h>
#include <math.h>

// B=64, L=512, C=64, E=64, F=257, PRED=512, H1=1024, H2=3072
// ---- workspace layout (f32 units), peak 17,047,552 = 68.19 MB (proven) ----
#define U_H     0            // [4096][1024]            -> 4194304
#define U_MFT   4194304      // [4096][512]             -> 6291456
#define U_XRE   6291456      // [64][257][64]           -> 7344128
#define U_XIM   7344128      //                         -> 8396800
#define U_KEEPI 8396800      // int[4096*32]            -> 8527872
#define U_KEEPW 8527872      //                         -> 8658944
#define U_XFILT 8658944      // [64][512][64]           -> 10756096
#define U_NORM  10756096     // [64][512][64]           -> 12853248
#define U_Q     6291456      // f32 [64][512][64] over dead xre/xim -> 8388608
#define U_K     12853248     //                         -> 14950400
#define U_V     14950400     //                         -> 17047552  (peak)
#define U_HBF   6291456      // bf16 [4096][1024] = 2097152 u -> 8388608
#define U_HIDBF 8388608      // bf16 [4096][3072] = 6291456 u -> 14680064
#define U_W1BF  14680064     // bf16 [3072][1024] = 1572864 u -> 16252928
#define U_W2BF  16252928     // bf16 [512][3072]  =  786432 u -> 17039360

#define TWO_PI_OVER_512 0.012271846303085129

typedef __attribute__((ext_vector_type(8))) short short8;
typedef __attribute__((ext_vector_type(4))) float floatx4;

__device__ inline unsigned short f2bf(float f) {
    union { unsigned int i; float f; } x; x.f = f;
    unsigned int r = x.i + 0x7fff + ((x.i >> 16) & 1);
    return (unsigned short)(r >> 16);
}

// ===== 1. tiled DFT: block = (64-freq tile, b), 256 thr; thread = 8 f x 2 c =====
// Wave holds 2 distinct ct/st addresses per read step -> broadcast, conflict-free.
__global__ __launch_bounds__(256) void dft_tile(const float* __restrict__ x,
                                                float* __restrict__ xre,
                                                float* __restrict__ xim) {
    __shared__ float xs[64 * 64];          // [t-local][c], staged per t-tile
    __shared__ float ct[512], st[512];
    int tid = threadIdx.x;
    int b = blockIdx.y;
    int f0 = blockIdx.x * 64;
    for (int i = tid; i < 512; i += 256) {
        float s, c; sincosf((float)((double)i * TWO_PI_OVER_512), &s, &c);
        ct[i] = c; st[i] = s;
    }
    int c2 = (tid & 31) * 2;               // two consecutive channels
    int fg = tid >> 5;                     // 0..7
    int fb = f0 + fg * 8;                  // 8 consecutive freqs per thread
    float2 ar[8], ai[8];
    #pragma unroll
    for (int i = 0; i < 8; ++i) { ar[i] = make_float2(0.f, 0.f); ai[i] = make_float2(0.f, 0.f); }
    for (int t0 = 0; t0 < 512; t0 += 64) {
        __syncthreads();
        for (int i = tid; i < 4096; i += 256)
            xs[i] = x[(size_t)(b * 512 + t0) * 64 + i];   // coalesced
        __syncthreads();
        for (int tt = 0; tt < 64; ++tt) {
            float2 xv = *(float2*)&xs[tt * 64 + c2];
            int t = t0 + tt;
            int idx = (fb * t) & 511;
            #pragma unroll
            for (int i = 0; i < 8; ++i) {
                float cv = ct[idx], sv = st[idx];
                ar[i].x += xv.x * cv; ar[i].y += xv.y * cv;
                ai[i].x -= xv.x * sv; ai[i].y -= xv.y * sv;
                idx = (idx + t) & 511;
            }
        }
    }
    #pragma unroll
    for (int i = 0; i < 8; ++i) {
        int f = fb + i;
        if (f < 257) {
            *(float2*)&xre[((size_t)(b * 257) + f) * 64 + c2] = ar[i];
            *(float2*)&xim[((size_t)(b * 257) + f) * 64 + c2] = ai[i];
        }
    }
}

// ===== 2. naive top-k (proven round 3) =====
__global__ __launch_bounds__(256) void topk_naive(const float* __restrict__ xre,
                                                  const float* __restrict__ xim,
                                                  int* __restrict__ keepi,
                                                  float* __restrict__ keepw,
                                                  const int* __restrict__ kptr) {
    int bc = blockIdx.x * 256 + threadIdx.x;
    int b = bc >> 6, c = bc & 63;
    int kk = *kptr; if (kk > 32) kk = 32;
    float mag[257];
    for (int f = 0; f < 257; ++f) {
        float re = xre[((size_t)b * 257 + f) * 64 + c];
        float im = xim[((size_t)b * 257 + f) * 64 + c];
        mag[f] = sqrtf(re * re + im * im);
    }
    for (int j = 0; j < kk; ++j) {
        float best = -1.f; int bf = 0;
        for (int f = 0; f < 257; ++f)
            if (mag[f] > best) { best = mag[f]; bf = f; }
        keepi[bc * 32 + j] = bf;
        keepw[bc * 32 + j] = (bf == 0 || bf == 256) ? (1.f / 512.f) : (2.f / 512.f);
        mag[bf] = -1.f;
    }
}

// ===== 3. fused x_filt: reconstruction + norm + mft + h-xt transpose =====
// Block = (64-t tile, b). Phase 1: lanes = t, c wave-uniform -> keep-list reads
// broadcast; ct/st gathers stride-f (mostly conflict-free). Phase 2: LDS-transposed
// coalesced writes (absorbs old transpose_k).
__global__ __launch_bounds__(256) void xfilt_fused(const float* __restrict__ x,
                                                   const float* __restrict__ xre,
                                                   const float* __restrict__ xim,
                                                   const int* __restrict__ keepi,
                                                   const float* __restrict__ keepw,
                                                   float* __restrict__ xfilt,
                                                   float* __restrict__ norm,
                                                   float* __restrict__ mft,
                                                   float* __restrict__ h,
                                                   const int* __restrict__ kptr) {
    __shared__ float ct[512], st[512];
    __shared__ int   kf[64 * 33];
    __shared__ float kre[64 * 33], kim[64 * 33];
    __shared__ float xs[64 * 65];          // [t-local][c]
    __shared__ float ft[64 * 65];          // [c][t-local]
    int tid = threadIdx.x;
    int b = blockIdx.y;
    int t0 = blockIdx.x * 64;
    int kk = *kptr; if (kk > 32) kk = 32;
    for (int i = tid; i < 512; i += 256) {
        float s, c; sincosf((float)((double)i * TWO_PI_OVER_512), &s, &c);
        ct[i] = c; st[i] = s;
    }
    // stage x tile (coalesced)
    for (int i = tid; i < 4096; i += 256) {
        int tl = i >> 6, c = i & 63;
        xs[tl * 65 + c] = x[((size_t)(b * 512) + t0 + tl) * 64 + c];
    }
    // keep-lists: premultiply w into re/im
    for (int e = tid; e < 64 * kk; e += 256) {
        int c = e / kk, j = e - c * kk;
        int bc = b * 64 + c;
        int f = keepi[bc * 32 + j];
        float w = keepw[bc * 32 + j];
        size_t a = ((size_t)(b * 257) + f) * 64 + c;
        kf[c * 33 + j]  = f;
        kre[c * 33 + j] = w * xre[a];
        kim[c * 33 + j] = w * xim[a];
    }
    __syncthreads();
    // phase 1: lane l = t-local, c = w*16 + ci (wave-uniform)
    int l = tid & 63, w = tid >> 6;
    int t = t0 + l;
    for (int ci = 0; ci < 16; ++ci) {
        int c = w * 16 + ci;
        float acc = 0.f;
        for (int j = 0; j < kk; ++j) {
            int f = kf[c * 33 + j];                  // broadcast
            int idx = (f * t) & 511;                 // stride-f over lanes
            acc += kre[c * 33 + j] * ct[idx] - kim[c * 33 + j] * st[idx];
        }
        ft[c * 65 + l] = acc;
    }
    __syncthreads();
    // phase 2: coalesced writes
    for (int i = tid; i < 4096; i += 256) {
        int tl = i >> 6, c = i & 63;
        float v = ft[c * 65 + tl];
        size_t a = ((size_t)(b * 512) + t0 + tl) * 64 + c;
        xfilt[a] = v;
        norm[a]  = xs[tl * 65 + c] - v;
    }
    for (int i = tid; i < 4096; i += 256) {
        int cr = i >> 6, tl = i & 63;
        mft[((size_t)(b * 64) + cr) * 512 + t0 + tl] = ft[cr * 65 + tl];
        h[((size_t)(b * 64) + cr) * 1024 + 512 + t0 + tl] = xs[tl * 65 + cr];
    }
}

// ===== 4. naive QKV (proven round 3) =====
__global__ __launch_bounds__(192) void qkv_naive(const float* __restrict__ xfilt,
                                                 const float* __restrict__ norm,
                                                 const float* __restrict__ w,
                                                 const float* __restrict__ bias,
                                                 float* __restrict__ q,
                                                 float* __restrict__ kmat,
                                                 float* __restrict__ v) {
    __shared__ float xf[64], nm[64];
    int tid = threadIdx.x;
    int t = blockIdx.x;
    int b = blockIdx.y;
    if (tid < 64) {
        size_t a = ((size_t)b * 512 + t) * 64 + tid;
        xf[tid] = xfilt[a];
        nm[tid] = norm[a];
    }
    __syncthreads();
    int o = tid;
    const float* src = (o < 64) ? xf : nm;
    float acc = bias[o];
    for (int e = 0; e < 64; ++e) acc += w[(size_t)o * 64 + e] * src[e];
    size_t base = ((size_t)b * 512 + t) * 64;
    if (o < 64)       q[base + o] = acc;
    else if (o < 128) kmat[base + o - 64] = acc;
    else              v[base + o - 128] = acc;
}

// ===== 5. attention + out-proj (proven rounds 0-6) =====
__global__ __launch_bounds__(256) void attn_kernel(const float* __restrict__ q,
                                                   const float* __restrict__ kmat,
                                                   const float* __restrict__ v,
                                                   const float* __restrict__ ow,
                                                   const float* __restrict__ ob,
                                                   float* __restrict__ out) {
    __shared__ float qs[16 * 65];
    __shared__ float kv[64 * 65];
    __shared__ float S[16 * 512];
    __shared__ float Os[16 * 65];
    __shared__ float invl[16];
    int tid = threadIdx.x;
    int b = blockIdx.y;
    int i0 = blockIdx.x * 16;
    int jl = tid & 63, rg = tid >> 6;
    for (int i = tid; i < 1024; i += 256) {
        int r = i >> 6, e = i & 63;
        qs[r * 65 + e] = q[((size_t)(b * 512) + i0 + r) * 64 + e];
    }
    for (int jt = 0; jt < 8; ++jt) {
        __syncthreads();
        for (int i = tid; i < 4096; i += 256) {
            int r = i >> 6, e = i & 63;
            kv[r * 65 + e] = kmat[((size_t)(b * 512) + jt * 64 + r) * 64 + e];
        }
        __syncthreads();
        float a0 = 0, a1 = 0, a2 = 0, a3 = 0;
        for (int e = 0; e < 64; ++e) {
            float kvv = kv[jl * 65 + e];
            a0 += qs[(rg * 4 + 0) * 65 + e] * kvv;
            a1 += qs[(rg * 4 + 1) * 65 + e] * kvv;
            a2 += qs[(rg * 4 + 2) * 65 + e] * kvv;
            a3 += qs[(rg * 4 + 3) * 65 + e] * kvv;
        }
        S[(rg * 4 + 0) * 512 + jt * 64 + jl] = a0 * 0.125f;
        S[(rg * 4 + 1) * 512 + jt * 64 + jl] = a1 * 0.125f;
        S[(rg * 4 + 2) * 512 + jt * 64 + jl] = a2 * 0.125f;
        S[(rg * 4 + 3) * 512 + jt * 64 + jl] = a3 * 0.125f;
    }
    #pragma unroll
    for (int ii = 0; ii < 4; ++ii) {
        int il = rg * 4 + ii;
        float p[8];
        float mx = -1e30f;
        #pragma unroll
        for (int s = 0; s < 8; ++s) { p[s] = S[il * 512 + jl + 64 * s]; mx = fmaxf(mx, p[s]); }
        for (int off = 32; off; off >>= 1) mx = fmaxf(mx, __shfl_xor(mx, off));
        float sum = 0.f;
        #pragma unroll
        for (int s = 0; s < 8; ++s) { p[s] = expf(p[s] - mx); sum += p[s]; S[il * 512 + jl + 64 * s] = p[s]; }
        for (int off = 32; off; off >>= 1) sum += __shfl_xor(sum, off);
        if (jl == 0) invl[il] = 1.0f / sum;
    }
    float o0 = 0, o1 = 0, o2 = 0, o3 = 0;
    for (int jt = 0; jt < 8; ++jt) {
        __syncthreads();
        for (int i = tid; i < 4096; i += 256) {
            int r = i >> 6, e = i & 63;
            kv[r * 65 + e] = v[((size_t)(b * 512) + jt * 64 + r) * 64 + e];
        }
        __syncthreads();
        for (int j2 = 0; j2 < 64; ++j2) {
            float vv = kv[j2 * 65 + jl];
            o0 += S[(rg * 4 + 0) * 512 + jt * 64 + j2] * vv;
            o1 += S[(rg * 4 + 1) * 512 + jt * 64 + j2] * vv;
            o2 += S[(rg * 4 + 2) * 512 + jt * 64 + j2] * vv;
            o3 += S[(rg * 4 + 3) * 512 + jt * 64 + j2] * vv;
        }
    }
    o0 *= invl[rg * 4 + 0]; o1 *= invl[rg * 4 + 1];
    o2 *= invl[rg * 4 + 2]; o3 *= invl[rg * 4 + 3];
    Os[(rg * 4 + 0) * 65 + jl] = o0;
    Os[(rg * 4 + 1) * 65 + jl] = o1;
    Os[(rg * 4 + 2) * 65 + jl] = o2;
    Os[(rg * 4 + 3) * 65 + jl] = o3;
    __syncthreads();
    for (int i = tid; i < 4096; i += 256) {
        int o = i >> 6, e = i & 63;
        kv[e * 65 + o] = ow[i];
    }
    __syncthreads();
    {
        int o = jl;
        float bb = ob[o];
        #pragma unroll
        for (int ii = 0; ii < 4; ++ii) {
            int il = rg * 4 + ii;
            float acc = bb;
            for (int e = 0; e < 64; ++e) acc += Os[il * 65 + e] * kv[e * 65 + o];
            out[((size_t)(b * 512) + i0 + il) * 64 + o] = acc;
        }
    }
}

// ===== 6. tiled fp32 GEMM (proven round 4) — FAN epilogues only =====
template<int EPI>
__global__ __launch_bounds__(256) void gemm_k(const float* __restrict__ A,
                                              const float* __restrict__ W,
                                              const float* __restrict__ bias,
                                              float* __restrict__ C,
                                              int K, int ldc,
                                              const float* __restrict__ gate,
                                              int moff) {
    __shared__ float As[32 * 64];
    __shared__ float Bs[32 * 64];
    int tid = threadIdx.x;
    int tx = tid & 15, ty = tid >> 4;
    int m0 = blockIdx.y * 64, n0 = blockIdx.x * 64;
    float acc[4][4] = {};
    for (int k0 = 0; k0 < K; k0 += 32) {
        __syncthreads();
        #pragma unroll
        for (int s = 0; s < 2; ++s) {
            int i4 = tid + s * 256;
            int row = i4 >> 3, kq = i4 & 7;
            float4 a4 = *(const float4*)&A[(size_t)(m0 + row) * K + k0 + kq * 4];
            float4 w4 = *(const float4*)&W[(size_t)(n0 + row) * K + k0 + kq * 4];
            int kb = kq * 4;
            As[(kb + 0) * 64 + row] = a4.x; As[(kb + 1) * 64 + row] = a4.y;
            As[(kb + 2) * 64 + row] = a4.z; As[(kb + 3) * 64 + row] = a4.w;
            Bs[(kb + 0) * 64 + row] = w4.x; Bs[(kb + 1) * 64 + row] = w4.y;
            Bs[(kb + 2) * 64 + row] = w4.z; Bs[(kb + 3) * 64 + row] = w4.w;
        }
        __syncthreads();
        #pragma unroll
        for (int kk = 0; kk < 32; ++kk) {
            float4 a4 = *(const float4*)&As[kk * 64 + (ty << 2)];
            float4 b4 = *(const float4*)&Bs[kk * 64 + (tx << 2)];
            #pragma unroll
            for (int i = 0; i < 4; ++i)
                #pragma unroll
                for (int j = 0; j < 4; ++j)
                    acc[i][j] += (&a4.x)[i] * (&b4.x)[j];
        }
    }
    int row0 = m0 + ty * 4, col0 = n0 + tx * 4;
    float4 bb = *(const float4*)&bias[col0];
    float gt = 1.f / (1.f + expf(-gate[0]));
    #pragma unroll
    for (int i = 0; i < 4; ++i) {
        int row = row0 + i;
        float v0 = acc[i][0] + bb.x, v1 = acc[i][1] + bb.y;
        float v2 = acc[i][2] + bb.z, v3 = acc[i][3] + bb.w;
        if (EPI == 2) {
            float4 co = make_float4(gt * cosf(v0), gt * cosf(v1), gt * cosf(v2), gt * cosf(v3));
            float4 si = make_float4(gt * sinf(v0), gt * sinf(v1), gt * sinf(v2), gt * sinf(v3));
            *(float4*)&C[(size_t)row * 1024 + col0] = co;
            *(float4*)&C[(size_t)row * 1024 + 128 + col0] = si;
        } else if (EPI == 3) {
            float ig = 1.f - gt;
            float4 o = make_float4(
                ig * 0.5f * v0 * (1.f + erff(v0 * 0.70710678118f)),
                ig * 0.5f * v1 * (1.f + erff(v1 * 0.70710678118f)),
                ig * 0.5f * v2 * (1.f + erff(v2 * 0.70710678118f)),
                ig * 0.5f * v3 * (1.f + erff(v3 * 0.70710678118f)));
            *(float4*)&C[(size_t)row * 1024 + 256 + col0] = o;
        }
    }
}

// ===== 7. cast f32 -> bf16 =====
__global__ __launch_bounds__(256) void cast_bf16(const float* __restrict__ in,
                                                 unsigned short* __restrict__ out, int n4) {
    int i = blockIdx.x * 256 + threadIdx.x;
    if (i < n4) {
        float4 v = *(const float4*)&in[(size_t)i * 4];
        ushort4 o;
        o.x = f2bf(v.x); o.y = f2bf(v.y); o.z = f2bf(v.z); o.w = f2bf(v.w);
        *(ushort4*)&out[(size_t)i * 4] = o;
    }
}

// ===== 8. bf16 MFMA GEMM (proven round 6): C = A[M,K] @ B[N,K]^T, 128x128, BK=64 =====
template<int EPI>
__global__ __launch_bounds__(256) void gemm_mfma(const unsigned short* __restrict__ A,
                                                 const unsigned short* __restrict__ B,
                                                 const float* __restrict__ bias,
                                                 void* __restrict__ Cout,
                                                 int M, int N, int K) {
    __shared__ unsigned short As[8192];
    __shared__ unsigned short Bs[8192];
    int tid = threadIdx.x;
    int l = tid & 63, w = tid >> 6;
    int q = l >> 4, cl = l & 15;
    int wm = w >> 1, wn = w & 1;
    int m0 = blockIdx.y * 128, n0 = blockIdx.x * 128;
    floatx4 acc[4][4];
    #pragma unroll
    for (int i = 0; i < 4; ++i)
        #pragma unroll
        for (int j = 0; j < 4; ++j)
            acc[i][j] = (floatx4){0.f, 0.f, 0.f, 0.f};

    for (int k0 = 0; k0 < K; k0 += 64) {
        __syncthreads();
        #pragma unroll
        for (int ci = 0; ci < 8; ++ci) {
            int cid = w * 8 + ci;
            int isB = cid >> 4;
            int c = cid & 15;
            int cq = c >> 3, cks = (c >> 2) & 1, cf = c & 3;
            int row = cq * 64 + cf * 16 + cl;
            int col = k0 + cks * 32 + q * 8;
            const unsigned short* gp = isB ? (B + (size_t)(n0 + row) * K + col)
                                           : (A + (size_t)(m0 + row) * K + col);
            unsigned short* lp = (isB ? Bs : As) + c * 512;
            __builtin_amdgcn_global_load_lds((const __attribute__((address_space(1))) void*)gp,
                                             (__attribute__((address_space(3))) void*)lp,
                                             16, 0, 0);
        }
        __syncthreads();
        #pragma unroll
        for (int ks = 0; ks < 2; ++ks) {
            short8 af[4], bg[4];
            #pragma unroll
            for (int f = 0; f < 4; ++f) {
                af[f] = *(short8*)&As[(wm * 8 + ks * 4 + f) * 512 + l * 8];
                bg[f] = *(short8*)&Bs[(wn * 8 + ks * 4 + f) * 512 + l * 8];
            }
            #pragma unroll
            for (int i = 0; i < 4; ++i)
                #pragma unroll
                for (int j = 0; j < 4; ++j)
                    acc[i][j] = __builtin_amdgcn_mfma_f32_16x16x32_bf16(af[i], bg[j], acc[i][j], 0, 0, 0);
        }
    }

    if (EPI == 1) {
        unsigned short* Cb = (unsigned short*)Cout;
        #pragma unroll
        for (int j = 0; j < 4; ++j) {
            int col = n0 + wn * 64 + j * 16 + cl;
            float bb = bias[col];
            #pragma unroll
            for (int i = 0; i < 4; ++i) {
                int rowb = m0 + wm * 64 + i * 16 + q * 4;
                #pragma unroll
                for (int r = 0; r < 4; ++r) {
                    float v = acc[i][j][r] + bb;
                    Cb[(size_t)(rowb + r) * N + col] = f2bf(fmaxf(v, 0.f));
                }
            }
        }
    } else {
        float* Ob = (float*)Cout;
        int bidx = (n0 >> 6) + wn;
        #pragma unroll
        for (int i = 0; i < 4; ++i) {
            #pragma unroll
            for (int r = 0; r < 4; ++r) {
                int t = m0 + wm * 64 + i * 16 + q * 4 + r;
                float bb = bias[t];
                #pragma unroll
                for (int j = 0; j < 4; ++j) {
                    int c = j * 16 + cl;
                    Ob[((size_t)bidx * 512 + t) * 64 + c] = acc[i][j][r] + bb;
                }
            }
        }
    }
}

extern "C" void kernel_launch(void* const* d_in, const int* in_sizes, int n_in,
                              void* d_out, int out_size, void* d_ws, size_t ws_size,
                              hipStream_t stream) {
    const float* x         = (const float*)d_in[0];
    const float* in_proj_w = (const float*)d_in[1];
    const float* in_proj_b = (const float*)d_in[2];
    const float* out_w     = (const float*)d_in[3];
    const float* out_b     = (const float*)d_in[4];
    const float* Wp        = (const float*)d_in[5];
    const float* bp        = (const float*)d_in[6];
    const float* Wg        = (const float*)d_in[7];
    const float* bg        = (const float*)d_in[8];
    const float* gate      = (const float*)d_in[9];
    const float* fc1_w     = (const float*)d_in[10];
    const float* fc1_b     = (const float*)d_in[11];
    const float* fc2_w     = (const float*)d_in[12];
    const float* fc2_b     = (const float*)d_in[13];
    const int*   kptr      = (const int*)d_in[14];
    float* ws  = (float*)d_ws;
    float* out = (float*)d_out;

    float* h     = ws + U_H;
    float* mft   = ws + U_MFT;
    float* xre   = ws + U_XRE;
    float* xim   = ws + U_XIM;
    int*   keepi = (int*)(ws + U_KEEPI);
    float* keepw = ws + U_KEEPW;
    float* xfilt = ws + U_XFILT;
    float* norm  = ws + U_NORM;
    float* qb    = ws + U_Q;
    float* kb    = ws + U_K;
    float* vb    = ws + U_V;
    unsigned short* hbf   = (unsigned short*)(ws + U_HBF);
    unsigned short* hidbf = (unsigned short*)(ws + U_HIDBF);
    unsigned short* w1bf  = (unsigned short*)(ws + U_W1BF);
    unsigned short* w2bf  = (unsigned short*)(ws + U_W2BF);

    dft_tile   <<<dim3(5, 64),   256, 0, stream>>>(x, xre, xim);
    topk_naive <<<dim3(16),      256, 0, stream>>>(xre, xim, keepi, keepw, kptr);
    xfilt_fused<<<dim3(8, 64),   256, 0, stream>>>(x, xre, xim, keepi, keepw, xfilt, norm, mft, h, kptr);
    qkv_naive  <<<dim3(512, 64), 192, 0, stream>>>(xfilt, norm, in_proj_w, in_proj_b, qb, kb, vb);
    attn_kernel<<<dim3(32, 64),  256, 0, stream>>>(qb, kb, vb, out_w, out_b, out);
    gemm_k<2>  <<<dim3(2, 64),   256, 0, stream>>>(mft, Wp, bp, h, 512, 1024, gate, 0);
    gemm_k<3>  <<<dim3(4, 64),   256, 0, stream>>>(mft, Wg, bg, h, 512, 1024, gate, 0);
    cast_bf16<<<4096, 256, 0, stream>>>(h,     hbf,  1048576);
    cast_bf16<<<3072, 256, 0, stream>>>(fc1_w, w1bf, 786432);
    cast_bf16<<<1536, 256, 0, stream>>>(fc2_w, w2bf, 393216);
    gemm_mfma<1><<<dim3(24, 32), 256, 0, stream>>>(hbf,  w1bf,  fc1_b, hidbf,          4096, 3072, 1024);
    gemm_mfma<2><<<dim3(32, 4),  256, 0, stream>>>(w2bf, hidbf, fc2_b, out + 2097152,  512,  4096, 3072);
}

// Round 9
// 939.194 us; speedup vs baseline: 10.2402x; 1.2026x over previous
//
#include <hip/hip_runtime.h>
#include <math.h>

// B=64, L=512, C=64, E=64, F=257, PRED=512, H1=1024, H2=3072
// ---- workspace layout (f32 units), peak 17,047,552 = 68.19 MB (proven) ----
#define U_H     0            // [4096][1024]            -> 4194304
#define U_MFT   4194304      // [4096][512]             -> 6291456
#define U_XRE   6291456      // [64][257][64]           -> 7344128
#define U_XIM   7344128      //                         -> 8396800
#define U_KEEPI 8396800      // int[4096*32]            -> 8527872
#define U_KEEPW 8527872      //                         -> 8658944
#define U_XFILT 8658944      // [64][512][64]           -> 10756096
#define U_NORM  10756096     // [64][512][64]           -> 12853248
#define U_Q     6291456      // f32 [64][512][64] over dead xre/xim -> 8388608
#define U_K     12853248     //                         -> 14950400
#define U_V     14950400     //                         -> 17047552  (peak)
#define U_HBF   6291456      // bf16 [4096][1024] = 2097152 u -> 8388608
#define U_HIDBF 8388608      // bf16 [4096][3072] = 6291456 u -> 14680064
#define U_W1BF  14680064     // bf16 [3072][1024] = 1572864 u -> 16252928
#define U_W2BF  16252928     // bf16 [512][3072]  =  786432 u -> 17039360

#define TWO_PI_OVER_512 0.012271846303085129

typedef __attribute__((ext_vector_type(8))) short short8;
typedef __attribute__((ext_vector_type(4))) float floatx4;

__device__ inline unsigned short f2bf(float f) {
    union { unsigned int i; float f; } x; x.f = f;
    unsigned int r = x.i + 0x7fff + ((x.i >> 16) & 1);
    return (unsigned short)(r >> 16);
}

// ===== 1. tiled DFT (proven round 7) =====
__global__ __launch_bounds__(256) void dft_tile(const float* __restrict__ x,
                                                float* __restrict__ xre,
                                                float* __restrict__ xim) {
    __shared__ float xs[64 * 64];
    __shared__ float ct[512], st[512];
    int tid = threadIdx.x;
    int b = blockIdx.y;
    int f0 = blockIdx.x * 64;
    for (int i = tid; i < 512; i += 256) {
        float s, c; sincosf((float)((double)i * TWO_PI_OVER_512), &s, &c);
        ct[i] = c; st[i] = s;
    }
    int c2 = (tid & 31) * 2;
    int fg = tid >> 5;
    int fb = f0 + fg * 8;
    float2 ar[8], ai[8];
    #pragma unroll
    for (int i = 0; i < 8; ++i) { ar[i] = make_float2(0.f, 0.f); ai[i] = make_float2(0.f, 0.f); }
    for (int t0 = 0; t0 < 512; t0 += 64) {
        __syncthreads();
        for (int i = tid; i < 4096; i += 256)
            xs[i] = x[(size_t)(b * 512 + t0) * 64 + i];
        __syncthreads();
        for (int tt = 0; tt < 64; ++tt) {
            float2 xv = *(float2*)&xs[tt * 64 + c2];
            int t = t0 + tt;
            int idx = (fb * t) & 511;
            #pragma unroll
            for (int i = 0; i < 8; ++i) {
                float cv = ct[idx], sv = st[idx];
                ar[i].x += xv.x * cv; ar[i].y += xv.y * cv;
                ai[i].x -= xv.x * sv; ai[i].y -= xv.y * sv;
                idx = (idx + t) & 511;
            }
        }
    }
    #pragma unroll
    for (int i = 0; i < 8; ++i) {
        int f = fb + i;
        if (f < 257) {
            *(float2*)&xre[((size_t)(b * 257) + f) * 64 + c2] = ar[i];
            *(float2*)&xim[((size_t)(b * 257) + f) * 64 + c2] = ai[i];
        }
    }
}

// ===== 2. block-per-row LDS-tree top-k (shuffle-free) =====
// One block per (b,c). mag[320] in LDS; 20 rounds of syncthreads-separated tree
// argmax; thread 0 clears winner. Selection semantics identical to proven naive:
// sqrtf magnitude, strict > with lowest-f tie-break.
__global__ __launch_bounds__(256) void topk_lds(const float* __restrict__ xre,
                                                const float* __restrict__ xim,
                                                int* __restrict__ keepi,
                                                float* __restrict__ keepw,
                                                const int* __restrict__ kptr) {
    __shared__ float vals[320];
    __shared__ float tv[256];
    __shared__ int   ti[256];
    int tid = threadIdx.x;
    int bc = blockIdx.x;
    int b = bc >> 6, c = bc & 63;
    int kk = *kptr; if (kk > 32) kk = 32;
    for (int f = tid; f < 320; f += 256) {
        if (f < 257) {
            size_t a = ((size_t)(b * 257) + f) * 64 + c;
            float re = xre[a], im = xim[a];
            vals[f] = sqrtf(re * re + im * im);
        } else vals[f] = -1.f;
    }
    __syncthreads();
    for (int j = 0; j < kk; ++j) {
        float v0 = vals[tid];
        int   i0 = tid;
        if (tid < 64) {
            float v1 = vals[tid + 256];
            if (v1 > v0) { v0 = v1; i0 = tid + 256; }   // strict >: lower f wins ties
        }
        tv[tid] = v0; ti[tid] = i0;
        __syncthreads();
        for (int s = 128; s > 0; s >>= 1) {
            if (tid < s) {
                float ov = tv[tid + s]; int oi = ti[tid + s];
                if (ov > tv[tid] || (ov == tv[tid] && oi < ti[tid])) { tv[tid] = ov; ti[tid] = oi; }
            }
            __syncthreads();
        }
        if (tid == 0) {
            int bf = ti[0];
            keepi[bc * 32 + j] = bf;
            keepw[bc * 32 + j] = (bf == 0 || bf == 256) ? (1.f / 512.f) : (2.f / 512.f);
            vals[bf] = -1.f;
        }
        __syncthreads();
    }
}

// ===== 3. fused x_filt (proven round 7) =====
__global__ __launch_bounds__(256) void xfilt_fused(const float* __restrict__ x,
                                                   const float* __restrict__ xre,
                                                   const float* __restrict__ xim,
                                                   const int* __restrict__ keepi,
                                                   const float* __restrict__ keepw,
                                                   float* __restrict__ xfilt,
                                                   float* __restrict__ norm,
                                                   float* __restrict__ mft,
                                                   float* __restrict__ h,
                                                   const int* __restrict__ kptr) {
    __shared__ float ct[512], st[512];
    __shared__ int   kf[64 * 33];
    __shared__ float kre[64 * 33], kim[64 * 33];
    __shared__ float xs[64 * 65];
    __shared__ float ft[64 * 65];
    int tid = threadIdx.x;
    int b = blockIdx.y;
    int t0 = blockIdx.x * 64;
    int kk = *kptr; if (kk > 32) kk = 32;
    for (int i = tid; i < 512; i += 256) {
        float s, c; sincosf((float)((double)i * TWO_PI_OVER_512), &s, &c);
        ct[i] = c; st[i] = s;
    }
    for (int i = tid; i < 4096; i += 256) {
        int tl = i >> 6, c = i & 63;
        xs[tl * 65 + c] = x[((size_t)(b * 512) + t0 + tl) * 64 + c];
    }
    for (int e = tid; e < 64 * kk; e += 256) {
        int c = e / kk, j = e - c * kk;
        int bc = b * 64 + c;
        int f = keepi[bc * 32 + j];
        float w = keepw[bc * 32 + j];
        size_t a = ((size_t)(b * 257) + f) * 64 + c;
        kf[c * 33 + j]  = f;
        kre[c * 33 + j] = w * xre[a];
        kim[c * 33 + j] = w * xim[a];
    }
    __syncthreads();
    int l = tid & 63, w = tid >> 6;
    int t = t0 + l;
    for (int ci = 0; ci < 16; ++ci) {
        int c = w * 16 + ci;
        float acc = 0.f;
        for (int j = 0; j < kk; ++j) {
            int f = kf[c * 33 + j];
            int idx = (f * t) & 511;
            acc += kre[c * 33 + j] * ct[idx] - kim[c * 33 + j] * st[idx];
        }
        ft[c * 65 + l] = acc;
    }
    __syncthreads();
    for (int i = tid; i < 4096; i += 256) {
        int tl = i >> 6, c = i & 63;
        float v = ft[c * 65 + tl];
        size_t a = ((size_t)(b * 512) + t0 + tl) * 64 + c;
        xfilt[a] = v;
        norm[a]  = xs[tl * 65 + c] - v;
    }
    for (int i = tid; i < 4096; i += 256) {
        int cr = i >> 6, tl = i & 63;
        mft[((size_t)(b * 64) + cr) * 512 + t0 + tl] = ft[cr * 65 + tl];
        h[((size_t)(b * 64) + cr) * 1024 + 512 + t0 + tl] = xs[tl * 65 + cr];
    }
}

// ===== 4. naive QKV (proven round 3) =====
__global__ __launch_bounds__(192) void qkv_naive(const float* __restrict__ xfilt,
                                                 const float* __restrict__ norm,
                                                 const float* __restrict__ w,
                                                 const float* __restrict__ bias,
                                                 float* __restrict__ q,
                                                 float* __restrict__ kmat,
                                                 float* __restrict__ v) {
    __shared__ float xf[64], nm[64];
    int tid = threadIdx.x;
    int t = blockIdx.x;
    int b = blockIdx.y;
    if (tid < 64) {
        size_t a = ((size_t)b * 512 + t) * 64 + tid;
        xf[tid] = xfilt[a];
        nm[tid] = norm[a];
    }
    __syncthreads();
    int o = tid;
    const float* src = (o < 64) ? xf : nm;
    float acc = bias[o];
    for (int e = 0; e < 64; ++e) acc += w[(size_t)o * 64 + e] * src[e];
    size_t base = ((size_t)b * 512 + t) * 64;
    if (o < 64)       q[base + o] = acc;
    else if (o < 128) kmat[base + o - 64] = acc;
    else              v[base + o - 128] = acc;
}

// ===== 5. attention + out-proj (proven rounds 0-7) =====
__global__ __launch_bounds__(256) void attn_kernel(const float* __restrict__ q,
                                                   const float* __restrict__ kmat,
                                                   const float* __restrict__ v,
                                                   const float* __restrict__ ow,
                                                   const float* __restrict__ ob,
                                                   float* __restrict__ out) {
    __shared__ float qs[16 * 65];
    __shared__ float kv[64 * 65];
    __shared__ float S[16 * 512];
    __shared__ float Os[16 * 65];
    __shared__ float invl[16];
    int tid = threadIdx.x;
    int b = blockIdx.y;
    int i0 = blockIdx.x * 16;
    int jl = tid & 63, rg = tid >> 6;
    for (int i = tid; i < 1024; i += 256) {
        int r = i >> 6, e = i & 63;
        qs[r * 65 + e] = q[((size_t)(b * 512) + i0 + r) * 64 + e];
    }
    for (int jt = 0; jt < 8; ++jt) {
        __syncthreads();
        for (int i = tid; i < 4096; i += 256) {
            int r = i >> 6, e = i & 63;
            kv[r * 65 + e] = kmat[((size_t)(b * 512) + jt * 64 + r) * 64 + e];
        }
        __syncthreads();
        float a0 = 0, a1 = 0, a2 = 0, a3 = 0;
        for (int e = 0; e < 64; ++e) {
            float kvv = kv[jl * 65 + e];
            a0 += qs[(rg * 4 + 0) * 65 + e] * kvv;
            a1 += qs[(rg * 4 + 1) * 65 + e] * kvv;
            a2 += qs[(rg * 4 + 2) * 65 + e] * kvv;
            a3 += qs[(rg * 4 + 3) * 65 + e] * kvv;
        }
        S[(rg * 4 + 0) * 512 + jt * 64 + jl] = a0 * 0.125f;
        S[(rg * 4 + 1) * 512 + jt * 64 + jl] = a1 * 0.125f;
        S[(rg * 4 + 2) * 512 + jt * 64 + jl] = a2 * 0.125f;
        S[(rg * 4 + 3) * 512 + jt * 64 + jl] = a3 * 0.125f;
    }
    #pragma unroll
    for (int ii = 0; ii < 4; ++ii) {
        int il = rg * 4 + ii;
        float p[8];
        float mx = -1e30f;
        #pragma unroll
        for (int s = 0; s < 8; ++s) { p[s] = S[il * 512 + jl + 64 * s]; mx = fmaxf(mx, p[s]); }
        for (int off = 32; off; off >>= 1) mx = fmaxf(mx, __shfl_xor(mx, off));
        float sum = 0.f;
        #pragma unroll
        for (int s = 0; s < 8; ++s) { p[s] = expf(p[s] - mx); sum += p[s]; S[il * 512 + jl + 64 * s] = p[s]; }
        for (int off = 32; off; off >>= 1) sum += __shfl_xor(sum, off);
        if (jl == 0) invl[il] = 1.0f / sum;
    }
    float o0 = 0, o1 = 0, o2 = 0, o3 = 0;
    for (int jt = 0; jt < 8; ++jt) {
        __syncthreads();
        for (int i = tid; i < 4096; i += 256) {
            int r = i >> 6, e = i & 63;
            kv[r * 65 + e] = v[((size_t)(b * 512) + jt * 64 + r) * 64 + e];
        }
        __syncthreads();
        for (int j2 = 0; j2 < 64; ++j2) {
            float vv = kv[j2 * 65 + jl];
            o0 += S[(rg * 4 + 0) * 512 + jt * 64 + j2] * vv;
            o1 += S[(rg * 4 + 1) * 512 + jt * 64 + j2] * vv;
            o2 += S[(rg * 4 + 2) * 512 + jt * 64 + j2] * vv;
            o3 += S[(rg * 4 + 3) * 512 + jt * 64 + j2] * vv;
        }
    }
    o0 *= invl[rg * 4 + 0]; o1 *= invl[rg * 4 + 1];
    o2 *= invl[rg * 4 + 2]; o3 *= invl[rg * 4 + 3];
    Os[(rg * 4 + 0) * 65 + jl] = o0;
    Os[(rg * 4 + 1) * 65 + jl] = o1;
    Os[(rg * 4 + 2) * 65 + jl] = o2;
    Os[(rg * 4 + 3) * 65 + jl] = o3;
    __syncthreads();
    for (int i = tid; i < 4096; i += 256) {
        int o = i >> 6, e = i & 63;
        kv[e * 65 + o] = ow[i];
    }
    __syncthreads();
    {
        int o = jl;
        float bb = ob[o];
        #pragma unroll
        for (int ii = 0; ii < 4; ++ii) {
            int il = rg * 4 + ii;
            float acc = bb;
            for (int e = 0; e < 64; ++e) acc += Os[il * 65 + e] * kv[e * 65 + o];
            out[((size_t)(b * 512) + i0 + il) * 64 + o] = acc;
        }
    }
}

// ===== 6. tiled fp32 GEMM (proven round 4) — FAN epilogues only =====
template<int EPI>
__global__ __launch_bounds__(256) void gemm_k(const float* __restrict__ A,
                                              const float* __restrict__ W,
                                              const float* __restrict__ bias,
                                              float* __restrict__ C,
                                              int K, int ldc,
                                              const float* __restrict__ gate,
                                              int moff) {
    __shared__ float As[32 * 64];
    __shared__ float Bs[32 * 64];
    int tid = threadIdx.x;
    int tx = tid & 15, ty = tid >> 4;
    int m0 = blockIdx.y * 64, n0 = blockIdx.x * 64;
    float acc[4][4] = {};
    for (int k0 = 0; k0 < K; k0 += 32) {
        __syncthreads();
        #pragma unroll
        for (int s = 0; s < 2; ++s) {
            int i4 = tid + s * 256;
            int row = i4 >> 3, kq = i4 & 7;
            float4 a4 = *(const float4*)&A[(size_t)(m0 + row) * K + k0 + kq * 4];
            float4 w4 = *(const float4*)&W[(size_t)(n0 + row) * K + k0 + kq * 4];
            int kb = kq * 4;
            As[(kb + 0) * 64 + row] = a4.x; As[(kb + 1) * 64 + row] = a4.y;
            As[(kb + 2) * 64 + row] = a4.z; As[(kb + 3) * 64 + row] = a4.w;
            Bs[(kb + 0) * 64 + row] = w4.x; Bs[(kb + 1) * 64 + row] = w4.y;
            Bs[(kb + 2) * 64 + row] = w4.z; Bs[(kb + 3) * 64 + row] = w4.w;
        }
        __syncthreads();
        #pragma unroll
        for (int kk = 0; kk < 32; ++kk) {
            float4 a4 = *(const float4*)&As[kk * 64 + (ty << 2)];
            float4 b4 = *(const float4*)&Bs[kk * 64 + (tx << 2)];
            #pragma unroll
            for (int i = 0; i < 4; ++i)
                #pragma unroll
                for (int j = 0; j < 4; ++j)
                    acc[i][j] += (&a4.x)[i] * (&b4.x)[j];
        }
    }
    int row0 = m0 + ty * 4, col0 = n0 + tx * 4;
    float4 bb = *(const float4*)&bias[col0];
    float gt = 1.f / (1.f + expf(-gate[0]));
    #pragma unroll
    for (int i = 0; i < 4; ++i) {
        int row = row0 + i;
        float v0 = acc[i][0] + bb.x, v1 = acc[i][1] + bb.y;
        float v2 = acc[i][2] + bb.z, v3 = acc[i][3] + bb.w;
        if (EPI == 2) {
            float4 co = make_float4(gt * cosf(v0), gt * cosf(v1), gt * cosf(v2), gt * cosf(v3));
            float4 si = make_float4(gt * sinf(v0), gt * sinf(v1), gt * sinf(v2), gt * sinf(v3));
            *(float4*)&C[(size_t)row * 1024 + col0] = co;
            *(float4*)&C[(size_t)row * 1024 + 128 + col0] = si;
        } else if (EPI == 3) {
            float ig = 1.f - gt;
            float4 o = make_float4(
                ig * 0.5f * v0 * (1.f + erff(v0 * 0.70710678118f)),
                ig * 0.5f * v1 * (1.f + erff(v1 * 0.70710678118f)),
                ig * 0.5f * v2 * (1.f + erff(v2 * 0.70710678118f)),
                ig * 0.5f * v3 * (1.f + erff(v3 * 0.70710678118f)));
            *(float4*)&C[(size_t)row * 1024 + 256 + col0] = o;
        }
    }
}

// ===== 7. cast f32 -> bf16 =====
__global__ __launch_bounds__(256) void cast_bf16(const float* __restrict__ in,
                                                 unsigned short* __restrict__ out, int n4) {
    int i = blockIdx.x * 256 + threadIdx.x;
    if (i < n4) {
        float4 v = *(const float4*)&in[(size_t)i * 4];
        ushort4 o;
        o.x = f2bf(v.x); o.y = f2bf(v.y); o.z = f2bf(v.z); o.w = f2bf(v.w);
        *(ushort4*)&out[(size_t)i * 4] = o;
    }
}

// ===== 8. bf16 MFMA GEMM (proven round 6): C = A[M,K] @ B[N,K]^T, 128x128, BK=64 =====
template<int EPI>
__global__ __launch_bounds__(256) void gemm_mfma(const unsigned short* __restrict__ A,
                                                 const unsigned short* __restrict__ B,
                                                 const float* __restrict__ bias,
                                                 void* __restrict__ Cout,
                                                 int M, int N, int K) {
    __shared__ unsigned short As[8192];
    __shared__ unsigned short Bs[8192];
    int tid = threadIdx.x;
    int l = tid & 63, w = tid >> 6;
    int q = l >> 4, cl = l & 15;
    int wm = w >> 1, wn = w & 1;
    int m0 = blockIdx.y * 128, n0 = blockIdx.x * 128;
    floatx4 acc[4][4];
    #pragma unroll
    for (int i = 0; i < 4; ++i)
        #pragma unroll
        for (int j = 0; j < 4; ++j)
            acc[i][j] = (floatx4){0.f, 0.f, 0.f, 0.f};

    for (int k0 = 0; k0 < K; k0 += 64) {
        __syncthreads();
        #pragma unroll
        for (int ci = 0; ci < 8; ++ci) {
            int cid = w * 8 + ci;
            int isB = cid >> 4;
            int c = cid & 15;
            int cq = c >> 3, cks = (c >> 2) & 1, cf = c & 3;
            int row = cq * 64 + cf * 16 + cl;
            int col = k0 + cks * 32 + q * 8;
            const unsigned short* gp = isB ? (B + (size_t)(n0 + row) * K + col)
                                           : (A + (size_t)(m0 + row) * K + col);
            unsigned short* lp = (isB ? Bs : As) + c * 512;
            __builtin_amdgcn_global_load_lds((const __attribute__((address_space(1))) void*)gp,
                                             (__attribute__((address_space(3))) void*)lp,
                                             16, 0, 0);
        }
        __syncthreads();
        #pragma unroll
        for (int ks = 0; ks < 2; ++ks) {
            short8 af[4], bg[4];
            #pragma unroll
            for (int f = 0; f < 4; ++f) {
                af[f] = *(short8*)&As[(wm * 8 + ks * 4 + f) * 512 + l * 8];
                bg[f] = *(short8*)&Bs[(wn * 8 + ks * 4 + f) * 512 + l * 8];
            }
            #pragma unroll
            for (int i = 0; i < 4; ++i)
                #pragma unroll
                for (int j = 0; j < 4; ++j)
                    acc[i][j] = __builtin_amdgcn_mfma_f32_16x16x32_bf16(af[i], bg[j], acc[i][j], 0, 0, 0);
        }
    }

    if (EPI == 1) {
        unsigned short* Cb = (unsigned short*)Cout;
        #pragma unroll
        for (int j = 0; j < 4; ++j) {
            int col = n0 + wn * 64 + j * 16 + cl;
            float bb = bias[col];
            #pragma unroll
            for (int i = 0; i < 4; ++i) {
                int rowb = m0 + wm * 64 + i * 16 + q * 4;
                #pragma unroll
                for (int r = 0; r < 4; ++r) {
                    float v = acc[i][j][r] + bb;
                    Cb[(size_t)(rowb + r) * N + col] = f2bf(fmaxf(v, 0.f));
                }
            }
        }
    } else {
        float* Ob = (float*)Cout;
        int bidx = (n0 >> 6) + wn;
        #pragma unroll
        for (int i = 0; i < 4; ++i) {
            #pragma unroll
            for (int r = 0; r < 4; ++r) {
                int t = m0 + wm * 64 + i * 16 + q * 4 + r;
                float bb = bias[t];
                #pragma unroll
                for (int j = 0; j < 4; ++j) {
                    int c = j * 16 + cl;
                    Ob[((size_t)bidx * 512 + t) * 64 + c] = acc[i][j][r] + bb;
                }
            }
        }
    }
}

extern "C" void kernel_launch(void* const* d_in, const int* in_sizes, int n_in,
                              void* d_out, int out_size, void* d_ws, size_t ws_size,
                              hipStream_t stream) {
    const float* x         = (const float*)d_in[0];
    const float* in_proj_w = (const float*)d_in[1];
    const float* in_proj_b = (const float*)d_in[2];
    const float* out_w     = (const float*)d_in[3];
    const float* out_b     = (const float*)d_in[4];
    const float* Wp        = (const float*)d_in[5];
    const float* bp        = (const float*)d_in[6];
    const float* Wg        = (const float*)d_in[7];
    const float* bg        = (const float*)d_in[8];
    const float* gate      = (const float*)d_in[9];
    const float* fc1_w     = (const float*)d_in[10];
    const float* fc1_b     = (const float*)d_in[11];
    const float* fc2_w     = (const float*)d_in[12];
    const float* fc2_b     = (const float*)d_in[13];
    const int*   kptr      = (const int*)d_in[14];
    float* ws  = (float*)d_ws;
    float* out = (float*)d_out;

    float* h     = ws + U_H;
    float* mft   = ws + U_MFT;
    float* xre   = ws + U_XRE;
    float* xim   = ws + U_XIM;
    int*   keepi = (int*)(ws + U_KEEPI);
    float* keepw = ws + U_KEEPW;
    float* xfilt = ws + U_XFILT;
    float* norm  = ws + U_NORM;
    float* qb    = ws + U_Q;
    float* kb    = ws + U_K;
    float* vb    = ws + U_V;
    unsigned short* hbf   = (unsigned short*)(ws + U_HBF);
    unsigned short* hidbf = (unsigned short*)(ws + U_HIDBF);
    unsigned short* w1bf  = (unsigned short*)(ws + U_W1BF);
    unsigned short* w2bf  = (unsigned short*)(ws + U_W2BF);

    dft_tile   <<<dim3(5, 64),   256, 0, stream>>>(x, xre, xim);
    topk_lds   <<<dim3(4096),    256, 0, stream>>>(xre, xim, keepi, keepw, kptr);
    xfilt_fused<<<dim3(8, 64),   256, 0, stream>>>(x, xre, xim, keepi, keepw, xfilt, norm, mft, h, kptr);
    qkv_naive  <<<dim3(512, 64), 192, 0, stream>>>(xfilt, norm, in_proj_w, in_proj_b, qb, kb, vb);
    attn_kernel<<<dim3(32, 64),  256, 0, stream>>>(qb, kb, vb, out_w, out_b, out);
    gemm_k<2>  <<<dim3(2, 64),   256, 0, stream>>>(mft, Wp, bp, h, 512, 1024, gate, 0);
    gemm_k<3>  <<<dim3(4, 64),   256, 0, stream>>>(mft, Wg, bg, h, 512, 1024, gate, 0);
    cast_bf16<<<4096, 256, 0, stream>>>(h,     hbf,  1048576);
    cast_bf16<<<3072, 256, 0, stream>>>(fc1_w, w1bf, 786432);
    cast_bf16<<<1536, 256, 0, stream>>>(fc2_w, w2bf, 393216);
    gemm_mfma<1><<<dim3(24, 32), 256, 0, stream>>>(hbf,  w1bf,  fc1_b, hidbf,          4096, 3072, 1024);
    gemm_mfma<2><<<dim3(32, 4),  256, 0, stream>>>(w2bf, hidbf, fc2_b, out + 2097152,  512,  4096, 3072);
}

// Round 10
// 787.185 us; speedup vs baseline: 12.2177x; 1.1931x over previous
//
#include <hip/hip_runtime.h>
#include <math.h>

// B=64, L=512, C=64, E=64, F=257, PRED=512, H1=1024, H2=3072
// ---- workspace layout (f32 units), peak 17,047,552 = 68.19 MB (proven) ----
#define U_H     0            // [4096][1024]            -> 4194304
#define U_MFT   4194304      // [4096][512]             -> 6291456
#define U_XRE   6291456      // [64][257][64]           -> 7344128
#define U_XIM   7344128      //                         -> 8396800
#define U_KEEPI 8396800      // int[4096*32]            -> 8527872
#define U_KEEPW 8527872      //                         -> 8658944
#define U_XFILT 8658944      // [64][512][64]           -> 10756096
#define U_NORM  10756096     // [64][512][64]           -> 12853248
#define U_Q     6291456      // bf16 [64][512][64] over dead xre/xim (half of f32 slot)
#define U_K     12853248     // bf16 [64][512][64]
#define U_V     14950400     // bf16 V^T [64][64][512]           (peak 17047552)
#define U_HBF   6291456      // bf16 [4096][1024] = 2097152 u -> 8388608
#define U_HIDBF 8388608      // bf16 [4096][3072] = 6291456 u -> 14680064
#define U_W1BF  14680064     // bf16 [3072][1024] = 1572864 u -> 16252928
#define U_W2BF  16252928     // bf16 [512][3072]  =  786432 u -> 17039360

#define TWO_PI_OVER_512 0.012271846303085129

typedef __attribute__((ext_vector_type(8))) short short8;
typedef __attribute__((ext_vector_type(4))) float floatx4;

__device__ inline unsigned short f2bf(float f) {
    union { unsigned int i; float f; } x; x.f = f;
    unsigned int r = x.i + 0x7fff + ((x.i >> 16) & 1);
    return (unsigned short)(r >> 16);
}

// ===== 1. tiled DFT (proven round 7) =====
__global__ __launch_bounds__(256) void dft_tile(const float* __restrict__ x,
                                                float* __restrict__ xre,
                                                float* __restrict__ xim) {
    __shared__ float xs[64 * 64];
    __shared__ float ct[512], st[512];
    int tid = threadIdx.x;
    int b = blockIdx.y;
    int f0 = blockIdx.x * 64;
    for (int i = tid; i < 512; i += 256) {
        float s, c; sincosf((float)((double)i * TWO_PI_OVER_512), &s, &c);
        ct[i] = c; st[i] = s;
    }
    int c2 = (tid & 31) * 2;
    int fg = tid >> 5;
    int fb = f0 + fg * 8;
    float2 ar[8], ai[8];
    #pragma unroll
    for (int i = 0; i < 8; ++i) { ar[i] = make_float2(0.f, 0.f); ai[i] = make_float2(0.f, 0.f); }
    for (int t0 = 0; t0 < 512; t0 += 64) {
        __syncthreads();
        for (int i = tid; i < 4096; i += 256)
            xs[i] = x[(size_t)(b * 512 + t0) * 64 + i];
        __syncthreads();
        for (int tt = 0; tt < 64; ++tt) {
            float2 xv = *(float2*)&xs[tt * 64 + c2];
            int t = t0 + tt;
            int idx = (fb * t) & 511;
            #pragma unroll
            for (int i = 0; i < 8; ++i) {
                float cv = ct[idx], sv = st[idx];
                ar[i].x += xv.x * cv; ar[i].y += xv.y * cv;
                ai[i].x -= xv.x * sv; ai[i].y -= xv.y * sv;
                idx = (idx + t) & 511;
            }
        }
    }
    #pragma unroll
    for (int i = 0; i < 8; ++i) {
        int f = fb + i;
        if (f < 257) {
            *(float2*)&xre[((size_t)(b * 257) + f) * 64 + c2] = ar[i];
            *(float2*)&xim[((size_t)(b * 257) + f) * 64 + c2] = ai[i];
        }
    }
}

// ===== 2. block-per-row LDS-tree top-k (proven round 9) =====
__global__ __launch_bounds__(256) void topk_lds(const float* __restrict__ xre,
                                                const float* __restrict__ xim,
                                                int* __restrict__ keepi,
                                                float* __restrict__ keepw,
                                                const int* __restrict__ kptr) {
    __shared__ float vals[320];
    __shared__ float tv[256];
    __shared__ int   ti[256];
    int tid = threadIdx.x;
    int bc = blockIdx.x;
    int b = bc >> 6, c = bc & 63;
    int kk = *kptr; if (kk > 32) kk = 32;
    for (int f = tid; f < 320; f += 256) {
        if (f < 257) {
            size_t a = ((size_t)(b * 257) + f) * 64 + c;
            float re = xre[a], im = xim[a];
            vals[f] = sqrtf(re * re + im * im);
        } else vals[f] = -1.f;
    }
    __syncthreads();
    for (int j = 0; j < kk; ++j) {
        float v0 = vals[tid];
        int   i0 = tid;
        if (tid < 64) {
            float v1 = vals[tid + 256];
            if (v1 > v0) { v0 = v1; i0 = tid + 256; }
        }
        tv[tid] = v0; ti[tid] = i0;
        __syncthreads();
        for (int s = 128; s > 0; s >>= 1) {
            if (tid < s) {
                float ov = tv[tid + s]; int oi = ti[tid + s];
                if (ov > tv[tid] || (ov == tv[tid] && oi < ti[tid])) { tv[tid] = ov; ti[tid] = oi; }
            }
            __syncthreads();
        }
        if (tid == 0) {
            int bf = ti[0];
            keepi[bc * 32 + j] = bf;
            keepw[bc * 32 + j] = (bf == 0 || bf == 256) ? (1.f / 512.f) : (2.f / 512.f);
            vals[bf] = -1.f;
        }
        __syncthreads();
    }
}

// ===== 3. fused x_filt (proven round 7) =====
__global__ __launch_bounds__(256) void xfilt_fused(const float* __restrict__ x,
                                                   const float* __restrict__ xre,
                                                   const float* __restrict__ xim,
                                                   const int* __restrict__ keepi,
                                                   const float* __restrict__ keepw,
                                                   float* __restrict__ xfilt,
                                                   float* __restrict__ norm,
                                                   float* __restrict__ mft,
                                                   float* __restrict__ h,
                                                   const int* __restrict__ kptr) {
    __shared__ float ct[512], st[512];
    __shared__ int   kf[64 * 33];
    __shared__ float kre[64 * 33], kim[64 * 33];
    __shared__ float xs[64 * 65];
    __shared__ float ft[64 * 65];
    int tid = threadIdx.x;
    int b = blockIdx.y;
    int t0 = blockIdx.x * 64;
    int kk = *kptr; if (kk > 32) kk = 32;
    for (int i = tid; i < 512; i += 256) {
        float s, c; sincosf((float)((double)i * TWO_PI_OVER_512), &s, &c);
        ct[i] = c; st[i] = s;
    }
    for (int i = tid; i < 4096; i += 256) {
        int tl = i >> 6, c = i & 63;
        xs[tl * 65 + c] = x[((size_t)(b * 512) + t0 + tl) * 64 + c];
    }
    for (int e = tid; e < 64 * kk; e += 256) {
        int c = e / kk, j = e - c * kk;
        int bc = b * 64 + c;
        int f = keepi[bc * 32 + j];
        float w = keepw[bc * 32 + j];
        size_t a = ((size_t)(b * 257) + f) * 64 + c;
        kf[c * 33 + j]  = f;
        kre[c * 33 + j] = w * xre[a];
        kim[c * 33 + j] = w * xim[a];
    }
    __syncthreads();
    int l = tid & 63, w = tid >> 6;
    int t = t0 + l;
    for (int ci = 0; ci < 16; ++ci) {
        int c = w * 16 + ci;
        float acc = 0.f;
        for (int j = 0; j < kk; ++j) {
            int f = kf[c * 33 + j];
            int idx = (f * t) & 511;
            acc += kre[c * 33 + j] * ct[idx] - kim[c * 33 + j] * st[idx];
        }
        ft[c * 65 + l] = acc;
    }
    __syncthreads();
    for (int i = tid; i < 4096; i += 256) {
        int tl = i >> 6, c = i & 63;
        float v = ft[c * 65 + tl];
        size_t a = ((size_t)(b * 512) + t0 + tl) * 64 + c;
        xfilt[a] = v;
        norm[a]  = xs[tl * 65 + c] - v;
    }
    for (int i = tid; i < 4096; i += 256) {
        int cr = i >> 6, tl = i & 63;
        mft[((size_t)(b * 64) + cr) * 512 + t0 + tl] = ft[cr * 65 + tl];
        h[((size_t)(b * 64) + cr) * 1024 + 512 + t0 + tl] = xs[tl * 65 + cr];
    }
}

// ===== 4. QKV -> bf16 (q,k row-major; v transposed [b][e][t]) =====
__global__ __launch_bounds__(192) void qkv_bf16(const float* __restrict__ xfilt,
                                                const float* __restrict__ norm,
                                                const float* __restrict__ w,
                                                const float* __restrict__ bias,
                                                unsigned short* __restrict__ q,
                                                unsigned short* __restrict__ kmat,
                                                unsigned short* __restrict__ vt) {
    __shared__ float xf[64], nm[64];
    int tid = threadIdx.x;
    int t = blockIdx.x;
    int b = blockIdx.y;
    if (tid < 64) {
        size_t a = ((size_t)b * 512 + t) * 64 + tid;
        xf[tid] = xfilt[a];
        nm[tid] = norm[a];
    }
    __syncthreads();
    int o = tid;
    const float* src = (o < 64) ? xf : nm;
    float acc = bias[o];
    for (int e = 0; e < 64; ++e) acc += w[(size_t)o * 64 + e] * src[e];
    if (o < 64)       q[((size_t)b * 512 + t) * 64 + o] = f2bf(acc);
    else if (o < 128) kmat[((size_t)b * 512 + t) * 64 + o - 64] = f2bf(acc);
    else              vt[((size_t)b * 64 + (o - 128)) * 512 + t] = f2bf(acc);
}

// ===== 5. MFMA attention + out-proj =====
// Block = (64 q-rows, b), 4 waves x 16 rows. Fragment layouts identical to the
// verified gemm_mfma: A/B row=lane&15, k=(lane>>4)*8+j; C/D col=lane&15, row=quad*4+reg.
// P goes C-layout -> LDS (bf16, pad 520) -> A-layout (m120 recipe).
__global__ __launch_bounds__(256) void attn_mfma(const unsigned short* __restrict__ qbf,
                                                 const unsigned short* __restrict__ kbf,
                                                 const unsigned short* __restrict__ vtbf,
                                                 const float* __restrict__ ow,
                                                 const float* __restrict__ ob,
                                                 float* __restrict__ out) {
    __shared__ unsigned short Qs[64 * 72];
    __shared__ unsigned short KVs[64 * 72];
    __shared__ unsigned short Pw[4 * 16 * 520];   // per-wave 16 x 520
    __shared__ unsigned short Obs[64 * 72];
    __shared__ unsigned short OWs[64 * 72];
    int tid = threadIdx.x;
    int l = tid & 63, w = tid >> 6;
    int q = l >> 4, cl = l & 15;
    int b = blockIdx.y, i0 = blockIdx.x * 64;

    for (int i = tid; i < 1024; i += 256) {
        int r = i >> 4, e4 = (i & 15) * 4;
        *(ushort4*)&Qs[r * 72 + e4] = *(const ushort4*)&qbf[((size_t)(b * 512) + i0 + r) * 64 + e4];
    }
    for (int i = tid; i < 1024; i += 256) {
        int o = i >> 4, e4 = (i & 15) * 4;
        float4 v = *(const float4*)&ow[o * 64 + e4];
        ushort4 u; u.x = f2bf(v.x); u.y = f2bf(v.y); u.z = f2bf(v.z); u.w = f2bf(v.w);
        *(ushort4*)&OWs[o * 72 + e4] = u;
    }
    __syncthreads();
    short8 aq0 = *(short8*)&Qs[(w * 16 + cl) * 72 + q * 8];
    short8 aq1 = *(short8*)&Qs[(w * 16 + cl) * 72 + 32 + q * 8];

    floatx4 s[32];
    #pragma unroll
    for (int f = 0; f < 32; ++f) s[f] = (floatx4){0.f, 0.f, 0.f, 0.f};

    // ---- QK^T over 8 K-chunks of 64 j ----
    #pragma unroll
    for (int ch = 0; ch < 8; ++ch) {
        __syncthreads();
        for (int i = tid; i < 1024; i += 256) {
            int jj = i >> 4, e4 = (i & 15) * 4;
            *(ushort4*)&KVs[jj * 72 + e4] =
                *(const ushort4*)&kbf[((size_t)(b * 512) + ch * 64 + jj) * 64 + e4];
        }
        __syncthreads();
        #pragma unroll
        for (int jt = 0; jt < 4; ++jt) {
            short8 b0 = *(short8*)&KVs[(jt * 16 + cl) * 72 + q * 8];
            short8 b1 = *(short8*)&KVs[(jt * 16 + cl) * 72 + 32 + q * 8];
            s[ch * 4 + jt] = __builtin_amdgcn_mfma_f32_16x16x32_bf16(aq0, b0, s[ch * 4 + jt], 0, 0, 0);
            s[ch * 4 + jt] = __builtin_amdgcn_mfma_f32_16x16x32_bf16(aq1, b1, s[ch * 4 + jt], 0, 0, 0);
        }
    }

    // ---- softmax in registers (per-quad: 16 lanes hold one row's 16 cols) ----
    float invl[4];
    #pragma unroll
    for (int r = 0; r < 4; ++r) {
        float m = -1e30f;
        #pragma unroll
        for (int f = 0; f < 32; ++f) m = fmaxf(m, s[f][r]);
        m = fmaxf(m, __shfl_xor(m, 1)); m = fmaxf(m, __shfl_xor(m, 2));
        m = fmaxf(m, __shfl_xor(m, 4)); m = fmaxf(m, __shfl_xor(m, 8));
        float sum = 0.f;
        #pragma unroll
        for (int f = 0; f < 32; ++f) {
            float p = expf((s[f][r] - m) * 0.125f);   // softmax(s/8)
            s[f][r] = p; sum += p;
        }
        sum += __shfl_xor(sum, 1); sum += __shfl_xor(sum, 2);
        sum += __shfl_xor(sum, 4); sum += __shfl_xor(sum, 8);
        invl[r] = 1.f / sum;
    }

    // ---- P (C-layout) -> LDS row-major bf16 ----
    #pragma unroll
    for (int f = 0; f < 32; ++f)
        #pragma unroll
        for (int r = 0; r < 4; ++r)
            Pw[w * 8320 + (q * 4 + r) * 520 + f * 16 + cl] = f2bf(s[f][r]);

    // ---- PV over 8 V^T-chunks ----
    floatx4 o4[4];
    #pragma unroll
    for (int nt = 0; nt < 4; ++nt) o4[nt] = (floatx4){0.f, 0.f, 0.f, 0.f};
    #pragma unroll
    for (int ch = 0; ch < 8; ++ch) {
        __syncthreads();
        for (int i = tid; i < 1024; i += 256) {
            int e = i >> 4, j4 = (i & 15) * 4;
            *(ushort4*)&KVs[e * 72 + j4] =
                *(const ushort4*)&vtbf[((size_t)(b * 64) + e) * 512 + ch * 64 + j4];
        }
        __syncthreads();
        #pragma unroll
        for (int ks = 0; ks < 2; ++ks) {
            short8 ap = *(short8*)&Pw[w * 8320 + cl * 520 + ch * 64 + ks * 32 + q * 8];
            #pragma unroll
            for (int nt = 0; nt < 4; ++nt) {
                short8 bv = *(short8*)&KVs[(nt * 16 + cl) * 72 + ks * 32 + q * 8];
                o4[nt] = __builtin_amdgcn_mfma_f32_16x16x32_bf16(ap, bv, o4[nt], 0, 0, 0);
            }
        }
    }

    // ---- O/l -> LDS bf16; out-proj via MFMA; +bias store ----
    #pragma unroll
    for (int nt = 0; nt < 4; ++nt)
        #pragma unroll
        for (int r = 0; r < 4; ++r)
            Obs[(w * 16 + q * 4 + r) * 72 + nt * 16 + cl] = f2bf(o4[nt][r] * invl[r]);
    __syncthreads();
    floatx4 acc2[4];
    #pragma unroll
    for (int nt = 0; nt < 4; ++nt) acc2[nt] = (floatx4){0.f, 0.f, 0.f, 0.f};
    #pragma unroll
    for (int ks = 0; ks < 2; ++ks) {
        short8 ao = *(short8*)&Obs[(w * 16 + cl) * 72 + ks * 32 + q * 8];
        #pragma unroll
        for (int nt = 0; nt < 4; ++nt) {
            short8 bo = *(short8*)&OWs[(nt * 16 + cl) * 72 + ks * 32 + q * 8];
            acc2[nt] = __builtin_amdgcn_mfma_f32_16x16x32_bf16(ao, bo, acc2[nt], 0, 0, 0);
        }
    }
    #pragma unroll
    for (int nt = 0; nt < 4; ++nt) {
        float bb = ob[nt * 16 + cl];
        #pragma unroll
        for (int r = 0; r < 4; ++r)
            out[((size_t)(b * 512) + i0 + w * 16 + q * 4 + r) * 64 + nt * 16 + cl] = acc2[nt][r] + bb;
    }
}

// ===== 6. tiled fp32 GEMM (proven round 4) — FAN epilogues only =====
template<int EPI>
__global__ __launch_bounds__(256) void gemm_k(const float* __restrict__ A,
                                              const float* __restrict__ W,
                                              const float* __restrict__ bias,
                                              float* __restrict__ C,
                                              int K, int ldc,
                                              const float* __restrict__ gate,
                                              int moff) {
    __shared__ float As[32 * 64];
    __shared__ float Bs[32 * 64];
    int tid = threadIdx.x;
    int tx = tid & 15, ty = tid >> 4;
    int m0 = blockIdx.y * 64, n0 = blockIdx.x * 64;
    float acc[4][4] = {};
    for (int k0 = 0; k0 < K; k0 += 32) {
        __syncthreads();
        #pragma unroll
        for (int s = 0; s < 2; ++s) {
            int i4 = tid + s * 256;
            int row = i4 >> 3, kq = i4 & 7;
            float4 a4 = *(const float4*)&A[(size_t)(m0 + row) * K + k0 + kq * 4];
            float4 w4 = *(const float4*)&W[(size_t)(n0 + row) * K + k0 + kq * 4];
            int kb = kq * 4;
            As[(kb + 0) * 64 + row] = a4.x; As[(kb + 1) * 64 + row] = a4.y;
            As[(kb + 2) * 64 + row] = a4.z; As[(kb + 3) * 64 + row] = a4.w;
            Bs[(kb + 0) * 64 + row] = w4.x; Bs[(kb + 1) * 64 + row] = w4.y;
            Bs[(kb + 2) * 64 + row] = w4.z; Bs[(kb + 3) * 64 + row] = w4.w;
        }
        __syncthreads();
        #pragma unroll
        for (int kk = 0; kk < 32; ++kk) {
            float4 a4 = *(const float4*)&As[kk * 64 + (ty << 2)];
            float4 b4 = *(const float4*)&Bs[kk * 64 + (tx << 2)];
            #pragma unroll
            for (int i = 0; i < 4; ++i)
                #pragma unroll
                for (int j = 0; j < 4; ++j)
                    acc[i][j] += (&a4.x)[i] * (&b4.x)[j];
        }
    }
    int row0 = m0 + ty * 4, col0 = n0 + tx * 4;
    float4 bb = *(const float4*)&bias[col0];
    float gt = 1.f / (1.f + expf(-gate[0]));
    #pragma unroll
    for (int i = 0; i < 4; ++i) {
        int row = row0 + i;
        float v0 = acc[i][0] + bb.x, v1 = acc[i][1] + bb.y;
        float v2 = acc[i][2] + bb.z, v3 = acc[i][3] + bb.w;
        if (EPI == 2) {
            float4 co = make_float4(gt * cosf(v0), gt * cosf(v1), gt * cosf(v2), gt * cosf(v3));
            float4 si = make_float4(gt * sinf(v0), gt * sinf(v1), gt * sinf(v2), gt * sinf(v3));
            *(float4*)&C[(size_t)row * 1024 + col0] = co;
            *(float4*)&C[(size_t)row * 1024 + 128 + col0] = si;
        } else if (EPI == 3) {
            float ig = 1.f - gt;
            float4 o = make_float4(
                ig * 0.5f * v0 * (1.f + erff(v0 * 0.70710678118f)),
                ig * 0.5f * v1 * (1.f + erff(v1 * 0.70710678118f)),
                ig * 0.5f * v2 * (1.f + erff(v2 * 0.70710678118f)),
                ig * 0.5f * v3 * (1.f + erff(v3 * 0.70710678118f)));
            *(float4*)&C[(size_t)row * 1024 + 256 + col0] = o;
        }
    }
}

// ===== 7. cast f32 -> bf16 =====
__global__ __launch_bounds__(256) void cast_bf16(const float* __restrict__ in,
                                                 unsigned short* __restrict__ out, int n4) {
    int i = blockIdx.x * 256 + threadIdx.x;
    if (i < n4) {
        float4 v = *(const float4*)&in[(size_t)i * 4];
        ushort4 o;
        o.x = f2bf(v.x); o.y = f2bf(v.y); o.z = f2bf(v.z); o.w = f2bf(v.w);
        *(ushort4*)&out[(size_t)i * 4] = o;
    }
}

// ===== 8. bf16 MFMA GEMM (proven round 6): C = A[M,K] @ B[N,K]^T, 128x128, BK=64 =====
template<int EPI>
__global__ __launch_bounds__(256) void gemm_mfma(const unsigned short* __restrict__ A,
                                                 const unsigned short* __restrict__ B,
                                                 const float* __restrict__ bias,
                                                 void* __restrict__ Cout,
                                                 int M, int N, int K) {
    __shared__ unsigned short As[8192];
    __shared__ unsigned short Bs[8192];
    int tid = threadIdx.x;
    int l = tid & 63, w = tid >> 6;
    int q = l >> 4, cl = l & 15;
    int wm = w >> 1, wn = w & 1;
    int m0 = blockIdx.y * 128, n0 = blockIdx.x * 128;
    floatx4 acc[4][4];
    #pragma unroll
    for (int i = 0; i < 4; ++i)
        #pragma unroll
        for (int j = 0; j < 4; ++j)
            acc[i][j] = (floatx4){0.f, 0.f, 0.f, 0.f};

    for (int k0 = 0; k0 < K; k0 += 64) {
        __syncthreads();
        #pragma unroll
        for (int ci = 0; ci < 8; ++ci) {
            int cid = w * 8 + ci;
            int isB = cid >> 4;
            int c = cid & 15;
            int cq = c >> 3, cks = (c >> 2) & 1, cf = c & 3;
            int row = cq * 64 + cf * 16 + cl;
            int col = k0 + cks * 32 + q * 8;
            const unsigned short* gp = isB ? (B + (size_t)(n0 + row) * K + col)
                                           : (A + (size_t)(m0 + row) * K + col);
            unsigned short* lp = (isB ? Bs : As) + c * 512;
            __builtin_amdgcn_global_load_lds((const __attribute__((address_space(1))) void*)gp,
                                             (__attribute__((address_space(3))) void*)lp,
                                             16, 0, 0);
        }
        __syncthreads();
        #pragma unroll
        for (int ks = 0; ks < 2; ++ks) {
            short8 af[4], bg[4];
            #pragma unroll
            for (int f = 0; f < 4; ++f) {
                af[f] = *(short8*)&As[(wm * 8 + ks * 4 + f) * 512 + l * 8];
                bg[f] = *(short8*)&Bs[(wn * 8 + ks * 4 + f) * 512 + l * 8];
            }
            #pragma unroll
            for (int i = 0; i < 4; ++i)
                #pragma unroll
                for (int j = 0; j < 4; ++j)
                    acc[i][j] = __builtin_amdgcn_mfma_f32_16x16x32_bf16(af[i], bg[j], acc[i][j], 0, 0, 0);
        }
    }

    if (EPI == 1) {
        unsigned short* Cb = (unsigned short*)Cout;
        #pragma unroll
        for (int j = 0; j < 4; ++j) {
            int col = n0 + wn * 64 + j * 16 + cl;
            float bb = bias[col];
            #pragma unroll
            for (int i = 0; i < 4; ++i) {
                int rowb = m0 + wm * 64 + i * 16 + q * 4;
                #pragma unroll
                for (int r = 0; r < 4; ++r) {
                    float v = acc[i][j][r] + bb;
                    Cb[(size_t)(rowb + r) * N + col] = f2bf(fmaxf(v, 0.f));
                }
            }
        }
    } else {
        float* Ob = (float*)Cout;
        int bidx = (n0 >> 6) + wn;
        #pragma unroll
        for (int i = 0; i < 4; ++i) {
            #pragma unroll
            for (int r = 0; r < 4; ++r) {
                int t = m0 + wm * 64 + i * 16 + q * 4 + r;
                float bb = bias[t];
                #pragma unroll
                for (int j = 0; j < 4; ++j) {
                    int c = j * 16 + cl;
                    Ob[((size_t)bidx * 512 + t) * 64 + c] = acc[i][j][r] + bb;
                }
            }
        }
    }
}

extern "C" void kernel_launch(void* const* d_in, const int* in_sizes, int n_in,
                              void* d_out, int out_size, void* d_ws, size_t ws_size,
                              hipStream_t stream) {
    const float* x         = (const float*)d_in[0];
    const float* in_proj_w = (const float*)d_in[1];
    const float* in_proj_b = (const float*)d_in[2];
    const float* out_w     = (const float*)d_in[3];
    const float* out_b     = (const float*)d_in[4];
    const float* Wp        = (const float*)d_in[5];
    const float* bp        = (const float*)d_in[6];
    const float* Wg        = (const float*)d_in[7];
    const float* bg        = (const float*)d_in[8];
    const float* gate      = (const float*)d_in[9];
    const float* fc1_w     = (const float*)d_in[10];
    const float* fc1_b     = (const float*)d_in[11];
    const float* fc2_w     = (const float*)d_in[12];
    const float* fc2_b     = (const float*)d_in[13];
    const int*   kptr      = (const int*)d_in[14];
    float* ws  = (float*)d_ws;
    float* out = (float*)d_out;

    float* h     = ws + U_H;
    float* mft   = ws + U_MFT;
    float* xre   = ws + U_XRE;
    float* xim   = ws + U_XIM;
    int*   keepi = (int*)(ws + U_KEEPI);
    float* keepw = ws + U_KEEPW;
    float* xfilt = ws + U_XFILT;
    float* norm  = ws + U_NORM;
    unsigned short* qb    = (unsigned short*)(ws + U_Q);
    unsigned short* kb    = (unsigned short*)(ws + U_K);
    unsigned short* vtb   = (unsigned short*)(ws + U_V);
    unsigned short* hbf   = (unsigned short*)(ws + U_HBF);
    unsigned short* hidbf = (unsigned short*)(ws + U_HIDBF);
    unsigned short* w1bf  = (unsigned short*)(ws + U_W1BF);
    unsigned short* w2bf  = (unsigned short*)(ws + U_W2BF);

    dft_tile   <<<dim3(5, 64),   256, 0, stream>>>(x, xre, xim);
    topk_lds   <<<dim3(4096),    256, 0, stream>>>(xre, xim, keepi, keepw, kptr);
    xfilt_fused<<<dim3(8, 64),   256, 0, stream>>>(x, xre, xim, keepi, keepw, xfilt, norm, mft, h, kptr);
    qkv_bf16   <<<dim3(512, 64), 192, 0, stream>>>(xfilt, norm, in_proj_w, in_proj_b, qb, kb, vtb);
    attn_mfma  <<<dim3(8, 64),   256, 0, stream>>>(qb, kb, vtb, out_w, out_b, out);
    gemm_k<2>  <<<dim3(2, 64),   256, 0, stream>>>(mft, Wp, bp, h, 512, 1024, gate, 0);
    gemm_k<3>  <<<dim3(4, 64),   256, 0, stream>>>(mft, Wg, bg, h, 512, 1024, gate, 0);
    cast_bf16<<<4096, 256, 0, stream>>>(h,     hbf,  1048576);
    cast_bf16<<<3072, 256, 0, stream>>>(fc1_w, w1bf, 786432);
    cast_bf16<<<1536, 256, 0, stream>>>(fc2_w, w2bf, 393216);
    gemm_mfma<1><<<dim3(24, 32), 256, 0, stream>>>(hbf,  w1bf,  fc1_b, hidbf,          4096, 3072, 1024);
    gemm_mfma<2><<<dim3(32, 4),  256, 0, stream>>>(w2bf, hidbf, fc2_b, out + 2097152,  512,  4096, 3072);
}

// Round 11
// 633.221 us; speedup vs baseline: 15.1883x; 1.2431x over previous
//
#include <hip/hip_runtime.h>
#include <math.h>

// B=64, L=512, C=64, E=64, F=257, PRED=512, H1=1024, H2=3072
// ---- workspace layout (f32 units), peak 17,047,552 = 68.19 MB (proven) ----
#define U_H     0            // [4096][1024]            -> 4194304
#define U_MFT   4194304      // [4096][512]             -> 6291456
#define U_XRE   6291456      // [64][257][64]           -> 7344128
#define U_XIM   7344128      //                         -> 8396800
#define U_KEEPI 8396800      // int[4096*32]            -> 8527872
#define U_KEEPW 8527872      //                         -> 8658944
#define U_XFILT 8658944      // [64][512][64]           -> 10756096
#define U_NORM  10756096     // [64][512][64]           -> 12853248
#define U_Q     6291456      // bf16 [64][512][64] over dead xre/xim (half of f32 slot)
#define U_K     12853248     // bf16 [64][512][64]
#define U_V     14950400     // bf16 V^T [64][64][512]           (peak 17047552)
#define U_HBF   6291456      // bf16 [4096][1024] = 2097152 u -> 8388608
#define U_HIDBF 8388608      // bf16 [4096][3072] = 6291456 u -> 14680064
#define U_W1BF  14680064     // bf16 [3072][1024] = 1572864 u -> 16252928
#define U_W2BF  16252928     // bf16 [512][3072]  =  786432 u -> 17039360

#define TWO_PI_OVER_512 0.012271846303085129

typedef __attribute__((ext_vector_type(8))) short short8;
typedef __attribute__((ext_vector_type(4))) float floatx4;

__device__ inline unsigned short f2bf(float f) {
    union { unsigned int i; float f; } x; x.f = f;
    unsigned int r = x.i + 0x7fff + ((x.i >> 16) & 1);
    return (unsigned short)(r >> 16);
}

// ===== 1. tiled DFT (proven round 7) =====
__global__ __launch_bounds__(256) void dft_tile(const float* __restrict__ x,
                                                float* __restrict__ xre,
                                                float* __restrict__ xim) {
    __shared__ float xs[64 * 64];
    __shared__ float ct[512], st[512];
    int tid = threadIdx.x;
    int b = blockIdx.y;
    int f0 = blockIdx.x * 64;
    for (int i = tid; i < 512; i += 256) {
        float s, c; sincosf((float)((double)i * TWO_PI_OVER_512), &s, &c);
        ct[i] = c; st[i] = s;
    }
    int c2 = (tid & 31) * 2;
    int fg = tid >> 5;
    int fb = f0 + fg * 8;
    float2 ar[8], ai[8];
    #pragma unroll
    for (int i = 0; i < 8; ++i) { ar[i] = make_float2(0.f, 0.f); ai[i] = make_float2(0.f, 0.f); }
    for (int t0 = 0; t0 < 512; t0 += 64) {
        __syncthreads();
        for (int i = tid; i < 4096; i += 256)
            xs[i] = x[(size_t)(b * 512 + t0) * 64 + i];
        __syncthreads();
        for (int tt = 0; tt < 64; ++tt) {
            float2 xv = *(float2*)&xs[tt * 64 + c2];
            int t = t0 + tt;
            int idx = (fb * t) & 511;
            #pragma unroll
            for (int i = 0; i < 8; ++i) {
                float cv = ct[idx], sv = st[idx];
                ar[i].x += xv.x * cv; ar[i].y += xv.y * cv;
                ai[i].x -= xv.x * sv; ai[i].y -= xv.y * sv;
                idx = (idx + t) & 511;
            }
        }
    }
    #pragma unroll
    for (int i = 0; i < 8; ++i) {
        int f = fb + i;
        if (f < 257) {
            *(float2*)&xre[((size_t)(b * 257) + f) * 64 + c2] = ar[i];
            *(float2*)&xim[((size_t)(b * 257) + f) * 64 + c2] = ai[i];
        }
    }
}

// ===== 2. block-per-row LDS-tree top-k (proven round 9) =====
__global__ __launch_bounds__(256) void topk_lds(const float* __restrict__ xre,
                                                const float* __restrict__ xim,
                                                int* __restrict__ keepi,
                                                float* __restrict__ keepw,
                                                const int* __restrict__ kptr) {
    __shared__ float vals[320];
    __shared__ float tv[256];
    __shared__ int   ti[256];
    int tid = threadIdx.x;
    int bc = blockIdx.x;
    int b = bc >> 6, c = bc & 63;
    int kk = *kptr; if (kk > 32) kk = 32;
    for (int f = tid; f < 320; f += 256) {
        if (f < 257) {
            size_t a = ((size_t)(b * 257) + f) * 64 + c;
            float re = xre[a], im = xim[a];
            vals[f] = sqrtf(re * re + im * im);
        } else vals[f] = -1.f;
    }
    __syncthreads();
    for (int j = 0; j < kk; ++j) {
        float v0 = vals[tid];
        int   i0 = tid;
        if (tid < 64) {
            float v1 = vals[tid + 256];
            if (v1 > v0) { v0 = v1; i0 = tid + 256; }
        }
        tv[tid] = v0; ti[tid] = i0;
        __syncthreads();
        for (int s = 128; s > 0; s >>= 1) {
            if (tid < s) {
                float ov = tv[tid + s]; int oi = ti[tid + s];
                if (ov > tv[tid] || (ov == tv[tid] && oi < ti[tid])) { tv[tid] = ov; ti[tid] = oi; }
            }
            __syncthreads();
        }
        if (tid == 0) {
            int bf = ti[0];
            keepi[bc * 32 + j] = bf;
            keepw[bc * 32 + j] = (bf == 0 || bf == 256) ? (1.f / 512.f) : (2.f / 512.f);
            vals[bf] = -1.f;
        }
        __syncthreads();
    }
}

// ===== 3. fused x_filt (proven round 7) =====
__global__ __launch_bounds__(256) void xfilt_fused(const float* __restrict__ x,
                                                   const float* __restrict__ xre,
                                                   const float* __restrict__ xim,
                                                   const int* __restrict__ keepi,
                                                   const float* __restrict__ keepw,
                                                   float* __restrict__ xfilt,
                                                   float* __restrict__ norm,
                                                   float* __restrict__ mft,
                                                   float* __restrict__ h,
                                                   const int* __restrict__ kptr) {
    __shared__ float ct[512], st[512];
    __shared__ int   kf[64 * 33];
    __shared__ float kre[64 * 33], kim[64 * 33];
    __shared__ float xs[64 * 65];
    __shared__ float ft[64 * 65];
    int tid = threadIdx.x;
    int b = blockIdx.y;
    int t0 = blockIdx.x * 64;
    int kk = *kptr; if (kk > 32) kk = 32;
    for (int i = tid; i < 512; i += 256) {
        float s, c; sincosf((float)((double)i * TWO_PI_OVER_512), &s, &c);
        ct[i] = c; st[i] = s;
    }
    for (int i = tid; i < 4096; i += 256) {
        int tl = i >> 6, c = i & 63;
        xs[tl * 65 + c] = x[((size_t)(b * 512) + t0 + tl) * 64 + c];
    }
    for (int e = tid; e < 64 * kk; e += 256) {
        int c = e / kk, j = e - c * kk;
        int bc = b * 64 + c;
        int f = keepi[bc * 32 + j];
        float w = keepw[bc * 32 + j];
        size_t a = ((size_t)(b * 257) + f) * 64 + c;
        kf[c * 33 + j]  = f;
        kre[c * 33 + j] = w * xre[a];
        kim[c * 33 + j] = w * xim[a];
    }
    __syncthreads();
    int l = tid & 63, w = tid >> 6;
    int t = t0 + l;
    for (int ci = 0; ci < 16; ++ci) {
        int c = w * 16 + ci;
        float acc = 0.f;
        for (int j = 0; j < kk; ++j) {
            int f = kf[c * 33 + j];
            int idx = (f * t) & 511;
            acc += kre[c * 33 + j] * ct[idx] - kim[c * 33 + j] * st[idx];
        }
        ft[c * 65 + l] = acc;
    }
    __syncthreads();
    for (int i = tid; i < 4096; i += 256) {
        int tl = i >> 6, c = i & 63;
        float v = ft[c * 65 + tl];
        size_t a = ((size_t)(b * 512) + t0 + tl) * 64 + c;
        xfilt[a] = v;
        norm[a]  = xs[tl * 65 + c] - v;
    }
    for (int i = tid; i < 4096; i += 256) {
        int cr = i >> 6, tl = i & 63;
        mft[((size_t)(b * 64) + cr) * 512 + t0 + tl] = ft[cr * 65 + tl];
        h[((size_t)(b * 64) + cr) * 1024 + 512 + t0 + tl] = xs[tl * 65 + cr];
    }
}

// ===== 4. QKV as tiled GEMM (gemm_k pattern): grid (3 groups, 512 token-tiles) =====
// group 0: q = xfilt @ wq^T  -> bf16 row-major
// group 1: k = norm  @ wk^T  -> bf16 row-major
// group 2: v = norm  @ wv^T  -> bf16 transposed vt[b][e][t] via LDS
__global__ __launch_bounds__(256) void qkv_gemm(const float* __restrict__ xfilt,
                                                const float* __restrict__ norm,
                                                const float* __restrict__ w,
                                                const float* __restrict__ bias,
                                                unsigned short* __restrict__ q,
                                                unsigned short* __restrict__ kmat,
                                                unsigned short* __restrict__ vt) {
    __shared__ float As[32 * 64];
    __shared__ float Bs[32 * 64];
    __shared__ unsigned short Cs[64 * 65];
    int tid = threadIdx.x;
    int tx = tid & 15, ty = tid >> 4;
    int grp = blockIdx.x;
    int m0 = blockIdx.y * 64;               // global token index (b*512 + t)
    int n0 = grp * 64;                      // output channel group
    const float* A = (grp == 0) ? xfilt : norm;
    float acc[4][4] = {};
    for (int k0 = 0; k0 < 64; k0 += 32) {
        __syncthreads();
        #pragma unroll
        for (int s = 0; s < 2; ++s) {
            int i4 = tid + s * 256;
            int row = i4 >> 3, kq = i4 & 7;
            float4 a4 = *(const float4*)&A[(size_t)(m0 + row) * 64 + k0 + kq * 4];
            float4 w4 = *(const float4*)&w[(size_t)(n0 + row) * 64 + k0 + kq * 4];
            int kb = kq * 4;
            As[(kb + 0) * 64 + row] = a4.x; As[(kb + 1) * 64 + row] = a4.y;
            As[(kb + 2) * 64 + row] = a4.z; As[(kb + 3) * 64 + row] = a4.w;
            Bs[(kb + 0) * 64 + row] = w4.x; Bs[(kb + 1) * 64 + row] = w4.y;
            Bs[(kb + 2) * 64 + row] = w4.z; Bs[(kb + 3) * 64 + row] = w4.w;
        }
        __syncthreads();
        #pragma unroll
        for (int kk = 0; kk < 32; ++kk) {
            float4 a4 = *(const float4*)&As[kk * 64 + (ty << 2)];
            float4 b4 = *(const float4*)&Bs[kk * 64 + (tx << 2)];
            #pragma unroll
            for (int i = 0; i < 4; ++i)
                #pragma unroll
                for (int j = 0; j < 4; ++j)
                    acc[i][j] += (&a4.x)[i] * (&b4.x)[j];
        }
    }
    int row0 = ty * 4, col0 = tx * 4;
    float4 bb = *(const float4*)&bias[n0 + col0];
    #pragma unroll
    for (int i = 0; i < 4; ++i) {
        float v0 = acc[i][0] + bb.x, v1 = acc[i][1] + bb.y;
        float v2 = acc[i][2] + bb.z, v3 = acc[i][3] + bb.w;
        ushort4 o;
        o.x = f2bf(v0); o.y = f2bf(v1); o.z = f2bf(v2); o.w = f2bf(v3);
        if (grp == 0) {
            *(ushort4*)&q[(size_t)(m0 + row0 + i) * 64 + col0] = o;
        } else if (grp == 1) {
            *(ushort4*)&kmat[(size_t)(m0 + row0 + i) * 64 + col0] = o;
        } else {
            Cs[(row0 + i) * 65 + col0 + 0] = o.x;
            Cs[(row0 + i) * 65 + col0 + 1] = o.y;
            Cs[(row0 + i) * 65 + col0 + 2] = o.z;
            Cs[(row0 + i) * 65 + col0 + 3] = o.w;
        }
    }
    if (grp == 2) {
        __syncthreads();
        int b = m0 >> 9, t0 = m0 & 511;
        for (int i2 = tid; i2 < 4096; i2 += 256) {
            int e = i2 >> 6, tl = i2 & 63;
            vt[((size_t)(b * 64) + e) * 512 + t0 + tl] = Cs[tl * 65 + e];
        }
    }
}

// ===== 5. MFMA attention + out-proj (proven round 10) =====
__global__ __launch_bounds__(256) void attn_mfma(const unsigned short* __restrict__ qbf,
                                                 const unsigned short* __restrict__ kbf,
                                                 const unsigned short* __restrict__ vtbf,
                                                 const float* __restrict__ ow,
                                                 const float* __restrict__ ob,
                                                 float* __restrict__ out) {
    __shared__ unsigned short Qs[64 * 72];
    __shared__ unsigned short KVs[64 * 72];
    __shared__ unsigned short Pw[4 * 16 * 520];
    __shared__ unsigned short Obs[64 * 72];
    __shared__ unsigned short OWs[64 * 72];
    int tid = threadIdx.x;
    int l = tid & 63, w = tid >> 6;
    int q = l >> 4, cl = l & 15;
    int b = blockIdx.y, i0 = blockIdx.x * 64;

    for (int i = tid; i < 1024; i += 256) {
        int r = i >> 4, e4 = (i & 15) * 4;
        *(ushort4*)&Qs[r * 72 + e4] = *(const ushort4*)&qbf[((size_t)(b * 512) + i0 + r) * 64 + e4];
    }
    for (int i = tid; i < 1024; i += 256) {
        int o = i >> 4, e4 = (i & 15) * 4;
        float4 v = *(const float4*)&ow[o * 64 + e4];
        ushort4 u; u.x = f2bf(v.x); u.y = f2bf(v.y); u.z = f2bf(v.z); u.w = f2bf(v.w);
        *(ushort4*)&OWs[o * 72 + e4] = u;
    }
    __syncthreads();
    short8 aq0 = *(short8*)&Qs[(w * 16 + cl) * 72 + q * 8];
    short8 aq1 = *(short8*)&Qs[(w * 16 + cl) * 72 + 32 + q * 8];

    floatx4 s[32];
    #pragma unroll
    for (int f = 0; f < 32; ++f) s[f] = (floatx4){0.f, 0.f, 0.f, 0.f};

    #pragma unroll
    for (int ch = 0; ch < 8; ++ch) {
        __syncthreads();
        for (int i = tid; i < 1024; i += 256) {
            int jj = i >> 4, e4 = (i & 15) * 4;
            *(ushort4*)&KVs[jj * 72 + e4] =
                *(const ushort4*)&kbf[((size_t)(b * 512) + ch * 64 + jj) * 64 + e4];
        }
        __syncthreads();
        #pragma unroll
        for (int jt = 0; jt < 4; ++jt) {
            short8 b0 = *(short8*)&KVs[(jt * 16 + cl) * 72 + q * 8];
            short8 b1 = *(short8*)&KVs[(jt * 16 + cl) * 72 + 32 + q * 8];
            s[ch * 4 + jt] = __builtin_amdgcn_mfma_f32_16x16x32_bf16(aq0, b0, s[ch * 4 + jt], 0, 0, 0);
            s[ch * 4 + jt] = __builtin_amdgcn_mfma_f32_16x16x32_bf16(aq1, b1, s[ch * 4 + jt], 0, 0, 0);
        }
    }

    float invl[4];
    #pragma unroll
    for (int r = 0; r < 4; ++r) {
        float m = -1e30f;
        #pragma unroll
        for (int f = 0; f < 32; ++f) m = fmaxf(m, s[f][r]);
        m = fmaxf(m, __shfl_xor(m, 1)); m = fmaxf(m, __shfl_xor(m, 2));
        m = fmaxf(m, __shfl_xor(m, 4)); m = fmaxf(m, __shfl_xor(m, 8));
        float sum = 0.f;
        #pragma unroll
        for (int f = 0; f < 32; ++f) {
            float p = expf((s[f][r] - m) * 0.125f);
            s[f][r] = p; sum += p;
        }
        sum += __shfl_xor(sum, 1); sum += __shfl_xor(sum, 2);
        sum += __shfl_xor(sum, 4); sum += __shfl_xor(sum, 8);
        invl[r] = 1.f / sum;
    }

    #pragma unroll
    for (int f = 0; f < 32; ++f)
        #pragma unroll
        for (int r = 0; r < 4; ++r)
            Pw[w * 8320 + (q * 4 + r) * 520 + f * 16 + cl] = f2bf(s[f][r]);

    floatx4 o4[4];
    #pragma unroll
    for (int nt = 0; nt < 4; ++nt) o4[nt] = (floatx4){0.f, 0.f, 0.f, 0.f};
    #pragma unroll
    for (int ch = 0; ch < 8; ++ch) {
        __syncthreads();
        for (int i = tid; i < 1024; i += 256) {
            int e = i >> 4, j4 = (i & 15) * 4;
            *(ushort4*)&KVs[e * 72 + j4] =
                *(const ushort4*)&vtbf[((size_t)(b * 64) + e) * 512 + ch * 64 + j4];
        }
        __syncthreads();
        #pragma unroll
        for (int ks = 0; ks < 2; ++ks) {
            short8 ap = *(short8*)&Pw[w * 8320 + cl * 520 + ch * 64 + ks * 32 + q * 8];
            #pragma unroll
            for (int nt = 0; nt < 4; ++nt) {
                short8 bv = *(short8*)&KVs[(nt * 16 + cl) * 72 + ks * 32 + q * 8];
                o4[nt] = __builtin_amdgcn_mfma_f32_16x16x32_bf16(ap, bv, o4[nt], 0, 0, 0);
            }
        }
    }

    #pragma unroll
    for (int nt = 0; nt < 4; ++nt)
        #pragma unroll
        for (int r = 0; r < 4; ++r)
            Obs[(w * 16 + q * 4 + r) * 72 + nt * 16 + cl] = f2bf(o4[nt][r] * invl[r]);
    __syncthreads();
    floatx4 acc2[4];
    #pragma unroll
    for (int nt = 0; nt < 4; ++nt) acc2[nt] = (floatx4){0.f, 0.f, 0.f, 0.f};
    #pragma unroll
    for (int ks = 0; ks < 2; ++ks) {
        short8 ao = *(short8*)&Obs[(w * 16 + cl) * 72 + ks * 32 + q * 8];
        #pragma unroll
        for (int nt = 0; nt < 4; ++nt) {
            short8 bo = *(short8*)&OWs[(nt * 16 + cl) * 72 + ks * 32 + q * 8];
            acc2[nt] = __builtin_amdgcn_mfma_f32_16x16x32_bf16(ao, bo, acc2[nt], 0, 0, 0);
        }
    }
    #pragma unroll
    for (int nt = 0; nt < 4; ++nt) {
        float bb = ob[nt * 16 + cl];
        #pragma unroll
        for (int r = 0; r < 4; ++r)
            out[((size_t)(b * 512) + i0 + w * 16 + q * 4 + r) * 64 + nt * 16 + cl] = acc2[nt][r] + bb;
    }
}

// ===== 6. tiled fp32 GEMM (proven round 4) — FAN epilogues only =====
template<int EPI>
__global__ __launch_bounds__(256) void gemm_k(const float* __restrict__ A,
                                              const float* __restrict__ W,
                                              const float* __restrict__ bias,
                                              float* __restrict__ C,
                                              int K, int ldc,
                                              const float* __restrict__ gate,
                                              int moff) {
    __shared__ float As[32 * 64];
    __shared__ float Bs[32 * 64];
    int tid = threadIdx.x;
    int tx = tid & 15, ty = tid >> 4;
    int m0 = blockIdx.y * 64, n0 = blockIdx.x * 64;
    float acc[4][4] = {};
    for (int k0 = 0; k0 < K; k0 += 32) {
        __syncthreads();
        #pragma unroll
        for (int s = 0; s < 2; ++s) {
            int i4 = tid + s * 256;
            int row = i4 >> 3, kq = i4 & 7;
            float4 a4 = *(const float4*)&A[(size_t)(m0 + row) * K + k0 + kq * 4];
            float4 w4 = *(const float4*)&W[(size_t)(n0 + row) * K + k0 + kq * 4];
            int kb = kq * 4;
            As[(kb + 0) * 64 + row] = a4.x; As[(kb + 1) * 64 + row] = a4.y;
            As[(kb + 2) * 64 + row] = a4.z; As[(kb + 3) * 64 + row] = a4.w;
            Bs[(kb + 0) * 64 + row] = w4.x; Bs[(kb + 1) * 64 + row] = w4.y;
            Bs[(kb + 2) * 64 + row] = w4.z; Bs[(kb + 3) * 64 + row] = w4.w;
        }
        __syncthreads();
        #pragma unroll
        for (int kk = 0; kk < 32; ++kk) {
            float4 a4 = *(const float4*)&As[kk * 64 + (ty << 2)];
            float4 b4 = *(const float4*)&Bs[kk * 64 + (tx << 2)];
            #pragma unroll
            for (int i = 0; i < 4; ++i)
                #pragma unroll
                for (int j = 0; j < 4; ++j)
                    acc[i][j] += (&a4.x)[i] * (&b4.x)[j];
        }
    }
    int row0 = m0 + ty * 4, col0 = n0 + tx * 4;
    float4 bb = *(const float4*)&bias[col0];
    float gt = 1.f / (1.f + expf(-gate[0]));
    #pragma unroll
    for (int i = 0; i < 4; ++i) {
        int row = row0 + i;
        float v0 = acc[i][0] + bb.x, v1 = acc[i][1] + bb.y;
        float v2 = acc[i][2] + bb.z, v3 = acc[i][3] + bb.w;
        if (EPI == 2) {
            float4 co = make_float4(gt * cosf(v0), gt * cosf(v1), gt * cosf(v2), gt * cosf(v3));
            float4 si = make_float4(gt * sinf(v0), gt * sinf(v1), gt * sinf(v2), gt * sinf(v3));
            *(float4*)&C[(size_t)row * 1024 + col0] = co;
            *(float4*)&C[(size_t)row * 1024 + 128 + col0] = si;
        } else if (EPI == 3) {
            float ig = 1.f - gt;
            float4 o = make_float4(
                ig * 0.5f * v0 * (1.f + erff(v0 * 0.70710678118f)),
                ig * 0.5f * v1 * (1.f + erff(v1 * 0.70710678118f)),
                ig * 0.5f * v2 * (1.f + erff(v2 * 0.70710678118f)),
                ig * 0.5f * v3 * (1.f + erff(v3 * 0.70710678118f)));
            *(float4*)&C[(size_t)row * 1024 + 256 + col0] = o;
        }
    }
}

// ===== 7. cast f32 -> bf16 =====
__global__ __launch_bounds__(256) void cast_bf16(const float* __restrict__ in,
                                                 unsigned short* __restrict__ out, int n4) {
    int i = blockIdx.x * 256 + threadIdx.x;
    if (i < n4) {
        float4 v = *(const float4*)&in[(size_t)i * 4];
        ushort4 o;
        o.x = f2bf(v.x); o.y = f2bf(v.y); o.z = f2bf(v.z); o.w = f2bf(v.w);
        *(ushort4*)&out[(size_t)i * 4] = o;
    }
}

// ===== 8. bf16 MFMA GEMM (proven round 6): C = A[M,K] @ B[N,K]^T, 128x128, BK=64 =====
template<int EPI>
__global__ __launch_bounds__(256) void gemm_mfma(const unsigned short* __restrict__ A,
                                                 const unsigned short* __restrict__ B,
                                                 const float* __restrict__ bias,
                                                 void* __restrict__ Cout,
                                                 int M, int N, int K) {
    __shared__ unsigned short As[8192];
    __shared__ unsigned short Bs[8192];
    int tid = threadIdx.x;
    int l = tid & 63, w = tid >> 6;
    int q = l >> 4, cl = l & 15;
    int wm = w >> 1, wn = w & 1;
    int m0 = blockIdx.y * 128, n0 = blockIdx.x * 128;
    floatx4 acc[4][4];
    #pragma unroll
    for (int i = 0; i < 4; ++i)
        #pragma unroll
        for (int j = 0; j < 4; ++j)
            acc[i][j] = (floatx4){0.f, 0.f, 0.f, 0.f};

    for (int k0 = 0; k0 < K; k0 += 64) {
        __syncthreads();
        #pragma unroll
        for (int ci = 0; ci < 8; ++ci) {
            int cid = w * 8 + ci;
            int isB = cid >> 4;
            int c = cid & 15;
            int cq = c >> 3, cks = (c >> 2) & 1, cf = c & 3;
            int row = cq * 64 + cf * 16 + cl;
            int col = k0 + cks * 32 + q * 8;
            const unsigned short* gp = isB ? (B + (size_t)(n0 + row) * K + col)
                                           : (A + (size_t)(m0 + row) * K + col);
            unsigned short* lp = (isB ? Bs : As) + c * 512;
            __builtin_amdgcn_global_load_lds((const __attribute__((address_space(1))) void*)gp,
                                             (__attribute__((address_space(3))) void*)lp,
                                             16, 0, 0);
        }
        __syncthreads();
        #pragma unroll
        for (int ks = 0; ks < 2; ++ks) {
            short8 af[4], bg[4];
            #pragma unroll
            for (int f = 0; f < 4; ++f) {
                af[f] = *(short8*)&As[(wm * 8 + ks * 4 + f) * 512 + l * 8];
                bg[f] = *(short8*)&Bs[(wn * 8 + ks * 4 + f) * 512 + l * 8];
            }
            #pragma unroll
            for (int i = 0; i < 4; ++i)
                #pragma unroll
                for (int j = 0; j < 4; ++j)
                    acc[i][j] = __builtin_amdgcn_mfma_f32_16x16x32_bf16(af[i], bg[j], acc[i][j], 0, 0, 0);
        }
    }

    if (EPI == 1) {
        unsigned short* Cb = (unsigned short*)Cout;
        #pragma unroll
        for (int j = 0; j < 4; ++j) {
            int col = n0 + wn * 64 + j * 16 + cl;
            float bb = bias[col];
            #pragma unroll
            for (int i = 0; i < 4; ++i) {
                int rowb = m0 + wm * 64 + i * 16 + q * 4;
                #pragma unroll
                for (int r = 0; r < 4; ++r) {
                    float v = acc[i][j][r] + bb;
                    Cb[(size_t)(rowb + r) * N + col] = f2bf(fmaxf(v, 0.f));
                }
            }
        }
    } else {
        float* Ob = (float*)Cout;
        int bidx = (n0 >> 6) + wn;
        #pragma unroll
        for (int i = 0; i < 4; ++i) {
            #pragma unroll
            for (int r = 0; r < 4; ++r) {
                int t = m0 + wm * 64 + i * 16 + q * 4 + r;
                float bb = bias[t];
                #pragma unroll
                for (int j = 0; j < 4; ++j) {
                    int c = j * 16 + cl;
                    Ob[((size_t)bidx * 512 + t) * 64 + c] = acc[i][j][r] + bb;
                }
            }
        }
    }
}

extern "C" void kernel_launch(void* const* d_in, const int* in_sizes, int n_in,
                              void* d_out, int out_size, void* d_ws, size_t ws_size,
                              hipStream_t stream) {
    const float* x         = (const float*)d_in[0];
    const float* in_proj_w = (const float*)d_in[1];
    const float* in_proj_b = (const float*)d_in[2];
    const float* out_w     = (const float*)d_in[3];
    const float* out_b     = (const float*)d_in[4];
    const float* Wp        = (const float*)d_in[5];
    const float* bp        = (const float*)d_in[6];
    const float* Wg        = (const float*)d_in[7];
    const float* bg        = (const float*)d_in[8];
    const float* gate      = (const float*)d_in[9];
    const float* fc1_w     = (const float*)d_in[10];
    const float* fc1_b     = (const float*)d_in[11];
    const float* fc2_w     = (const float*)d_in[12];
    const float* fc2_b     = (const float*)d_in[13];
    const int*   kptr      = (const int*)d_in[14];
    float* ws  = (float*)d_ws;
    float* out = (float*)d_out;

    float* h     = ws + U_H;
    float* mft   = ws + U_MFT;
    float* xre   = ws + U_XRE;
    float* xim   = ws + U_XIM;
    int*   keepi = (int*)(ws + U_KEEPI);
    float* keepw = ws + U_KEEPW;
    float* xfilt = ws + U_XFILT;
    float* norm  = ws + U_NORM;
    unsigned short* qb    = (unsigned short*)(ws + U_Q);
    unsigned short* kb    = (unsigned short*)(ws + U_K);
    unsigned short* vtb   = (unsigned short*)(ws + U_V);
    unsigned short* hbf   = (unsigned short*)(ws + U_HBF);
    unsigned short* hidbf = (unsigned short*)(ws + U_HIDBF);
    unsigned short* w1bf  = (unsigned short*)(ws + U_W1BF);
    unsigned short* w2bf  = (unsigned short*)(ws + U_W2BF);

    dft_tile   <<<dim3(5, 64),   256, 0, stream>>>(x, xre, xim);
    topk_lds   <<<dim3(4096),    256, 0, stream>>>(xre, xim, keepi, keepw, kptr);
    xfilt_fused<<<dim3(8, 64),   256, 0, stream>>>(x, xre, xim, keepi, keepw, xfilt, norm, mft, h, kptr);
    qkv_gemm   <<<dim3(3, 512),  256, 0, stream>>>(xfilt, norm, in_proj_w, in_proj_b, qb, kb, vtb);
    attn_mfma  <<<dim3(8, 64),   256, 0, stream>>>(qb, kb, vtb, out_w, out_b, out);
    gemm_k<2>  <<<dim3(2, 64),   256, 0, stream>>>(mft, Wp, bp, h, 512, 1024, gate, 0);
    gemm_k<3>  <<<dim3(4, 64),   256, 0, stream>>>(mft, Wg, bg, h, 512, 1024, gate, 0);
    cast_bf16<<<4096, 256, 0, stream>>>(h,     hbf,  1048576);
    cast_bf16<<<3072, 256, 0, stream>>>(fc1_w, w1bf, 786432);
    cast_bf16<<<1536, 256, 0, stream>>>(fc2_w, w2bf, 393216);
    gemm_mfma<1><<<dim3(24, 32), 256, 0, stream>>>(hbf,  w1bf,  fc1_b, hidbf,          4096, 3072, 1024);
    gemm_mfma<2><<<dim3(32, 4),  256, 0, stream>>>(w2bf, hidbf, fc2_b, out + 2097152,  512,  4096, 3072);
}

// Round 12
// 624.925 us; speedup vs baseline: 15.3900x; 1.0133x over previous
//
#include <hip/hip_runtime.h>
#include <math.h>

// B=64, L=512, C=64, E=64, F=257, PRED=512, H1=1024, H2=3072
// ---- workspace layout (f32 units), peak 17,047,552 = 68.19 MB (proven) ----
#define U_H     0            // [4096][1024]            -> 4194304
#define U_MFT   4194304      // [4096][512]             -> 6291456
#define U_XRE   6291456      // [64][257][64]           -> 7344128
#define U_XIM   7344128      //                         -> 8396800
#define U_KEEPI 8396800      // int[4096*32]            -> 8527872
#define U_KEEPW 8527872      //                         -> 8658944
#define U_XFILT 8658944      // [64][512][64]           -> 10756096
#define U_NORM  10756096     // [64][512][64]           -> 12853248
#define U_Q     6291456      // bf16 [64][512][64] over dead xre/xim (half of f32 slot)
#define U_K     12853248     // bf16 [64][512][64]
#define U_V     14950400     // bf16 V^T [64][64][512]           (peak 17047552)
#define U_HBF   6291456      // bf16 [4096][1024] = 2097152 u -> 8388608
#define U_HIDBF 8388608      // bf16 [4096][3072] = 6291456 u -> 14680064
#define U_W1BF  14680064     // bf16 [3072][1024] = 1572864 u -> 16252928
#define U_W2BF  16252928     // bf16 [512][3072]  =  786432 u -> 17039360
// DFT partial slices (z=1..3), live only between dft_split and dft_reduce,
// overlaying the not-yet-written xfilt/norm region:
#define U_PART  8658944      // 3 x 2105344 floats -> ends 14974976 (< 17047552)

#define TWO_PI_OVER_512 0.012271846303085129

typedef __attribute__((ext_vector_type(8))) short short8;
typedef __attribute__((ext_vector_type(4))) float floatx4;

__device__ inline unsigned short f2bf(float f) {
    union { unsigned int i; float f; } x; x.f = f;
    unsigned int r = x.i + 0x7fff + ((x.i >> 16) & 1);
    return (unsigned short)(r >> 16);
}

// ===== 1a. split DFT: grid (5 f-tiles, 64 b, 4 t-chunks); same math as proven dft_tile =====
__global__ __launch_bounds__(256) void dft_split(const float* __restrict__ x,
                                                 float* __restrict__ xre,
                                                 float* __restrict__ xim,
                                                 float* __restrict__ part) {
    __shared__ float xs[64 * 64];
    __shared__ float ct[512], st[512];
    int tid = threadIdx.x;
    int b = blockIdx.y;
    int f0 = blockIdx.x * 64;
    int z = blockIdx.z;
    for (int i = tid; i < 512; i += 256) {
        float s, c; sincosf((float)((double)i * TWO_PI_OVER_512), &s, &c);
        ct[i] = c; st[i] = s;
    }
    int c2 = (tid & 31) * 2;
    int fg = tid >> 5;
    int fb = f0 + fg * 8;
    float2 ar[8], ai[8];
    #pragma unroll
    for (int i = 0; i < 8; ++i) { ar[i] = make_float2(0.f, 0.f); ai[i] = make_float2(0.f, 0.f); }
    for (int sub = 0; sub < 2; ++sub) {
        int t0 = z * 128 + sub * 64;
        __syncthreads();
        for (int i = tid; i < 4096; i += 256)
            xs[i] = x[(size_t)(b * 512 + t0) * 64 + i];
        __syncthreads();
        for (int tt = 0; tt < 64; ++tt) {
            float2 xv = *(float2*)&xs[tt * 64 + c2];
            int t = t0 + tt;
            int idx = (fb * t) & 511;
            #pragma unroll
            for (int i = 0; i < 8; ++i) {
                float cv = ct[idx], sv = st[idx];
                ar[i].x += xv.x * cv; ar[i].y += xv.y * cv;
                ai[i].x -= xv.x * sv; ai[i].y -= xv.y * sv;
                idx = (idx + t) & 511;
            }
        }
    }
    float* dre = (z == 0) ? xre : (part + (size_t)(z - 1) * 2105344);
    float* dim_ = (z == 0) ? xim : (part + (size_t)(z - 1) * 2105344 + 1052672);
    #pragma unroll
    for (int i = 0; i < 8; ++i) {
        int f = fb + i;
        if (f < 257) {
            *(float2*)&dre[((size_t)(b * 257) + f) * 64 + c2] = ar[i];
            *(float2*)&dim_[((size_t)(b * 257) + f) * 64 + c2] = ai[i];
        }
    }
}

// ===== 1b. reduce partials: xre/xim (flat 2105344 floats) += 3 slices =====
__global__ __launch_bounds__(256) void dft_reduce(float* __restrict__ xreflat,
                                                  const float* __restrict__ part) {
    int i = blockIdx.x * 256 + threadIdx.x;      // float4 index, 526336 total
    if (i < 526336) {
        float4 a  = *(float4*)&xreflat[(size_t)i * 4];
        float4 p0 = *(const float4*)&part[(size_t)i * 4];
        float4 p1 = *(const float4*)&part[2105344 + (size_t)i * 4];
        float4 p2 = *(const float4*)&part[4210688 + (size_t)i * 4];
        a.x += p0.x + p1.x + p2.x;
        a.y += p0.y + p1.y + p2.y;
        a.z += p0.z + p1.z + p2.z;
        a.w += p0.w + p1.w + p2.w;
        *(float4*)&xreflat[(size_t)i * 4] = a;
    }
}

// ===== 2. block-per-row LDS-tree top-k (proven round 9) =====
__global__ __launch_bounds__(256) void topk_lds(const float* __restrict__ xre,
                                                const float* __restrict__ xim,
                                                int* __restrict__ keepi,
                                                float* __restrict__ keepw,
                                                const int* __restrict__ kptr) {
    __shared__ float vals[320];
    __shared__ float tv[256];
    __shared__ int   ti[256];
    int tid = threadIdx.x;
    int bc = blockIdx.x;
    int b = bc >> 6, c = bc & 63;
    int kk = *kptr; if (kk > 32) kk = 32;
    for (int f = tid; f < 320; f += 256) {
        if (f < 257) {
            size_t a = ((size_t)(b * 257) + f) * 64 + c;
            float re = xre[a], im = xim[a];
            vals[f] = sqrtf(re * re + im * im);
        } else vals[f] = -1.f;
    }
    __syncthreads();
    for (int j = 0; j < kk; ++j) {
        float v0 = vals[tid];
        int   i0 = tid;
        if (tid < 64) {
            float v1 = vals[tid + 256];
            if (v1 > v0) { v0 = v1; i0 = tid + 256; }
        }
        tv[tid] = v0; ti[tid] = i0;
        __syncthreads();
        for (int s = 128; s > 0; s >>= 1) {
            if (tid < s) {
                float ov = tv[tid + s]; int oi = ti[tid + s];
                if (ov > tv[tid] || (ov == tv[tid] && oi < ti[tid])) { tv[tid] = ov; ti[tid] = oi; }
            }
            __syncthreads();
        }
        if (tid == 0) {
            int bf = ti[0];
            keepi[bc * 32 + j] = bf;
            keepw[bc * 32 + j] = (bf == 0 || bf == 256) ? (1.f / 512.f) : (2.f / 512.f);
            vals[bf] = -1.f;
        }
        __syncthreads();
    }
}

// ===== 3. fused x_filt (proven round 7) =====
__global__ __launch_bounds__(256) void xfilt_fused(const float* __restrict__ x,
                                                   const float* __restrict__ xre,
                                                   const float* __restrict__ xim,
                                                   const int* __restrict__ keepi,
                                                   const float* __restrict__ keepw,
                                                   float* __restrict__ xfilt,
                                                   float* __restrict__ norm,
                                                   float* __restrict__ mft,
                                                   float* __restrict__ h,
                                                   const int* __restrict__ kptr) {
    __shared__ float ct[512], st[512];
    __shared__ int   kf[64 * 33];
    __shared__ float kre[64 * 33], kim[64 * 33];
    __shared__ float xs[64 * 65];
    __shared__ float ft[64 * 65];
    int tid = threadIdx.x;
    int b = blockIdx.y;
    int t0 = blockIdx.x * 64;
    int kk = *kptr; if (kk > 32) kk = 32;
    for (int i = tid; i < 512; i += 256) {
        float s, c; sincosf((float)((double)i * TWO_PI_OVER_512), &s, &c);
        ct[i] = c; st[i] = s;
    }
    for (int i = tid; i < 4096; i += 256) {
        int tl = i >> 6, c = i & 63;
        xs[tl * 65 + c] = x[((size_t)(b * 512) + t0 + tl) * 64 + c];
    }
    for (int e = tid; e < 64 * kk; e += 256) {
        int c = e / kk, j = e - c * kk;
        int bc = b * 64 + c;
        int f = keepi[bc * 32 + j];
        float w = keepw[bc * 32 + j];
        size_t a = ((size_t)(b * 257) + f) * 64 + c;
        kf[c * 33 + j]  = f;
        kre[c * 33 + j] = w * xre[a];
        kim[c * 33 + j] = w * xim[a];
    }
    __syncthreads();
    int l = tid & 63, w = tid >> 6;
    int t = t0 + l;
    for (int ci = 0; ci < 16; ++ci) {
        int c = w * 16 + ci;
        float acc = 0.f;
        for (int j = 0; j < kk; ++j) {
            int f = kf[c * 33 + j];
            int idx = (f * t) & 511;
            acc += kre[c * 33 + j] * ct[idx] - kim[c * 33 + j] * st[idx];
        }
        ft[c * 65 + l] = acc;
    }
    __syncthreads();
    for (int i = tid; i < 4096; i += 256) {
        int tl = i >> 6, c = i & 63;
        float v = ft[c * 65 + tl];
        size_t a = ((size_t)(b * 512) + t0 + tl) * 64 + c;
        xfilt[a] = v;
        norm[a]  = xs[tl * 65 + c] - v;
    }
    for (int i = tid; i < 4096; i += 256) {
        int cr = i >> 6, tl = i & 63;
        mft[((size_t)(b * 64) + cr) * 512 + t0 + tl] = ft[cr * 65 + tl];
        h[((size_t)(b * 64) + cr) * 1024 + 512 + t0 + tl] = xs[tl * 65 + cr];
    }
}

// ===== 4. QKV as tiled GEMM (proven round 11) =====
__global__ __launch_bounds__(256) void qkv_gemm(const float* __restrict__ xfilt,
                                                const float* __restrict__ norm,
                                                const float* __restrict__ w,
                                                const float* __restrict__ bias,
                                                unsigned short* __restrict__ q,
                                                unsigned short* __restrict__ kmat,
                                                unsigned short* __restrict__ vt) {
    __shared__ float As[32 * 64];
    __shared__ float Bs[32 * 64];
    __shared__ unsigned short Cs[64 * 65];
    int tid = threadIdx.x;
    int tx = tid & 15, ty = tid >> 4;
    int grp = blockIdx.x;
    int m0 = blockIdx.y * 64;
    int n0 = grp * 64;
    const float* A = (grp == 0) ? xfilt : norm;
    float acc[4][4] = {};
    for (int k0 = 0; k0 < 64; k0 += 32) {
        __syncthreads();
        #pragma unroll
        for (int s = 0; s < 2; ++s) {
            int i4 = tid + s * 256;
            int row = i4 >> 3, kq = i4 & 7;
            float4 a4 = *(const float4*)&A[(size_t)(m0 + row) * 64 + k0 + kq * 4];
            float4 w4 = *(const float4*)&w[(size_t)(n0 + row) * 64 + k0 + kq * 4];
            int kb = kq * 4;
            As[(kb + 0) * 64 + row] = a4.x; As[(kb + 1) * 64 + row] = a4.y;
            As[(kb + 2) * 64 + row] = a4.z; As[(kb + 3) * 64 + row] = a4.w;
            Bs[(kb + 0) * 64 + row] = w4.x; Bs[(kb + 1) * 64 + row] = w4.y;
            Bs[(kb + 2) * 64 + row] = w4.z; Bs[(kb + 3) * 64 + row] = w4.w;
        }
        __syncthreads();
        #pragma unroll
        for (int kk = 0; kk < 32; ++kk) {
            float4 a4 = *(const float4*)&As[kk * 64 + (ty << 2)];
            float4 b4 = *(const float4*)&Bs[kk * 64 + (tx << 2)];
            #pragma unroll
            for (int i = 0; i < 4; ++i)
                #pragma unroll
                for (int j = 0; j < 4; ++j)
                    acc[i][j] += (&a4.x)[i] * (&b4.x)[j];
        }
    }
    int row0 = ty * 4, col0 = tx * 4;
    float4 bb = *(const float4*)&bias[n0 + col0];
    #pragma unroll
    for (int i = 0; i < 4; ++i) {
        float v0 = acc[i][0] + bb.x, v1 = acc[i][1] + bb.y;
        float v2 = acc[i][2] + bb.z, v3 = acc[i][3] + bb.w;
        ushort4 o;
        o.x = f2bf(v0); o.y = f2bf(v1); o.z = f2bf(v2); o.w = f2bf(v3);
        if (grp == 0) {
            *(ushort4*)&q[(size_t)(m0 + row0 + i) * 64 + col0] = o;
        } else if (grp == 1) {
            *(ushort4*)&kmat[(size_t)(m0 + row0 + i) * 64 + col0] = o;
        } else {
            Cs[(row0 + i) * 65 + col0 + 0] = o.x;
            Cs[(row0 + i) * 65 + col0 + 1] = o.y;
            Cs[(row0 + i) * 65 + col0 + 2] = o.z;
            Cs[(row0 + i) * 65 + col0 + 3] = o.w;
        }
    }
    if (grp == 2) {
        __syncthreads();
        int b = m0 >> 9, t0 = m0 & 511;
        for (int i2 = tid; i2 < 4096; i2 += 256) {
            int e = i2 >> 6, tl = i2 & 63;
            vt[((size_t)(b * 64) + e) * 512 + t0 + tl] = Cs[tl * 65 + e];
        }
    }
}

// ===== 5. MFMA attention + out-proj (proven round 10) =====
__global__ __launch_bounds__(256) void attn_mfma(const unsigned short* __restrict__ qbf,
                                                 const unsigned short* __restrict__ kbf,
                                                 const unsigned short* __restrict__ vtbf,
                                                 const float* __restrict__ ow,
                                                 const float* __restrict__ ob,
                                                 float* __restrict__ out) {
    __shared__ unsigned short Qs[64 * 72];
    __shared__ unsigned short KVs[64 * 72];
    __shared__ unsigned short Pw[4 * 16 * 520];
    __shared__ unsigned short Obs[64 * 72];
    __shared__ unsigned short OWs[64 * 72];
    int tid = threadIdx.x;
    int l = tid & 63, w = tid >> 6;
    int q = l >> 4, cl = l & 15;
    int b = blockIdx.y, i0 = blockIdx.x * 64;

    for (int i = tid; i < 1024; i += 256) {
        int r = i >> 4, e4 = (i & 15) * 4;
        *(ushort4*)&Qs[r * 72 + e4] = *(const ushort4*)&qbf[((size_t)(b * 512) + i0 + r) * 64 + e4];
    }
    for (int i = tid; i < 1024; i += 256) {
        int o = i >> 4, e4 = (i & 15) * 4;
        float4 v = *(const float4*)&ow[o * 64 + e4];
        ushort4 u; u.x = f2bf(v.x); u.y = f2bf(v.y); u.z = f2bf(v.z); u.w = f2bf(v.w);
        *(ushort4*)&OWs[o * 72 + e4] = u;
    }
    __syncthreads();
    short8 aq0 = *(short8*)&Qs[(w * 16 + cl) * 72 + q * 8];
    short8 aq1 = *(short8*)&Qs[(w * 16 + cl) * 72 + 32 + q * 8];

    floatx4 s[32];
    #pragma unroll
    for (int f = 0; f < 32; ++f) s[f] = (floatx4){0.f, 0.f, 0.f, 0.f};

    #pragma unroll
    for (int ch = 0; ch < 8; ++ch) {
        __syncthreads();
        for (int i = tid; i < 1024; i += 256) {
            int jj = i >> 4, e4 = (i & 15) * 4;
            *(ushort4*)&KVs[jj * 72 + e4] =
                *(const ushort4*)&kbf[((size_t)(b * 512) + ch * 64 + jj) * 64 + e4];
        }
        __syncthreads();
        #pragma unroll
        for (int jt = 0; jt < 4; ++jt) {
            short8 b0 = *(short8*)&KVs[(jt * 16 + cl) * 72 + q * 8];
            short8 b1 = *(short8*)&KVs[(jt * 16 + cl) * 72 + 32 + q * 8];
            s[ch * 4 + jt] = __builtin_amdgcn_mfma_f32_16x16x32_bf16(aq0, b0, s[ch * 4 + jt], 0, 0, 0);
            s[ch * 4 + jt] = __builtin_amdgcn_mfma_f32_16x16x32_bf16(aq1, b1, s[ch * 4 + jt], 0, 0, 0);
        }
    }

    float invl[4];
    #pragma unroll
    for (int r = 0; r < 4; ++r) {
        float m = -1e30f;
        #pragma unroll
        for (int f = 0; f < 32; ++f) m = fmaxf(m, s[f][r]);
        m = fmaxf(m, __shfl_xor(m, 1)); m = fmaxf(m, __shfl_xor(m, 2));
        m = fmaxf(m, __shfl_xor(m, 4)); m = fmaxf(m, __shfl_xor(m, 8));
        float sum = 0.f;
        #pragma unroll
        for (int f = 0; f < 32; ++f) {
            float p = expf((s[f][r] - m) * 0.125f);
            s[f][r] = p; sum += p;
        }
        sum += __shfl_xor(sum, 1); sum += __shfl_xor(sum, 2);
        sum += __shfl_xor(sum, 4); sum += __shfl_xor(sum, 8);
        invl[r] = 1.f / sum;
    }

    #pragma unroll
    for (int f = 0; f < 32; ++f)
        #pragma unroll
        for (int r = 0; r < 4; ++r)
            Pw[w * 8320 + (q * 4 + r) * 520 + f * 16 + cl] = f2bf(s[f][r]);

    floatx4 o4[4];
    #pragma unroll
    for (int nt = 0; nt < 4; ++nt) o4[nt] = (floatx4){0.f, 0.f, 0.f, 0.f};
    #pragma unroll
    for (int ch = 0; ch < 8; ++ch) {
        __syncthreads();
        for (int i = tid; i < 1024; i += 256) {
            int e = i >> 4, j4 = (i & 15) * 4;
            *(ushort4*)&KVs[e * 72 + j4] =
                *(const ushort4*)&vtbf[((size_t)(b * 64) + e) * 512 + ch * 64 + j4];
        }
        __syncthreads();
        #pragma unroll
        for (int ks = 0; ks < 2; ++ks) {
            short8 ap = *(short8*)&Pw[w * 8320 + cl * 520 + ch * 64 + ks * 32 + q * 8];
            #pragma unroll
            for (int nt = 0; nt < 4; ++nt) {
                short8 bv = *(short8*)&KVs[(nt * 16 + cl) * 72 + ks * 32 + q * 8];
                o4[nt] = __builtin_amdgcn_mfma_f32_16x16x32_bf16(ap, bv, o4[nt], 0, 0, 0);
            }
        }
    }

    #pragma unroll
    for (int nt = 0; nt < 4; ++nt)
        #pragma unroll
        for (int r = 0; r < 4; ++r)
            Obs[(w * 16 + q * 4 + r) * 72 + nt * 16 + cl] = f2bf(o4[nt][r] * invl[r]);
    __syncthreads();
    floatx4 acc2[4];
    #pragma unroll
    for (int nt = 0; nt < 4; ++nt) acc2[nt] = (floatx4){0.f, 0.f, 0.f, 0.f};
    #pragma unroll
    for (int ks = 0; ks < 2; ++ks) {
        short8 ao = *(short8*)&Obs[(w * 16 + cl) * 72 + ks * 32 + q * 8];
        #pragma unroll
        for (int nt = 0; nt < 4; ++nt) {
            short8 bo = *(short8*)&OWs[(nt * 16 + cl) * 72 + ks * 32 + q * 8];
            acc2[nt] = __builtin_amdgcn_mfma_f32_16x16x32_bf16(ao, bo, acc2[nt], 0, 0, 0);
        }
    }
    #pragma unroll
    for (int nt = 0; nt < 4; ++nt) {
        float bb = ob[nt * 16 + cl];
        #pragma unroll
        for (int r = 0; r < 4; ++r)
            out[((size_t)(b * 512) + i0 + w * 16 + q * 4 + r) * 64 + nt * 16 + cl] = acc2[nt][r] + bb;
    }
}

// ===== 6. tiled fp32 GEMM (proven round 4) — FAN epilogues only =====
template<int EPI>
__global__ __launch_bounds__(256) void gemm_k(const float* __restrict__ A,
                                              const float* __restrict__ W,
                                              const float* __restrict__ bias,
                                              float* __restrict__ C,
                                              int K, int ldc,
                                              const float* __restrict__ gate,
                                              int moff) {
    __shared__ float As[32 * 64];
    __shared__ float Bs[32 * 64];
    int tid = threadIdx.x;
    int tx = tid & 15, ty = tid >> 4;
    int m0 = blockIdx.y * 64, n0 = blockIdx.x * 64;
    float acc[4][4] = {};
    for (int k0 = 0; k0 < K; k0 += 32) {
        __syncthreads();
        #pragma unroll
        for (int s = 0; s < 2; ++s) {
            int i4 = tid + s * 256;
            int row = i4 >> 3, kq = i4 & 7;
            float4 a4 = *(const float4*)&A[(size_t)(m0 + row) * K + k0 + kq * 4];
            float4 w4 = *(const float4*)&W[(size_t)(n0 + row) * K + k0 + kq * 4];
            int kb = kq * 4;
            As[(kb + 0) * 64 + row] = a4.x; As[(kb + 1) * 64 + row] = a4.y;
            As[(kb + 2) * 64 + row] = a4.z; As[(kb + 3) * 64 + row] = a4.w;
            Bs[(kb + 0) * 64 + row] = w4.x; Bs[(kb + 1) * 64 + row] = w4.y;
            Bs[(kb + 2) * 64 + row] = w4.z; Bs[(kb + 3) * 64 + row] = w4.w;
        }
        __syncthreads();
        #pragma unroll
        for (int kk = 0; kk < 32; ++kk) {
            float4 a4 = *(const float4*)&As[kk * 64 + (ty << 2)];
            float4 b4 = *(const float4*)&Bs[kk * 64 + (tx << 2)];
            #pragma unroll
            for (int i = 0; i < 4; ++i)
                #pragma unroll
                for (int j = 0; j < 4; ++j)
                    acc[i][j] += (&a4.x)[i] * (&b4.x)[j];
        }
    }
    int row0 = m0 + ty * 4, col0 = n0 + tx * 4;
    float4 bb = *(const float4*)&bias[col0];
    float gt = 1.f / (1.f + expf(-gate[0]));
    #pragma unroll
    for (int i = 0; i < 4; ++i) {
        int row = row0 + i;
        float v0 = acc[i][0] + bb.x, v1 = acc[i][1] + bb.y;
        float v2 = acc[i][2] + bb.z, v3 = acc[i][3] + bb.w;
        if (EPI == 2) {
            float4 co = make_float4(gt * cosf(v0), gt * cosf(v1), gt * cosf(v2), gt * cosf(v3));
            float4 si = make_float4(gt * sinf(v0), gt * sinf(v1), gt * sinf(v2), gt * sinf(v3));
            *(float4*)&C[(size_t)row * 1024 + col0] = co;
            *(float4*)&C[(size_t)row * 1024 + 128 + col0] = si;
        } else if (EPI == 3) {
            float ig = 1.f - gt;
            float4 o = make_float4(
                ig * 0.5f * v0 * (1.f + erff(v0 * 0.70710678118f)),
                ig * 0.5f * v1 * (1.f + erff(v1 * 0.70710678118f)),
                ig * 0.5f * v2 * (1.f + erff(v2 * 0.70710678118f)),
                ig * 0.5f * v3 * (1.f + erff(v3 * 0.70710678118f)));
            *(float4*)&C[(size_t)row * 1024 + 256 + col0] = o;
        }
    }
}

// ===== 7. cast f32 -> bf16 =====
__global__ __launch_bounds__(256) void cast_bf16(const float* __restrict__ in,
                                                 unsigned short* __restrict__ out, int n4) {
    int i = blockIdx.x * 256 + threadIdx.x;
    if (i < n4) {
        float4 v = *(const float4*)&in[(size_t)i * 4];
        ushort4 o;
        o.x = f2bf(v.x); o.y = f2bf(v.y); o.z = f2bf(v.z); o.w = f2bf(v.w);
        *(ushort4*)&out[(size_t)i * 4] = o;
    }
}

// ===== 8. bf16 MFMA GEMM (proven round 6): C = A[M,K] @ B[N,K]^T, 128x128, BK=64 =====
template<int EPI>
__global__ __launch_bounds__(256) void gemm_mfma(const unsigned short* __restrict__ A,
                                                 const unsigned short* __restrict__ B,
                                                 const float* __restrict__ bias,
                                                 void* __restrict__ Cout,
                                                 int M, int N, int K) {
    __shared__ unsigned short As[8192];
    __shared__ unsigned short Bs[8192];
    int tid = threadIdx.x;
    int l = tid & 63, w = tid >> 6;
    int q = l >> 4, cl = l & 15;
    int wm = w >> 1, wn = w & 1;
    int m0 = blockIdx.y * 128, n0 = blockIdx.x * 128;
    floatx4 acc[4][4];
    #pragma unroll
    for (int i = 0; i < 4; ++i)
        #pragma unroll
        for (int j = 0; j < 4; ++j)
            acc[i][j] = (floatx4){0.f, 0.f, 0.f, 0.f};

    for (int k0 = 0; k0 < K; k0 += 64) {
        __syncthreads();
        #pragma unroll
        for (int ci = 0; ci < 8; ++ci) {
            int cid = w * 8 + ci;
            int isB = cid >> 4;
            int c = cid & 15;
            int cq = c >> 3, cks = (c >> 2) & 1, cf = c & 3;
            int row = cq * 64 + cf * 16 + cl;
            int col = k0 + cks * 32 + q * 8;
            const unsigned short* gp = isB ? (B + (size_t)(n0 + row) * K + col)
                                           : (A + (size_t)(m0 + row) * K + col);
            unsigned short* lp = (isB ? Bs : As) + c * 512;
            __builtin_amdgcn_global_load_lds((const __attribute__((address_space(1))) void*)gp,
                                             (__attribute__((address_space(3))) void*)lp,
                                             16, 0, 0);
        }
        __syncthreads();
        #pragma unroll
        for (int ks = 0; ks < 2; ++ks) {
            short8 af[4], bg[4];
            #pragma unroll
            for (int f = 0; f < 4; ++f) {
                af[f] = *(short8*)&As[(wm * 8 + ks * 4 + f) * 512 + l * 8];
                bg[f] = *(short8*)&Bs[(wn * 8 + ks * 4 + f) * 512 + l * 8];
            }
            #pragma unroll
            for (int i = 0; i < 4; ++i)
                #pragma unroll
                for (int j = 0; j < 4; ++j)
                    acc[i][j] = __builtin_amdgcn_mfma_f32_16x16x32_bf16(af[i], bg[j], acc[i][j], 0, 0, 0);
        }
    }

    if (EPI == 1) {
        unsigned short* Cb = (unsigned short*)Cout;
        #pragma unroll
        for (int j = 0; j < 4; ++j) {
            int col = n0 + wn * 64 + j * 16 + cl;
            float bb = bias[col];
            #pragma unroll
            for (int i = 0; i < 4; ++i) {
                int rowb = m0 + wm * 64 + i * 16 + q * 4;
                #pragma unroll
                for (int r = 0; r < 4; ++r) {
                    float v = acc[i][j][r] + bb;
                    Cb[(size_t)(rowb + r) * N + col] = f2bf(fmaxf(v, 0.f));
                }
            }
        }
    } else {
        float* Ob = (float*)Cout;
        int bidx = (n0 >> 6) + wn;
        #pragma unroll
        for (int i = 0; i < 4; ++i) {
            #pragma unroll
            for (int r = 0; r < 4; ++r) {
                int t = m0 + wm * 64 + i * 16 + q * 4 + r;
                float bb = bias[t];
                #pragma unroll
                for (int j = 0; j < 4; ++j) {
                    int c = j * 16 + cl;
                    Ob[((size_t)bidx * 512 + t) * 64 + c] = acc[i][j][r] + bb;
                }
            }
        }
    }
}

extern "C" void kernel_launch(void* const* d_in, const int* in_sizes, int n_in,
                              void* d_out, int out_size, void* d_ws, size_t ws_size,
                              hipStream_t stream) {
    const float* x         = (const float*)d_in[0];
    const float* in_proj_w = (const float*)d_in[1];
    const float* in_proj_b = (const float*)d_in[2];
    const float* out_w     = (const float*)d_in[3];
    const float* out_b     = (const float*)d_in[4];
    const float* Wp        = (const float*)d_in[5];
    const float* bp        = (const float*)d_in[6];
    const float* Wg        = (const float*)d_in[7];
    const float* bg        = (const float*)d_in[8];
    const float* gate      = (const float*)d_in[9];
    const float* fc1_w     = (const float*)d_in[10];
    const float* fc1_b     = (const float*)d_in[11];
    const float* fc2_w     = (const float*)d_in[12];
    const float* fc2_b     = (const float*)d_in[13];
    const int*   kptr      = (const int*)d_in[14];
    float* ws  = (float*)d_ws;
    float* out = (float*)d_out;

    float* h     = ws + U_H;
    float* mft   = ws + U_MFT;
    float* xre   = ws + U_XRE;
    float* xim   = ws + U_XIM;
    int*   keepi = (int*)(ws + U_KEEPI);
    float* keepw = ws + U_KEEPW;
    float* xfilt = ws + U_XFILT;
    float* norm  = ws + U_NORM;
    float* part  = ws + U_PART;
    unsigned short* qb    = (unsigned short*)(ws + U_Q);
    unsigned short* kb    = (unsigned short*)(ws + U_K);
    unsigned short* vtb   = (unsigned short*)(ws + U_V);
    unsigned short* hbf   = (unsigned short*)(ws + U_HBF);
    unsigned short* hidbf = (unsigned short*)(ws + U_HIDBF);
    unsigned short* w1bf  = (unsigned short*)(ws + U_W1BF);
    unsigned short* w2bf  = (unsigned short*)(ws + U_W2BF);

    dft_split  <<<dim3(5, 64, 4), 256, 0, stream>>>(x, xre, xim, part);
    dft_reduce <<<dim3(2056),     256, 0, stream>>>(xre, part);
    topk_lds   <<<dim3(4096),    256, 0, stream>>>(xre, xim, keepi, keepw, kptr);
    xfilt_fused<<<dim3(8, 64),   256, 0, stream>>>(x, xre, xim, keepi, keepw, xfilt, norm, mft, h, kptr);
    qkv_gemm   <<<dim3(3, 512),  256, 0, stream>>>(xfilt, norm, in_proj_w, in_proj_b, qb, kb, vtb);
    attn_mfma  <<<dim3(8, 64),   256, 0, stream>>>(qb, kb, vtb, out_w, out_b, out);
    gemm_k<2>  <<<dim3(2, 64),   256, 0, stream>>>(mft, Wp, bp, h, 512, 1024, gate, 0);
    gemm_k<3>  <<<dim3(4, 64),   256, 0, stream>>>(mft, Wg, bg, h, 512, 1024, gate, 0);
    cast_bf16<<<4096, 256, 0, stream>>>(h,     hbf,  1048576);
    cast_bf16<<<3072, 256, 0, stream>>>(fc1_w, w1bf, 786432);
    cast_bf16<<<1536, 256, 0, stream>>>(fc2_w, w2bf, 393216);
    gemm_mfma<1><<<dim3(24, 32), 256, 0, stream>>>(hbf,  w1bf,  fc1_b, hidbf,          4096, 3072, 1024);
    gemm_mfma<2><<<dim3(32, 4),  256, 0, stream>>>(w2bf, hidbf, fc2_b, out + 2097152,  512,  4096, 3072);
}

// Round 13
// 617.802 us; speedup vs baseline: 15.5674x; 1.0115x over previous
//
#include <hip/hip_runtime.h>
#include <math.h>

// B=64, L=512, C=64, E=64, F=257, PRED=512, H1=1024, H2=3072
// ---- workspace layout (f32 units), peak 17,047,552 = 68.19 MB (proven) ----
#define U_HBF   0            // bf16 [4096][1024] = 2097152 f32 units (h now born bf16)
#define U_MFT   4194304      // [4096][512]             -> 6291456
#define U_XRE   6291456      // [64][257][64]           -> 7344128
#define U_XIM   7344128      //                         -> 8396800
#define U_KEEPI 8396800      // int[4096*32]            -> 8527872
#define U_KEEPW 8527872      //                         -> 8658944
#define U_XFILT 8658944      // [64][512][64]           -> 10756096
#define U_NORM  10756096     // [64][512][64]           -> 12853248
#define U_Q     6291456      // bf16 [64][512][64] over dead xre/xim
#define U_K     12853248     // bf16 [64][512][64]
#define U_V     14950400     // bf16 V^T [64][64][512]           (peak 17047552)
#define U_HIDBF 8388608      // bf16 [4096][3072] = 6291456 u -> 14680064
#define U_W1BF  14680064     // bf16 [3072][1024] = 1572864 u -> 16252928
#define U_W2BF  16252928     // bf16 [512][3072]  =  786432 u -> 17039360
// DFT partial slices (z=1..3), live only dft_split..dft_reduce:
#define U_PART  8658944      // 3 x 2105344 floats -> ends 14974976

#define TWO_PI_OVER_512 0.012271846303085129

typedef __attribute__((ext_vector_type(8))) short short8;
typedef __attribute__((ext_vector_type(4))) float floatx4;

__device__ inline unsigned short f2bf(float f) {
    union { unsigned int i; float f; } x; x.f = f;
    unsigned int r = x.i + 0x7fff + ((x.i >> 16) & 1);
    return (unsigned short)(r >> 16);
}

// ===== 1a. split DFT (proven round 12) =====
__global__ __launch_bounds__(256) void dft_split(const float* __restrict__ x,
                                                 float* __restrict__ xre,
                                                 float* __restrict__ xim,
                                                 float* __restrict__ part) {
    __shared__ float xs[64 * 64];
    __shared__ float ct[512], st[512];
    int tid = threadIdx.x;
    int b = blockIdx.y;
    int f0 = blockIdx.x * 64;
    int z = blockIdx.z;
    for (int i = tid; i < 512; i += 256) {
        float s, c; sincosf((float)((double)i * TWO_PI_OVER_512), &s, &c);
        ct[i] = c; st[i] = s;
    }
    int c2 = (tid & 31) * 2;
    int fg = tid >> 5;
    int fb = f0 + fg * 8;
    float2 ar[8], ai[8];
    #pragma unroll
    for (int i = 0; i < 8; ++i) { ar[i] = make_float2(0.f, 0.f); ai[i] = make_float2(0.f, 0.f); }
    for (int sub = 0; sub < 2; ++sub) {
        int t0 = z * 128 + sub * 64;
        __syncthreads();
        for (int i = tid; i < 4096; i += 256)
            xs[i] = x[(size_t)(b * 512 + t0) * 64 + i];
        __syncthreads();
        for (int tt = 0; tt < 64; ++tt) {
            float2 xv = *(float2*)&xs[tt * 64 + c2];
            int t = t0 + tt;
            int idx = (fb * t) & 511;
            #pragma unroll
            for (int i = 0; i < 8; ++i) {
                float cv = ct[idx], sv = st[idx];
                ar[i].x += xv.x * cv; ar[i].y += xv.y * cv;
                ai[i].x -= xv.x * sv; ai[i].y -= xv.y * sv;
                idx = (idx + t) & 511;
            }
        }
    }
    float* dre = (z == 0) ? xre : (part + (size_t)(z - 1) * 2105344);
    float* dim_ = (z == 0) ? xim : (part + (size_t)(z - 1) * 2105344 + 1052672);
    #pragma unroll
    for (int i = 0; i < 8; ++i) {
        int f = fb + i;
        if (f < 257) {
            *(float2*)&dre[((size_t)(b * 257) + f) * 64 + c2] = ar[i];
            *(float2*)&dim_[((size_t)(b * 257) + f) * 64 + c2] = ai[i];
        }
    }
}

// ===== 1b. reduce partials (proven round 12) =====
__global__ __launch_bounds__(256) void dft_reduce(float* __restrict__ xreflat,
                                                  const float* __restrict__ part) {
    int i = blockIdx.x * 256 + threadIdx.x;
    if (i < 526336) {
        float4 a  = *(float4*)&xreflat[(size_t)i * 4];
        float4 p0 = *(const float4*)&part[(size_t)i * 4];
        float4 p1 = *(const float4*)&part[2105344 + (size_t)i * 4];
        float4 p2 = *(const float4*)&part[4210688 + (size_t)i * 4];
        a.x += p0.x + p1.x + p2.x;
        a.y += p0.y + p1.y + p2.y;
        a.z += p0.z + p1.z + p2.z;
        a.w += p0.w + p1.w + p2.w;
        *(float4*)&xreflat[(size_t)i * 4] = a;
    }
}

// ===== 2. block-per-row LDS-tree top-k (proven round 9) =====
__global__ __launch_bounds__(256) void topk_lds(const float* __restrict__ xre,
                                                const float* __restrict__ xim,
                                                int* __restrict__ keepi,
                                                float* __restrict__ keepw,
                                                const int* __restrict__ kptr) {
    __shared__ float vals[320];
    __shared__ float tv[256];
    __shared__ int   ti[256];
    int tid = threadIdx.x;
    int bc = blockIdx.x;
    int b = bc >> 6, c = bc & 63;
    int kk = *kptr; if (kk > 32) kk = 32;
    for (int f = tid; f < 320; f += 256) {
        if (f < 257) {
            size_t a = ((size_t)(b * 257) + f) * 64 + c;
            float re = xre[a], im = xim[a];
            vals[f] = sqrtf(re * re + im * im);
        } else vals[f] = -1.f;
    }
    __syncthreads();
    for (int j = 0; j < kk; ++j) {
        float v0 = vals[tid];
        int   i0 = tid;
        if (tid < 64) {
            float v1 = vals[tid + 256];
            if (v1 > v0) { v0 = v1; i0 = tid + 256; }
        }
        tv[tid] = v0; ti[tid] = i0;
        __syncthreads();
        for (int s = 128; s > 0; s >>= 1) {
            if (tid < s) {
                float ov = tv[tid + s]; int oi = ti[tid + s];
                if (ov > tv[tid] || (ov == tv[tid] && oi < ti[tid])) { tv[tid] = ov; ti[tid] = oi; }
            }
            __syncthreads();
        }
        if (tid == 0) {
            int bf = ti[0];
            keepi[bc * 32 + j] = bf;
            keepw[bc * 32 + j] = (bf == 0 || bf == 256) ? (1.f / 512.f) : (2.f / 512.f);
            vals[bf] = -1.f;
        }
        __syncthreads();
    }
}

// ===== 3. fused x_filt (proven round 7; xt-half now written bf16 into hbf) =====
__global__ __launch_bounds__(256) void xfilt_fused(const float* __restrict__ x,
                                                   const float* __restrict__ xre,
                                                   const float* __restrict__ xim,
                                                   const int* __restrict__ keepi,
                                                   const float* __restrict__ keepw,
                                                   float* __restrict__ xfilt,
                                                   float* __restrict__ norm,
                                                   float* __restrict__ mft,
                                                   unsigned short* __restrict__ hbf,
                                                   const int* __restrict__ kptr) {
    __shared__ float ct[512], st[512];
    __shared__ int   kf[64 * 33];
    __shared__ float kre[64 * 33], kim[64 * 33];
    __shared__ float xs[64 * 65];
    __shared__ float ft[64 * 65];
    int tid = threadIdx.x;
    int b = blockIdx.y;
    int t0 = blockIdx.x * 64;
    int kk = *kptr; if (kk > 32) kk = 32;
    for (int i = tid; i < 512; i += 256) {
        float s, c; sincosf((float)((double)i * TWO_PI_OVER_512), &s, &c);
        ct[i] = c; st[i] = s;
    }
    for (int i = tid; i < 4096; i += 256) {
        int tl = i >> 6, c = i & 63;
        xs[tl * 65 + c] = x[((size_t)(b * 512) + t0 + tl) * 64 + c];
    }
    for (int e = tid; e < 64 * kk; e += 256) {
        int c = e / kk, j = e - c * kk;
        int bc = b * 64 + c;
        int f = keepi[bc * 32 + j];
        float w = keepw[bc * 32 + j];
        size_t a = ((size_t)(b * 257) + f) * 64 + c;
        kf[c * 33 + j]  = f;
        kre[c * 33 + j] = w * xre[a];
        kim[c * 33 + j] = w * xim[a];
    }
    __syncthreads();
    int l = tid & 63, w = tid >> 6;
    int t = t0 + l;
    for (int ci = 0; ci < 16; ++ci) {
        int c = w * 16 + ci;
        float acc = 0.f;
        for (int j = 0; j < kk; ++j) {
            int f = kf[c * 33 + j];
            int idx = (f * t) & 511;
            acc += kre[c * 33 + j] * ct[idx] - kim[c * 33 + j] * st[idx];
        }
        ft[c * 65 + l] = acc;
    }
    __syncthreads();
    for (int i = tid; i < 4096; i += 256) {
        int tl = i >> 6, c = i & 63;
        float v = ft[c * 65 + tl];
        size_t a = ((size_t)(b * 512) + t0 + tl) * 64 + c;
        xfilt[a] = v;
        norm[a]  = xs[tl * 65 + c] - v;
    }
    for (int i = tid; i < 4096; i += 256) {
        int cr = i >> 6, tl = i & 63;
        mft[((size_t)(b * 64) + cr) * 512 + t0 + tl] = ft[cr * 65 + tl];
        hbf[((size_t)(b * 64) + cr) * 1024 + 512 + t0 + tl] = f2bf(xs[tl * 65 + cr]);
    }
}

// ===== 4. QKV as tiled GEMM (proven round 11) =====
__global__ __launch_bounds__(256) void qkv_gemm(const float* __restrict__ xfilt,
                                                const float* __restrict__ norm,
                                                const float* __restrict__ w,
                                                const float* __restrict__ bias,
                                                unsigned short* __restrict__ q,
                                                unsigned short* __restrict__ kmat,
                                                unsigned short* __restrict__ vt) {
    __shared__ float As[32 * 64];
    __shared__ float Bs[32 * 64];
    __shared__ unsigned short Cs[64 * 65];
    int tid = threadIdx.x;
    int tx = tid & 15, ty = tid >> 4;
    int grp = blockIdx.x;
    int m0 = blockIdx.y * 64;
    int n0 = grp * 64;
    const float* A = (grp == 0) ? xfilt : norm;
    float acc[4][4] = {};
    for (int k0 = 0; k0 < 64; k0 += 32) {
        __syncthreads();
        #pragma unroll
        for (int s = 0; s < 2; ++s) {
            int i4 = tid + s * 256;
            int row = i4 >> 3, kq = i4 & 7;
            float4 a4 = *(const float4*)&A[(size_t)(m0 + row) * 64 + k0 + kq * 4];
            float4 w4 = *(const float4*)&w[(size_t)(n0 + row) * 64 + k0 + kq * 4];
            int kb = kq * 4;
            As[(kb + 0) * 64 + row] = a4.x; As[(kb + 1) * 64 + row] = a4.y;
            As[(kb + 2) * 64 + row] = a4.z; As[(kb + 3) * 64 + row] = a4.w;
            Bs[(kb + 0) * 64 + row] = w4.x; Bs[(kb + 1) * 64 + row] = w4.y;
            Bs[(kb + 2) * 64 + row] = w4.z; Bs[(kb + 3) * 64 + row] = w4.w;
        }
        __syncthreads();
        #pragma unroll
        for (int kk = 0; kk < 32; ++kk) {
            float4 a4 = *(const float4*)&As[kk * 64 + (ty << 2)];
            float4 b4 = *(const float4*)&Bs[kk * 64 + (tx << 2)];
            #pragma unroll
            for (int i = 0; i < 4; ++i)
                #pragma unroll
                for (int j = 0; j < 4; ++j)
                    acc[i][j] += (&a4.x)[i] * (&b4.x)[j];
        }
    }
    int row0 = ty * 4, col0 = tx * 4;
    float4 bb = *(const float4*)&bias[n0 + col0];
    #pragma unroll
    for (int i = 0; i < 4; ++i) {
        float v0 = acc[i][0] + bb.x, v1 = acc[i][1] + bb.y;
        float v2 = acc[i][2] + bb.z, v3 = acc[i][3] + bb.w;
        ushort4 o;
        o.x = f2bf(v0); o.y = f2bf(v1); o.z = f2bf(v2); o.w = f2bf(v3);
        if (grp == 0) {
            *(ushort4*)&q[(size_t)(m0 + row0 + i) * 64 + col0] = o;
        } else if (grp == 1) {
            *(ushort4*)&kmat[(size_t)(m0 + row0 + i) * 64 + col0] = o;
        } else {
            Cs[(row0 + i) * 65 + col0 + 0] = o.x;
            Cs[(row0 + i) * 65 + col0 + 1] = o.y;
            Cs[(row0 + i) * 65 + col0 + 2] = o.z;
            Cs[(row0 + i) * 65 + col0 + 3] = o.w;
        }
    }
    if (grp == 2) {
        __syncthreads();
        int b = m0 >> 9, t0 = m0 & 511;
        for (int i2 = tid; i2 < 4096; i2 += 256) {
            int e = i2 >> 6, tl = i2 & 63;
            vt[((size_t)(b * 64) + e) * 512 + t0 + tl] = Cs[tl * 65 + e];
        }
    }
}

// ===== 5. MFMA attention + out-proj, low-LDS (27.6 KB -> 2 blocks/CU) =====
// Same math/layouts as proven round 10; P staged per-64-col chunk in a
// wave-private buffer written BEFORE the V-stage barrier (write->barrier->read,
// mirroring the proven ordering). Qs reused for O-staging, KVs for out-proj W.
__global__ __launch_bounds__(256) void attn_mfma(const unsigned short* __restrict__ qbf,
                                                 const unsigned short* __restrict__ kbf,
                                                 const unsigned short* __restrict__ vtbf,
                                                 const float* __restrict__ ow,
                                                 const float* __restrict__ ob,
                                                 float* __restrict__ out) {
    __shared__ unsigned short Qs[64 * 72];        // Q; reused as O-staging
    __shared__ unsigned short KVs[64 * 72];       // K / V^T chunks; reused for ow
    __shared__ unsigned short Pp[4 * 16 * 72];    // per-wave P chunk (16 x 64, pad 72)
    int tid = threadIdx.x;
    int l = tid & 63, w = tid >> 6;
    int q = l >> 4, cl = l & 15;
    int b = blockIdx.y, i0 = blockIdx.x * 64;

    for (int i = tid; i < 1024; i += 256) {
        int r = i >> 4, e4 = (i & 15) * 4;
        *(ushort4*)&Qs[r * 72 + e4] = *(const ushort4*)&qbf[((size_t)(b * 512) + i0 + r) * 64 + e4];
    }
    __syncthreads();
    short8 aq0 = *(short8*)&Qs[(w * 16 + cl) * 72 + q * 8];
    short8 aq1 = *(short8*)&Qs[(w * 16 + cl) * 72 + 32 + q * 8];

    floatx4 s[32];
    #pragma unroll
    for (int f = 0; f < 32; ++f) s[f] = (floatx4){0.f, 0.f, 0.f, 0.f};

    // ---- QK^T over 8 K-chunks ----
    #pragma unroll
    for (int ch = 0; ch < 8; ++ch) {
        __syncthreads();
        for (int i = tid; i < 1024; i += 256) {
            int jj = i >> 4, e4 = (i & 15) * 4;
            *(ushort4*)&KVs[jj * 72 + e4] =
                *(const ushort4*)&kbf[((size_t)(b * 512) + ch * 64 + jj) * 64 + e4];
        }
        __syncthreads();
        #pragma unroll
        for (int jt = 0; jt < 4; ++jt) {
            short8 b0 = *(short8*)&KVs[(jt * 16 + cl) * 72 + q * 8];
            short8 b1 = *(short8*)&KVs[(jt * 16 + cl) * 72 + 32 + q * 8];
            s[ch * 4 + jt] = __builtin_amdgcn_mfma_f32_16x16x32_bf16(aq0, b0, s[ch * 4 + jt], 0, 0, 0);
            s[ch * 4 + jt] = __builtin_amdgcn_mfma_f32_16x16x32_bf16(aq1, b1, s[ch * 4 + jt], 0, 0, 0);
        }
    }

    // ---- softmax in registers ----
    float invl[4];
    #pragma unroll
    for (int r = 0; r < 4; ++r) {
        float m = -1e30f;
        #pragma unroll
        for (int f = 0; f < 32; ++f) m = fmaxf(m, s[f][r]);
        m = fmaxf(m, __shfl_xor(m, 1)); m = fmaxf(m, __shfl_xor(m, 2));
        m = fmaxf(m, __shfl_xor(m, 4)); m = fmaxf(m, __shfl_xor(m, 8));
        float sum = 0.f;
        #pragma unroll
        for (int f = 0; f < 32; ++f) {
            float p = expf((s[f][r] - m) * 0.125f);
            s[f][r] = p; sum += p;
        }
        sum += __shfl_xor(sum, 1); sum += __shfl_xor(sum, 2);
        sum += __shfl_xor(sum, 4); sum += __shfl_xor(sum, 8);
        invl[r] = 1.f / sum;
    }

    // ---- PV over 8 V^T-chunks; P chunk via wave-private LDS ----
    floatx4 o4[4];
    #pragma unroll
    for (int nt = 0; nt < 4; ++nt) o4[nt] = (floatx4){0.f, 0.f, 0.f, 0.f};
    #pragma unroll
    for (int ch = 0; ch < 8; ++ch) {
        #pragma unroll
        for (int jt = 0; jt < 4; ++jt)
            #pragma unroll
            for (int r = 0; r < 4; ++r)
                Pp[w * 1152 + (q * 4 + r) * 72 + jt * 16 + cl] = f2bf(s[ch * 4 + jt][r]);
        __syncthreads();
        for (int i = tid; i < 1024; i += 256) {
            int e = i >> 4, j4 = (i & 15) * 4;
            *(ushort4*)&KVs[e * 72 + j4] =
                *(const ushort4*)&vtbf[((size_t)(b * 64) + e) * 512 + ch * 64 + j4];
        }
        __syncthreads();
        #pragma unroll
        for (int ks = 0; ks < 2; ++ks) {
            short8 ap = *(short8*)&Pp[w * 1152 + cl * 72 + ks * 32 + q * 8];
            #pragma unroll
            for (int nt = 0; nt < 4; ++nt) {
                short8 bv = *(short8*)&KVs[(nt * 16 + cl) * 72 + ks * 32 + q * 8];
                o4[nt] = __builtin_amdgcn_mfma_f32_16x16x32_bf16(ap, bv, o4[nt], 0, 0, 0);
            }
        }
    }

    // ---- O -> Qs (wave-private rows); ow -> KVs; out-proj MFMA; store ----
    #pragma unroll
    for (int nt = 0; nt < 4; ++nt)
        #pragma unroll
        for (int r = 0; r < 4; ++r)
            Qs[(w * 16 + q * 4 + r) * 72 + nt * 16 + cl] = f2bf(o4[nt][r] * invl[r]);
    __syncthreads();                 // all PV reads of KVs done; safe to overwrite
    for (int i = tid; i < 1024; i += 256) {
        int o = i >> 4, e4 = (i & 15) * 4;
        float4 v = *(const float4*)&ow[o * 64 + e4];
        ushort4 u; u.x = f2bf(v.x); u.y = f2bf(v.y); u.z = f2bf(v.z); u.w = f2bf(v.w);
        *(ushort4*)&KVs[o * 72 + e4] = u;
    }
    __syncthreads();
    floatx4 acc2[4];
    #pragma unroll
    for (int nt = 0; nt < 4; ++nt) acc2[nt] = (floatx4){0.f, 0.f, 0.f, 0.f};
    #pragma unroll
    for (int ks = 0; ks < 2; ++ks) {
        short8 ao = *(short8*)&Qs[(w * 16 + cl) * 72 + ks * 32 + q * 8];
        #pragma unroll
        for (int nt = 0; nt < 4; ++nt) {
            short8 bo = *(short8*)&KVs[(nt * 16 + cl) * 72 + ks * 32 + q * 8];
            acc2[nt] = __builtin_amdgcn_mfma_f32_16x16x32_bf16(ao, bo, acc2[nt], 0, 0, 0);
        }
    }
    #pragma unroll
    for (int nt = 0; nt < 4; ++nt) {
        float bb = ob[nt * 16 + cl];
        #pragma unroll
        for (int r = 0; r < 4; ++r)
            out[((size_t)(b * 512) + i0 + w * 16 + q * 4 + r) * 64 + nt * 16 + cl] = acc2[nt][r] + bb;
    }
}

// ===== 6. tiled fp32 GEMM, FAN epilogues -> bf16 hbf (same f2bf values as before) =====
template<int EPI>
__global__ __launch_bounds__(256) void gemm_k(const float* __restrict__ A,
                                              const float* __restrict__ W,
                                              const float* __restrict__ bias,
                                              unsigned short* __restrict__ C,
                                              int K,
                                              const float* __restrict__ gate) {
    __shared__ float As[32 * 64];
    __shared__ float Bs[32 * 64];
    int tid = threadIdx.x;
    int tx = tid & 15, ty = tid >> 4;
    int m0 = blockIdx.y * 64, n0 = blockIdx.x * 64;
    float acc[4][4] = {};
    for (int k0 = 0; k0 < K; k0 += 32) {
        __syncthreads();
        #pragma unroll
        for (int s = 0; s < 2; ++s) {
            int i4 = tid + s * 256;
            int row = i4 >> 3, kq = i4 & 7;
            float4 a4 = *(const float4*)&A[(size_t)(m0 + row) * K + k0 + kq * 4];
            float4 w4 = *(const float4*)&W[(size_t)(n0 + row) * K + k0 + kq * 4];
            int kb = kq * 4;
            As[(kb + 0) * 64 + row] = a4.x; As[(kb + 1) * 64 + row] = a4.y;
            As[(kb + 2) * 64 + row] = a4.z; As[(kb + 3) * 64 + row] = a4.w;
            Bs[(kb + 0) * 64 + row] = w4.x; Bs[(kb + 1) * 64 + row] = w4.y;
            Bs[(kb + 2) * 64 + row] = w4.z; Bs[(kb + 3) * 64 + row] = w4.w;
        }
        __syncthreads();
        #pragma unroll
        for (int kk = 0; kk < 32; ++kk) {
            float4 a4 = *(const float4*)&As[kk * 64 + (ty << 2)];
            float4 b4 = *(const float4*)&Bs[kk * 64 + (tx << 2)];
            #pragma unroll
            for (int i = 0; i < 4; ++i)
                #pragma unroll
                for (int j = 0; j < 4; ++j)
                    acc[i][j] += (&a4.x)[i] * (&b4.x)[j];
        }
    }
    int row0 = m0 + ty * 4, col0 = n0 + tx * 4;
    float4 bb = *(const float4*)&bias[col0];
    float gt = 1.f / (1.f + expf(-gate[0]));
    #pragma unroll
    for (int i = 0; i < 4; ++i) {
        int row = row0 + i;
        float v0 = acc[i][0] + bb.x, v1 = acc[i][1] + bb.y;
        float v2 = acc[i][2] + bb.z, v3 = acc[i][3] + bb.w;
        if (EPI == 2) {
            ushort4 co, si;
            co.x = f2bf(gt * cosf(v0)); co.y = f2bf(gt * cosf(v1));
            co.z = f2bf(gt * cosf(v2)); co.w = f2bf(gt * cosf(v3));
            si.x = f2bf(gt * sinf(v0)); si.y = f2bf(gt * sinf(v1));
            si.z = f2bf(gt * sinf(v2)); si.w = f2bf(gt * sinf(v3));
            *(ushort4*)&C[(size_t)row * 1024 + col0] = co;
            *(ushort4*)&C[(size_t)row * 1024 + 128 + col0] = si;
        } else if (EPI == 3) {
            float ig = 1.f - gt;
            ushort4 o;
            o.x = f2bf(ig * 0.5f * v0 * (1.f + erff(v0 * 0.70710678118f)));
            o.y = f2bf(ig * 0.5f * v1 * (1.f + erff(v1 * 0.70710678118f)));
            o.z = f2bf(ig * 0.5f * v2 * (1.f + erff(v2 * 0.70710678118f)));
            o.w = f2bf(ig * 0.5f * v3 * (1.f + erff(v3 * 0.70710678118f)));
            *(ushort4*)&C[(size_t)row * 1024 + 256 + col0] = o;
        }
    }
}

// ===== 7. cast f32 -> bf16 (weights only now) =====
__global__ __launch_bounds__(256) void cast_bf16(const float* __restrict__ in,
                                                 unsigned short* __restrict__ out, int n4) {
    int i = blockIdx.x * 256 + threadIdx.x;
    if (i < n4) {
        float4 v = *(const float4*)&in[(size_t)i * 4];
        ushort4 o;
        o.x = f2bf(v.x); o.y = f2bf(v.y); o.z = f2bf(v.z); o.w = f2bf(v.w);
        *(ushort4*)&out[(size_t)i * 4] = o;
    }
}

// ===== 8. bf16 MFMA GEMM (proven round 6): C = A[M,K] @ B[N,K]^T, 128x128, BK=64 =====
template<int EPI>
__global__ __launch_bounds__(256) void gemm_mfma(const unsigned short* __restrict__ A,
                                                 const unsigned short* __restrict__ B,
                                                 const float* __restrict__ bias,
                                                 void* __restrict__ Cout,
                                                 int M, int N, int K) {
    __shared__ unsigned short As[8192];
    __shared__ unsigned short Bs[8192];
    int tid = threadIdx.x;
    int l = tid & 63, w = tid >> 6;
    int q = l >> 4, cl = l & 15;
    int wm = w >> 1, wn = w & 1;
    int m0 = blockIdx.y * 128, n0 = blockIdx.x * 128;
    floatx4 acc[4][4];
    #pragma unroll
    for (int i = 0; i < 4; ++i)
        #pragma unroll
        for (int j = 0; j < 4; ++j)
            acc[i][j] = (floatx4){0.f, 0.f, 0.f, 0.f};

    for (int k0 = 0; k0 < K; k0 += 64) {
        __syncthreads();
        #pragma unroll
        for (int ci = 0; ci < 8; ++ci) {
            int cid = w * 8 + ci;
            int isB = cid >> 4;
            int c = cid & 15;
            int cq = c >> 3, cks = (c >> 2) & 1, cf = c & 3;
            int row = cq * 64 + cf * 16 + cl;
            int col = k0 + cks * 32 + q * 8;
            const unsigned short* gp = isB ? (B + (size_t)(n0 + row) * K + col)
                                           : (A + (size_t)(m0 + row) * K + col);
            unsigned short* lp = (isB ? Bs : As) + c * 512;
            __builtin_amdgcn_global_load_lds((const __attribute__((address_space(1))) void*)gp,
                                             (__attribute__((address_space(3))) void*)lp,
                                             16, 0, 0);
        }
        __syncthreads();
        #pragma unroll
        for (int ks = 0; ks < 2; ++ks) {
            short8 af[4], bg[4];
            #pragma unroll
            for (int f = 0; f < 4; ++f) {
                af[f] = *(short8*)&As[(wm * 8 + ks * 4 + f) * 512 + l * 8];
                bg[f] = *(short8*)&Bs[(wn * 8 + ks * 4 + f) * 512 + l * 8];
            }
            #pragma unroll
            for (int i = 0; i < 4; ++i)
                #pragma unroll
                for (int j = 0; j < 4; ++j)
                    acc[i][j] = __builtin_amdgcn_mfma_f32_16x16x32_bf16(af[i], bg[j], acc[i][j], 0, 0, 0);
        }
    }

    if (EPI == 1) {
        unsigned short* Cb = (unsigned short*)Cout;
        #pragma unroll
        for (int j = 0; j < 4; ++j) {
            int col = n0 + wn * 64 + j * 16 + cl;
            float bb = bias[col];
            #pragma unroll
            for (int i = 0; i < 4; ++i) {
                int rowb = m0 + wm * 64 + i * 16 + q * 4;
                #pragma unroll
                for (int r = 0; r < 4; ++r) {
                    float v = acc[i][j][r] + bb;
                    Cb[(size_t)(rowb + r) * N + col] = f2bf(fmaxf(v, 0.f));
                }
            }
        }
    } else {
        float* Ob = (float*)Cout;
        int bidx = (n0 >> 6) + wn;
        #pragma unroll
        for (int i = 0; i < 4; ++i) {
            #pragma unroll
            for (int r = 0; r < 4; ++r) {
                int t = m0 + wm * 64 + i * 16 + q * 4 + r;
                float bb = bias[t];
                #pragma unroll
                for (int j = 0; j < 4; ++j) {
                    int c = j * 16 + cl;
                    Ob[((size_t)bidx * 512 + t) * 64 + c] = acc[i][j][r] + bb;
                }
            }
        }
    }
}

extern "C" void kernel_launch(void* const* d_in, const int* in_sizes, int n_in,
                              void* d_out, int out_size, void* d_ws, size_t ws_size,
                              hipStream_t stream) {
    const float* x         = (const float*)d_in[0];
    const float* in_proj_w = (const float*)d_in[1];
    const float* in_proj_b = (const float*)d_in[2];
    const float* out_w     = (const float*)d_in[3];
    const float* out_b     = (const float*)d_in[4];
    const float* Wp        = (const float*)d_in[5];
    const float* bp        = (const float*)d_in[6];
    const float* Wg        = (const float*)d_in[7];
    const float* bg        = (const float*)d_in[8];
    const float* gate      = (const float*)d_in[9];
    const float* fc1_w     = (const float*)d_in[10];
    const float* fc1_b     = (const float*)d_in[11];
    const float* fc2_w     = (const float*)d_in[12];
    const float* fc2_b     = (const float*)d_in[13];
    const int*   kptr      = (const int*)d_in[14];
    float* ws  = (float*)d_ws;
    float* out = (float*)d_out;

    float* mft   = ws + U_MFT;
    float* xre   = ws + U_XRE;
    float* xim   = ws + U_XIM;
    int*   keepi = (int*)(ws + U_KEEPI);
    float* keepw = ws + U_KEEPW;
    float* xfilt = ws + U_XFILT;
    float* norm  = ws + U_NORM;
    float* part  = ws + U_PART;
    unsigned short* hbf   = (unsigned short*)(ws + U_HBF);
    unsigned short* qb    = (unsigned short*)(ws + U_Q);
    unsigned short* kb    = (unsigned short*)(ws + U_K);
    unsigned short* vtb   = (unsigned short*)(ws + U_V);
    unsigned short* hidbf = (unsigned short*)(ws + U_HIDBF);
    unsigned short* w1bf  = (unsigned short*)(ws + U_W1BF);
    unsigned short* w2bf  = (unsigned short*)(ws + U_W2BF);

    dft_split  <<<dim3(5, 64, 4), 256, 0, stream>>>(x, xre, xim, part);
    dft_reduce <<<dim3(2056),     256, 0, stream>>>(xre, part);
    topk_lds   <<<dim3(4096),     256, 0, stream>>>(xre, xim, keepi, keepw, kptr);
    xfilt_fused<<<dim3(8, 64),    256, 0, stream>>>(x, xre, xim, keepi, keepw, xfilt, norm, mft, hbf, kptr);
    qkv_gemm   <<<dim3(3, 512),   256, 0, stream>>>(xfilt, norm, in_proj_w, in_proj_b, qb, kb, vtb);
    attn_mfma  <<<dim3(8, 64),    256, 0, stream>>>(qb, kb, vtb, out_w, out_b, out);
    gemm_k<2>  <<<dim3(2, 64),    256, 0, stream>>>(mft, Wp, bp, hbf, 512, gate);
    gemm_k<3>  <<<dim3(4, 64),    256, 0, stream>>>(mft, Wg, bg, hbf, 512, gate);
    cast_bf16<<<3072, 256, 0, stream>>>(fc1_w, w1bf, 786432);
    cast_bf16<<<1536, 256, 0, stream>>>(fc2_w, w2bf, 393216);
    gemm_mfma<1><<<dim3(24, 32), 256, 0, stream>>>(hbf,  w1bf,  fc1_b, hidbf,         4096, 3072, 1024);
    gemm_mfma<2><<<dim3(32, 4),  256, 0, stream>>>(w2bf, hidbf, fc2_b, out + 2097152, 512,  4096, 3072);
}

// Round 14
// 494.070 us; speedup vs baseline: 19.4660x; 1.2504x over previous
//
#include <hip/hip_runtime.h>
#include <math.h>

// B=64, L=512, C=64, E=64, F=257, PRED=512, H1=1024, H2=3072
// ---- workspace layout (f32 units), peak 17,047,552 = 68.19 MB (proven) ----
#define U_HBF   0            // bf16 [4096][1024] = 2097152 f32 units (h born bf16)
#define U_FC2P  0            // f32 4 x [512*4096] partials over dead hbf (fc2 stage)
#define U_MFT   4194304      // [4096][512]             -> 6291456
#define U_XRE   6291456      // [64][257][64]           -> 7344128
#define U_XIM   7344128      //                         -> 8396800
#define U_KEEPI 8396800      // int[4096*32]            -> 8527872
#define U_KEEPW 8527872      //                         -> 8658944
#define U_XFILT 8658944      // [64][512][64]           -> 10756096
#define U_NORM  10756096     // [64][512][64]           -> 12853248
#define U_Q     6291456      // bf16 [64][512][64] over dead xre/xim
#define U_K     12853248     // bf16 [64][512][64]
#define U_V     14950400     // bf16 V^T [64][64][512]           (peak 17047552)
#define U_HIDBF 8388608      // bf16 [4096][3072] = 6291456 u -> 14680064
#define U_W1BF  14680064     // bf16 [3072][1024] = 1572864 u -> 16252928
#define U_W2BF  16252928     // bf16 [512][3072]  =  786432 u -> 17039360
// DFT partial slices (z=1..3), live only dft_split..dft_reduce:
#define U_PART  8658944      // 3 x 2105344 floats -> ends 14974976

#define TWO_PI_OVER_512 0.012271846303085129

typedef __attribute__((ext_vector_type(8))) short short8;
typedef __attribute__((ext_vector_type(4))) float floatx4;

__device__ inline unsigned short f2bf(float f) {
    union { unsigned int i; float f; } x; x.f = f;
    unsigned int r = x.i + 0x7fff + ((x.i >> 16) & 1);
    return (unsigned short)(r >> 16);
}

// ===== 1a. split DFT (proven round 12) =====
__global__ __launch_bounds__(256) void dft_split(const float* __restrict__ x,
                                                 float* __restrict__ xre,
                                                 float* __restrict__ xim,
                                                 float* __restrict__ part) {
    __shared__ float xs[64 * 64];
    __shared__ float ct[512], st[512];
    int tid = threadIdx.x;
    int b = blockIdx.y;
    int f0 = blockIdx.x * 64;
    int z = blockIdx.z;
    for (int i = tid; i < 512; i += 256) {
        float s, c; sincosf((float)((double)i * TWO_PI_OVER_512), &s, &c);
        ct[i] = c; st[i] = s;
    }
    int c2 = (tid & 31) * 2;
    int fg = tid >> 5;
    int fb = f0 + fg * 8;
    float2 ar[8], ai[8];
    #pragma unroll
    for (int i = 0; i < 8; ++i) { ar[i] = make_float2(0.f, 0.f); ai[i] = make_float2(0.f, 0.f); }
    for (int sub = 0; sub < 2; ++sub) {
        int t0 = z * 128 + sub * 64;
        __syncthreads();
        for (int i = tid; i < 4096; i += 256)
            xs[i] = x[(size_t)(b * 512 + t0) * 64 + i];
        __syncthreads();
        for (int tt = 0; tt < 64; ++tt) {
            float2 xv = *(float2*)&xs[tt * 64 + c2];
            int t = t0 + tt;
            int idx = (fb * t) & 511;
            #pragma unroll
            for (int i = 0; i < 8; ++i) {
                float cv = ct[idx], sv = st[idx];
                ar[i].x += xv.x * cv; ar[i].y += xv.y * cv;
                ai[i].x -= xv.x * sv; ai[i].y -= xv.y * sv;
                idx = (idx + t) & 511;
            }
        }
    }
    float* dre = (z == 0) ? xre : (part + (size_t)(z - 1) * 2105344);
    float* dim_ = (z == 0) ? xim : (part + (size_t)(z - 1) * 2105344 + 1052672);
    #pragma unroll
    for (int i = 0; i < 8; ++i) {
        int f = fb + i;
        if (f < 257) {
            *(float2*)&dre[((size_t)(b * 257) + f) * 64 + c2] = ar[i];
            *(float2*)&dim_[((size_t)(b * 257) + f) * 64 + c2] = ai[i];
        }
    }
}

// ===== 1b. reduce partials (proven round 12) =====
__global__ __launch_bounds__(256) void dft_reduce(float* __restrict__ xreflat,
                                                  const float* __restrict__ part) {
    int i = blockIdx.x * 256 + threadIdx.x;
    if (i < 526336) {
        float4 a  = *(float4*)&xreflat[(size_t)i * 4];
        float4 p0 = *(const float4*)&part[(size_t)i * 4];
        float4 p1 = *(const float4*)&part[2105344 + (size_t)i * 4];
        float4 p2 = *(const float4*)&part[4210688 + (size_t)i * 4];
        a.x += p0.x + p1.x + p2.x;
        a.y += p0.y + p1.y + p2.y;
        a.z += p0.z + p1.z + p2.z;
        a.w += p0.w + p1.w + p2.w;
        *(float4*)&xreflat[(size_t)i * 4] = a;
    }
}

// ===== 2. block-per-row LDS-tree top-k (proven round 9) =====
__global__ __launch_bounds__(256) void topk_lds(const float* __restrict__ xre,
                                                const float* __restrict__ xim,
                                                int* __restrict__ keepi,
                                                float* __restrict__ keepw,
                                                const int* __restrict__ kptr) {
    __shared__ float vals[320];
    __shared__ float tv[256];
    __shared__ int   ti[256];
    int tid = threadIdx.x;
    int bc = blockIdx.x;
    int b = bc >> 6, c = bc & 63;
    int kk = *kptr; if (kk > 32) kk = 32;
    for (int f = tid; f < 320; f += 256) {
        if (f < 257) {
            size_t a = ((size_t)(b * 257) + f) * 64 + c;
            float re = xre[a], im = xim[a];
            vals[f] = sqrtf(re * re + im * im);
        } else vals[f] = -1.f;
    }
    __syncthreads();
    for (int j = 0; j < kk; ++j) {
        float v0 = vals[tid];
        int   i0 = tid;
        if (tid < 64) {
            float v1 = vals[tid + 256];
            if (v1 > v0) { v0 = v1; i0 = tid + 256; }
        }
        tv[tid] = v0; ti[tid] = i0;
        __syncthreads();
        for (int s = 128; s > 0; s >>= 1) {
            if (tid < s) {
                float ov = tv[tid + s]; int oi = ti[tid + s];
                if (ov > tv[tid] || (ov == tv[tid] && oi < ti[tid])) { tv[tid] = ov; ti[tid] = oi; }
            }
            __syncthreads();
        }
        if (tid == 0) {
            int bf = ti[0];
            keepi[bc * 32 + j] = bf;
            keepw[bc * 32 + j] = (bf == 0 || bf == 256) ? (1.f / 512.f) : (2.f / 512.f);
            vals[bf] = -1.f;
        }
        __syncthreads();
    }
}

// ===== 3. fused x_filt (proven round 7; xt-half written bf16 into hbf) =====
__global__ __launch_bounds__(256) void xfilt_fused(const float* __restrict__ x,
                                                   const float* __restrict__ xre,
                                                   const float* __restrict__ xim,
                                                   const int* __restrict__ keepi,
                                                   const float* __restrict__ keepw,
                                                   float* __restrict__ xfilt,
                                                   float* __restrict__ norm,
                                                   float* __restrict__ mft,
                                                   unsigned short* __restrict__ hbf,
                                                   const int* __restrict__ kptr) {
    __shared__ float ct[512], st[512];
    __shared__ int   kf[64 * 33];
    __shared__ float kre[64 * 33], kim[64 * 33];
    __shared__ float xs[64 * 65];
    __shared__ float ft[64 * 65];
    int tid = threadIdx.x;
    int b = blockIdx.y;
    int t0 = blockIdx.x * 64;
    int kk = *kptr; if (kk > 32) kk = 32;
    for (int i = tid; i < 512; i += 256) {
        float s, c; sincosf((float)((double)i * TWO_PI_OVER_512), &s, &c);
        ct[i] = c; st[i] = s;
    }
    for (int i = tid; i < 4096; i += 256) {
        int tl = i >> 6, c = i & 63;
        xs[tl * 65 + c] = x[((size_t)(b * 512) + t0 + tl) * 64 + c];
    }
    for (int e = tid; e < 64 * kk; e += 256) {
        int c = e / kk, j = e - c * kk;
        int bc = b * 64 + c;
        int f = keepi[bc * 32 + j];
        float w = keepw[bc * 32 + j];
        size_t a = ((size_t)(b * 257) + f) * 64 + c;
        kf[c * 33 + j]  = f;
        kre[c * 33 + j] = w * xre[a];
        kim[c * 33 + j] = w * xim[a];
    }
    __syncthreads();
    int l = tid & 63, w = tid >> 6;
    int t = t0 + l;
    for (int ci = 0; ci < 16; ++ci) {
        int c = w * 16 + ci;
        float acc = 0.f;
        for (int j = 0; j < kk; ++j) {
            int f = kf[c * 33 + j];
            int idx = (f * t) & 511;
            acc += kre[c * 33 + j] * ct[idx] - kim[c * 33 + j] * st[idx];
        }
        ft[c * 65 + l] = acc;
    }
    __syncthreads();
    for (int i = tid; i < 4096; i += 256) {
        int tl = i >> 6, c = i & 63;
        float v = ft[c * 65 + tl];
        size_t a = ((size_t)(b * 512) + t0 + tl) * 64 + c;
        xfilt[a] = v;
        norm[a]  = xs[tl * 65 + c] - v;
    }
    for (int i = tid; i < 4096; i += 256) {
        int cr = i >> 6, tl = i & 63;
        mft[((size_t)(b * 64) + cr) * 512 + t0 + tl] = ft[cr * 65 + tl];
        hbf[((size_t)(b * 64) + cr) * 1024 + 512 + t0 + tl] = f2bf(xs[tl * 65 + cr]);
    }
}

// ===== 4. QKV as tiled GEMM (proven round 11) =====
__global__ __launch_bounds__(256) void qkv_gemm(const float* __restrict__ xfilt,
                                                const float* __restrict__ norm,
                                                const float* __restrict__ w,
                                                const float* __restrict__ bias,
                                                unsigned short* __restrict__ q,
                                                unsigned short* __restrict__ kmat,
                                                unsigned short* __restrict__ vt) {
    __shared__ float As[32 * 64];
    __shared__ float Bs[32 * 64];
    __shared__ unsigned short Cs[64 * 65];
    int tid = threadIdx.x;
    int tx = tid & 15, ty = tid >> 4;
    int grp = blockIdx.x;
    int m0 = blockIdx.y * 64;
    int n0 = grp * 64;
    const float* A = (grp == 0) ? xfilt : norm;
    float acc[4][4] = {};
    for (int k0 = 0; k0 < 64; k0 += 32) {
        __syncthreads();
        #pragma unroll
        for (int s = 0; s < 2; ++s) {
            int i4 = tid + s * 256;
            int row = i4 >> 3, kq = i4 & 7;
            float4 a4 = *(const float4*)&A[(size_t)(m0 + row) * 64 + k0 + kq * 4];
            float4 w4 = *(const float4*)&w[(size_t)(n0 + row) * 64 + k0 + kq * 4];
            int kb = kq * 4;
            As[(kb + 0) * 64 + row] = a4.x; As[(kb + 1) * 64 + row] = a4.y;
            As[(kb + 2) * 64 + row] = a4.z; As[(kb + 3) * 64 + row] = a4.w;
            Bs[(kb + 0) * 64 + row] = w4.x; Bs[(kb + 1) * 64 + row] = w4.y;
            Bs[(kb + 2) * 64 + row] = w4.z; Bs[(kb + 3) * 64 + row] = w4.w;
        }
        __syncthreads();
        #pragma unroll
        for (int kk = 0; kk < 32; ++kk) {
            float4 a4 = *(const float4*)&As[kk * 64 + (ty << 2)];
            float4 b4 = *(const float4*)&Bs[kk * 64 + (tx << 2)];
            #pragma unroll
            for (int i = 0; i < 4; ++i)
                #pragma unroll
                for (int j = 0; j < 4; ++j)
                    acc[i][j] += (&a4.x)[i] * (&b4.x)[j];
        }
    }
    int row0 = ty * 4, col0 = tx * 4;
    float4 bb = *(const float4*)&bias[n0 + col0];
    #pragma unroll
    for (int i = 0; i < 4; ++i) {
        float v0 = acc[i][0] + bb.x, v1 = acc[i][1] + bb.y;
        float v2 = acc[i][2] + bb.z, v3 = acc[i][3] + bb.w;
        ushort4 o;
        o.x = f2bf(v0); o.y = f2bf(v1); o.z = f2bf(v2); o.w = f2bf(v3);
        if (grp == 0) {
            *(ushort4*)&q[(size_t)(m0 + row0 + i) * 64 + col0] = o;
        } else if (grp == 1) {
            *(ushort4*)&kmat[(size_t)(m0 + row0 + i) * 64 + col0] = o;
        } else {
            Cs[(row0 + i) * 65 + col0 + 0] = o.x;
            Cs[(row0 + i) * 65 + col0 + 1] = o.y;
            Cs[(row0 + i) * 65 + col0 + 2] = o.z;
            Cs[(row0 + i) * 65 + col0 + 3] = o.w;
        }
    }
    if (grp == 2) {
        __syncthreads();
        int b = m0 >> 9, t0 = m0 & 511;
        for (int i2 = tid; i2 < 4096; i2 += 256) {
            int e = i2 >> 6, tl = i2 & 63;
            vt[((size_t)(b * 64) + e) * 512 + t0 + tl] = Cs[tl * 65 + e];
        }
    }
}

// ===== 5. MFMA attention + out-proj, low-LDS (proven round 13) =====
__global__ __launch_bounds__(256) void attn_mfma(const unsigned short* __restrict__ qbf,
                                                 const unsigned short* __restrict__ kbf,
                                                 const unsigned short* __restrict__ vtbf,
                                                 const float* __restrict__ ow,
                                                 const float* __restrict__ ob,
                                                 float* __restrict__ out) {
    __shared__ unsigned short Qs[64 * 72];
    __shared__ unsigned short KVs[64 * 72];
    __shared__ unsigned short Pp[4 * 16 * 72];
    int tid = threadIdx.x;
    int l = tid & 63, w = tid >> 6;
    int q = l >> 4, cl = l & 15;
    int b = blockIdx.y, i0 = blockIdx.x * 64;

    for (int i = tid; i < 1024; i += 256) {
        int r = i >> 4, e4 = (i & 15) * 4;
        *(ushort4*)&Qs[r * 72 + e4] = *(const ushort4*)&qbf[((size_t)(b * 512) + i0 + r) * 64 + e4];
    }
    __syncthreads();
    short8 aq0 = *(short8*)&Qs[(w * 16 + cl) * 72 + q * 8];
    short8 aq1 = *(short8*)&Qs[(w * 16 + cl) * 72 + 32 + q * 8];

    floatx4 s[32];
    #pragma unroll
    for (int f = 0; f < 32; ++f) s[f] = (floatx4){0.f, 0.f, 0.f, 0.f};

    #pragma unroll
    for (int ch = 0; ch < 8; ++ch) {
        __syncthreads();
        for (int i = tid; i < 1024; i += 256) {
            int jj = i >> 4, e4 = (i & 15) * 4;
            *(ushort4*)&KVs[jj * 72 + e4] =
                *(const ushort4*)&kbf[((size_t)(b * 512) + ch * 64 + jj) * 64 + e4];
        }
        __syncthreads();
        #pragma unroll
        for (int jt = 0; jt < 4; ++jt) {
            short8 b0 = *(short8*)&KVs[(jt * 16 + cl) * 72 + q * 8];
            short8 b1 = *(short8*)&KVs[(jt * 16 + cl) * 72 + 32 + q * 8];
            s[ch * 4 + jt] = __builtin_amdgcn_mfma_f32_16x16x32_bf16(aq0, b0, s[ch * 4 + jt], 0, 0, 0);
            s[ch * 4 + jt] = __builtin_amdgcn_mfma_f32_16x16x32_bf16(aq1, b1, s[ch * 4 + jt], 0, 0, 0);
        }
    }

    float invl[4];
    #pragma unroll
    for (int r = 0; r < 4; ++r) {
        float m = -1e30f;
        #pragma unroll
        for (int f = 0; f < 32; ++f) m = fmaxf(m, s[f][r]);
        m = fmaxf(m, __shfl_xor(m, 1)); m = fmaxf(m, __shfl_xor(m, 2));
        m = fmaxf(m, __shfl_xor(m, 4)); m = fmaxf(m, __shfl_xor(m, 8));
        float sum = 0.f;
        #pragma unroll
        for (int f = 0; f < 32; ++f) {
            float p = expf((s[f][r] - m) * 0.125f);
            s[f][r] = p; sum += p;
        }
        sum += __shfl_xor(sum, 1); sum += __shfl_xor(sum, 2);
        sum += __shfl_xor(sum, 4); sum += __shfl_xor(sum, 8);
        invl[r] = 1.f / sum;
    }

    floatx4 o4[4];
    #pragma unroll
    for (int nt = 0; nt < 4; ++nt) o4[nt] = (floatx4){0.f, 0.f, 0.f, 0.f};
    #pragma unroll
    for (int ch = 0; ch < 8; ++ch) {
        #pragma unroll
        for (int jt = 0; jt < 4; ++jt)
            #pragma unroll
            for (int r = 0; r < 4; ++r)
                Pp[w * 1152 + (q * 4 + r) * 72 + jt * 16 + cl] = f2bf(s[ch * 4 + jt][r]);
        __syncthreads();
        for (int i = tid; i < 1024; i += 256) {
            int e = i >> 4, j4 = (i & 15) * 4;
            *(ushort4*)&KVs[e * 72 + j4] =
                *(const ushort4*)&vtbf[((size_t)(b * 64) + e) * 512 + ch * 64 + j4];
        }
        __syncthreads();
        #pragma unroll
        for (int ks = 0; ks < 2; ++ks) {
            short8 ap = *(short8*)&Pp[w * 1152 + cl * 72 + ks * 32 + q * 8];
            #pragma unroll
            for (int nt = 0; nt < 4; ++nt) {
                short8 bv = *(short8*)&KVs[(nt * 16 + cl) * 72 + ks * 32 + q * 8];
                o4[nt] = __builtin_amdgcn_mfma_f32_16x16x32_bf16(ap, bv, o4[nt], 0, 0, 0);
            }
        }
    }

    #pragma unroll
    for (int nt = 0; nt < 4; ++nt)
        #pragma unroll
        for (int r = 0; r < 4; ++r)
            Qs[(w * 16 + q * 4 + r) * 72 + nt * 16 + cl] = f2bf(o4[nt][r] * invl[r]);
    __syncthreads();
    for (int i = tid; i < 1024; i += 256) {
        int o = i >> 4, e4 = (i & 15) * 4;
        float4 v = *(const float4*)&ow[o * 64 + e4];
        ushort4 u; u.x = f2bf(v.x); u.y = f2bf(v.y); u.z = f2bf(v.z); u.w = f2bf(v.w);
        *(ushort4*)&KVs[o * 72 + e4] = u;
    }
    __syncthreads();
    floatx4 acc2[4];
    #pragma unroll
    for (int nt = 0; nt < 4; ++nt) acc2[nt] = (floatx4){0.f, 0.f, 0.f, 0.f};
    #pragma unroll
    for (int ks = 0; ks < 2; ++ks) {
        short8 ao = *(short8*)&Qs[(w * 16 + cl) * 72 + ks * 32 + q * 8];
        #pragma unroll
        for (int nt = 0; nt < 4; ++nt) {
            short8 bo = *(short8*)&KVs[(nt * 16 + cl) * 72 + ks * 32 + q * 8];
            acc2[nt] = __builtin_amdgcn_mfma_f32_16x16x32_bf16(ao, bo, acc2[nt], 0, 0, 0);
        }
    }
    #pragma unroll
    for (int nt = 0; nt < 4; ++nt) {
        float bb = ob[nt * 16 + cl];
        #pragma unroll
        for (int r = 0; r < 4; ++r)
            out[((size_t)(b * 512) + i0 + w * 16 + q * 4 + r) * 64 + nt * 16 + cl] = acc2[nt][r] + bb;
    }
}

// ===== 6. tiled fp32 GEMM, FAN epilogues -> bf16 hbf (proven round 13) =====
template<int EPI>
__global__ __launch_bounds__(256) void gemm_k(const float* __restrict__ A,
                                              const float* __restrict__ W,
                                              const float* __restrict__ bias,
                                              unsigned short* __restrict__ C,
                                              int K,
                                              const float* __restrict__ gate) {
    __shared__ float As[32 * 64];
    __shared__ float Bs[32 * 64];
    int tid = threadIdx.x;
    int tx = tid & 15, ty = tid >> 4;
    int m0 = blockIdx.y * 64, n0 = blockIdx.x * 64;
    float acc[4][4] = {};
    for (int k0 = 0; k0 < K; k0 += 32) {
        __syncthreads();
        #pragma unroll
        for (int s = 0; s < 2; ++s) {
            int i4 = tid + s * 256;
            int row = i4 >> 3, kq = i4 & 7;
            float4 a4 = *(const float4*)&A[(size_t)(m0 + row) * K + k0 + kq * 4];
            float4 w4 = *(const float4*)&W[(size_t)(n0 + row) * K + k0 + kq * 4];
            int kb = kq * 4;
            As[(kb + 0) * 64 + row] = a4.x; As[(kb + 1) * 64 + row] = a4.y;
            As[(kb + 2) * 64 + row] = a4.z; As[(kb + 3) * 64 + row] = a4.w;
            Bs[(kb + 0) * 64 + row] = w4.x; Bs[(kb + 1) * 64 + row] = w4.y;
            Bs[(kb + 2) * 64 + row] = w4.z; Bs[(kb + 3) * 64 + row] = w4.w;
        }
        __syncthreads();
        #pragma unroll
        for (int kk = 0; kk < 32; ++kk) {
            float4 a4 = *(const float4*)&As[kk * 64 + (ty << 2)];
            float4 b4 = *(const float4*)&Bs[kk * 64 + (tx << 2)];
            #pragma unroll
            for (int i = 0; i < 4; ++i)
                #pragma unroll
                for (int j = 0; j < 4; ++j)
                    acc[i][j] += (&a4.x)[i] * (&b4.x)[j];
        }
    }
    int row0 = m0 + ty * 4, col0 = n0 + tx * 4;
    float4 bb = *(const float4*)&bias[col0];
    float gt = 1.f / (1.f + expf(-gate[0]));
    #pragma unroll
    for (int i = 0; i < 4; ++i) {
        int row = row0 + i;
        float v0 = acc[i][0] + bb.x, v1 = acc[i][1] + bb.y;
        float v2 = acc[i][2] + bb.z, v3 = acc[i][3] + bb.w;
        if (EPI == 2) {
            ushort4 co, si;
            co.x = f2bf(gt * cosf(v0)); co.y = f2bf(gt * cosf(v1));
            co.z = f2bf(gt * cosf(v2)); co.w = f2bf(gt * cosf(v3));
            si.x = f2bf(gt * sinf(v0)); si.y = f2bf(gt * sinf(v1));
            si.z = f2bf(gt * sinf(v2)); si.w = f2bf(gt * sinf(v3));
            *(ushort4*)&C[(size_t)row * 1024 + col0] = co;
            *(ushort4*)&C[(size_t)row * 1024 + 128 + col0] = si;
        } else if (EPI == 3) {
            float ig = 1.f - gt;
            ushort4 o;
            o.x = f2bf(ig * 0.5f * v0 * (1.f + erff(v0 * 0.70710678118f)));
            o.y = f2bf(ig * 0.5f * v1 * (1.f + erff(v1 * 0.70710678118f)));
            o.z = f2bf(ig * 0.5f * v2 * (1.f + erff(v2 * 0.70710678118f)));
            o.w = f2bf(ig * 0.5f * v3 * (1.f + erff(v3 * 0.70710678118f)));
            *(ushort4*)&C[(size_t)row * 1024 + 256 + col0] = o;
        }
    }
}

// ===== 7. cast f32 -> bf16 (weights only) =====
__global__ __launch_bounds__(256) void cast_bf16(const float* __restrict__ in,
                                                 unsigned short* __restrict__ out, int n4) {
    int i = blockIdx.x * 256 + threadIdx.x;
    if (i < n4) {
        float4 v = *(const float4*)&in[(size_t)i * 4];
        ushort4 o;
        o.x = f2bf(v.x); o.y = f2bf(v.y); o.z = f2bf(v.z); o.w = f2bf(v.w);
        *(ushort4*)&out[(size_t)i * 4] = o;
    }
}

// ===== 8. bf16 MFMA GEMM (proven round 6) — fc1 only now =====
__global__ __launch_bounds__(256) void gemm_mfma1(const unsigned short* __restrict__ A,
                                                  const unsigned short* __restrict__ B,
                                                  const float* __restrict__ bias,
                                                  unsigned short* __restrict__ Cb,
                                                  int M, int N, int K) {
    __shared__ unsigned short As[8192];
    __shared__ unsigned short Bs[8192];
    int tid = threadIdx.x;
    int l = tid & 63, w = tid >> 6;
    int q = l >> 4, cl = l & 15;
    int wm = w >> 1, wn = w & 1;
    int m0 = blockIdx.y * 128, n0 = blockIdx.x * 128;
    floatx4 acc[4][4];
    #pragma unroll
    for (int i = 0; i < 4; ++i)
        #pragma unroll
        for (int j = 0; j < 4; ++j)
            acc[i][j] = (floatx4){0.f, 0.f, 0.f, 0.f};

    for (int k0 = 0; k0 < K; k0 += 64) {
        __syncthreads();
        #pragma unroll
        for (int ci = 0; ci < 8; ++ci) {
            int cid = w * 8 + ci;
            int isB = cid >> 4;
            int c = cid & 15;
            int cq = c >> 3, cks = (c >> 2) & 1, cf = c & 3;
            int row = cq * 64 + cf * 16 + cl;
            int col = k0 + cks * 32 + q * 8;
            const unsigned short* gp = isB ? (B + (size_t)(n0 + row) * K + col)
                                           : (A + (size_t)(m0 + row) * K + col);
            unsigned short* lp = (isB ? Bs : As) + c * 512;
            __builtin_amdgcn_global_load_lds((const __attribute__((address_space(1))) void*)gp,
                                             (__attribute__((address_space(3))) void*)lp,
                                             16, 0, 0);
        }
        __syncthreads();
        #pragma unroll
        for (int ks = 0; ks < 2; ++ks) {
            short8 af[4], bg[4];
            #pragma unroll
            for (int f = 0; f < 4; ++f) {
                af[f] = *(short8*)&As[(wm * 8 + ks * 4 + f) * 512 + l * 8];
                bg[f] = *(short8*)&Bs[(wn * 8 + ks * 4 + f) * 512 + l * 8];
            }
            #pragma unroll
            for (int i = 0; i < 4; ++i)
                #pragma unroll
                for (int j = 0; j < 4; ++j)
                    acc[i][j] = __builtin_amdgcn_mfma_f32_16x16x32_bf16(af[i], bg[j], acc[i][j], 0, 0, 0);
        }
    }

    #pragma unroll
    for (int j = 0; j < 4; ++j) {
        int col = n0 + wn * 64 + j * 16 + cl;
        float bb = bias[col];
        #pragma unroll
        for (int i = 0; i < 4; ++i) {
            int rowb = m0 + wm * 64 + i * 16 + q * 4;
            #pragma unroll
            for (int r = 0; r < 4; ++r) {
                float v = acc[i][j][r] + bb;
                Cb[(size_t)(rowb + r) * N + col] = f2bf(fmaxf(v, 0.f));
            }
        }
    }
}

// ===== 9. fc2 split-K: same MFMA body, blockIdx.z covers 768 of K=3072; f32 partials =====
// A = w2bf [512][3072] (rows=t), B = hidbf [4096][3072] (rows=bc); partial written
// in final out layout ((bidx*512+t)*64+c), no bias (added in fc2_reduce).
__global__ __launch_bounds__(256) void gemm_fc2_split(const unsigned short* __restrict__ A,
                                                      const unsigned short* __restrict__ B,
                                                      float* __restrict__ part,
                                                      int K) {
    __shared__ unsigned short As[8192];
    __shared__ unsigned short Bs[8192];
    int tid = threadIdx.x;
    int l = tid & 63, w = tid >> 6;
    int q = l >> 4, cl = l & 15;
    int wm = w >> 1, wn = w & 1;
    int m0 = blockIdx.y * 128, n0 = blockIdx.x * 128;
    int kbeg = blockIdx.z * 768;
    floatx4 acc[4][4];
    #pragma unroll
    for (int i = 0; i < 4; ++i)
        #pragma unroll
        for (int j = 0; j < 4; ++j)
            acc[i][j] = (floatx4){0.f, 0.f, 0.f, 0.f};

    for (int k0 = kbeg; k0 < kbeg + 768; k0 += 64) {
        __syncthreads();
        #pragma unroll
        for (int ci = 0; ci < 8; ++ci) {
            int cid = w * 8 + ci;
            int isB = cid >> 4;
            int c = cid & 15;
            int cq = c >> 3, cks = (c >> 2) & 1, cf = c & 3;
            int row = cq * 64 + cf * 16 + cl;
            int col = k0 + cks * 32 + q * 8;
            const unsigned short* gp = isB ? (B + (size_t)(n0 + row) * K + col)
                                           : (A + (size_t)(m0 + row) * K + col);
            unsigned short* lp = (isB ? Bs : As) + c * 512;
            __builtin_amdgcn_global_load_lds((const __attribute__((address_space(1))) void*)gp,
                                             (__attribute__((address_space(3))) void*)lp,
                                             16, 0, 0);
        }
        __syncthreads();
        #pragma unroll
        for (int ks = 0; ks < 2; ++ks) {
            short8 af[4], bg[4];
            #pragma unroll
            for (int f = 0; f < 4; ++f) {
                af[f] = *(short8*)&As[(wm * 8 + ks * 4 + f) * 512 + l * 8];
                bg[f] = *(short8*)&Bs[(wn * 8 + ks * 4 + f) * 512 + l * 8];
            }
            #pragma unroll
            for (int i = 0; i < 4; ++i)
                #pragma unroll
                for (int j = 0; j < 4; ++j)
                    acc[i][j] = __builtin_amdgcn_mfma_f32_16x16x32_bf16(af[i], bg[j], acc[i][j], 0, 0, 0);
        }
    }

    float* Ob = part + (size_t)blockIdx.z * 2097152;
    int bidx = (n0 >> 6) + wn;
    #pragma unroll
    for (int i = 0; i < 4; ++i) {
        #pragma unroll
        for (int r = 0; r < 4; ++r) {
            int t = m0 + wm * 64 + i * 16 + q * 4 + r;
            #pragma unroll
            for (int j = 0; j < 4; ++j) {
                int c = j * 16 + cl;
                Ob[((size_t)bidx * 512 + t) * 64 + c] = acc[i][j][r];
            }
        }
    }
}

// ===== 10. fc2 reduce: out = sum of 4 partials + bias[t] =====
__global__ __launch_bounds__(256) void fc2_reduce(const float* __restrict__ part,
                                                  const float* __restrict__ bias,
                                                  float* __restrict__ out) {
    int i = blockIdx.x * 256 + threadIdx.x;        // float4 index, 524288 total
    if (i < 524288) {
        size_t e = (size_t)i * 4;
        int t = (int)((e >> 6) & 511);             // same t for all 4 lanes of the float4
        float bb = bias[t];
        float4 p0 = *(const float4*)&part[e];
        float4 p1 = *(const float4*)&part[2097152 + e];
        float4 p2 = *(const float4*)&part[4194304 + e];
        float4 p3 = *(const float4*)&part[6291456 + e];
        float4 o;
        o.x = p0.x + p1.x + p2.x + p3.x + bb;
        o.y = p0.y + p1.y + p2.y + p3.y + bb;
        o.z = p0.z + p1.z + p2.z + p3.z + bb;
        o.w = p0.w + p1.w + p2.w + p3.w + bb;
        *(float4*)&out[e] = o;
    }
}

extern "C" void kernel_launch(void* const* d_in, const int* in_sizes, int n_in,
                              void* d_out, int out_size, void* d_ws, size_t ws_size,
                              hipStream_t stream) {
    const float* x         = (const float*)d_in[0];
    const float* in_proj_w = (const float*)d_in[1];
    const float* in_proj_b = (const float*)d_in[2];
    const float* out_w     = (const float*)d_in[3];
    const float* out_b     = (const float*)d_in[4];
    const float* Wp        = (const float*)d_in[5];
    const float* bp        = (const float*)d_in[6];
    const float* Wg        = (const float*)d_in[7];
    const float* bg        = (const float*)d_in[8];
    const float* gate      = (const float*)d_in[9];
    const float* fc1_w     = (const float*)d_in[10];
    const float* fc1_b     = (const float*)d_in[11];
    const float* fc2_w     = (const float*)d_in[12];
    const float* fc2_b     = (const float*)d_in[13];
    const int*   kptr      = (const int*)d_in[14];
    float* ws  = (float*)d_ws;
    float* out = (float*)d_out;

    float* mft   = ws + U_MFT;
    float* xre   = ws + U_XRE;
    float* xim   = ws + U_XIM;
    int*   keepi = (int*)(ws + U_KEEPI);
    float* keepw = ws + U_KEEPW;
    float* xfilt = ws + U_XFILT;
    float* norm  = ws + U_NORM;
    float* part  = ws + U_PART;
    float* fc2p  = ws + U_FC2P;
    unsigned short* hbf   = (unsigned short*)(ws + U_HBF);
    unsigned short* qb    = (unsigned short*)(ws + U_Q);
    unsigned short* kb    = (unsigned short*)(ws + U_K);
    unsigned short* vtb   = (unsigned short*)(ws + U_V);
    unsigned short* hidbf = (unsigned short*)(ws + U_HIDBF);
    unsigned short* w1bf  = (unsigned short*)(ws + U_W1BF);
    unsigned short* w2bf  = (unsigned short*)(ws + U_W2BF);

    dft_split  <<<dim3(5, 64, 4), 256, 0, stream>>>(x, xre, xim, part);
    dft_reduce <<<dim3(2056),     256, 0, stream>>>(xre, part);
    topk_lds   <<<dim3(4096),     256, 0, stream>>>(xre, xim, keepi, keepw, kptr);
    xfilt_fused<<<dim3(8, 64),    256, 0, stream>>>(x, xre, xim, keepi, keepw, xfilt, norm, mft, hbf, kptr);
    qkv_gemm   <<<dim3(3, 512),   256, 0, stream>>>(xfilt, norm, in_proj_w, in_proj_b, qb, kb, vtb);
    attn_mfma  <<<dim3(8, 64),    256, 0, stream>>>(qb, kb, vtb, out_w, out_b, out);
    gemm_k<2>  <<<dim3(2, 64),    256, 0, stream>>>(mft, Wp, bp, hbf, 512, gate);
    gemm_k<3>  <<<dim3(4, 64),    256, 0, stream>>>(mft, Wg, bg, hbf, 512, gate);
    cast_bf16<<<3072, 256, 0, stream>>>(fc1_w, w1bf, 786432);
    cast_bf16<<<1536, 256, 0, stream>>>(fc2_w, w2bf, 393216);
    gemm_mfma1    <<<dim3(24, 32),   256, 0, stream>>>(hbf, w1bf, fc1_b, hidbf, 4096, 3072, 1024);
    gemm_fc2_split<<<dim3(32, 4, 4), 256, 0, stream>>>(w2bf, hidbf, fc2p, 3072);
    fc2_reduce    <<<dim3(2048),     256, 0, stream>>>(fc2p, fc2_b, out + 2097152);
}